// Round 7
// baseline (462.559 us; speedup 1.0000x reference)
//
#include <hip/hip_runtime.h>
#include <stdint.h>

// ---------- bf16 helpers ----------
__device__ __forceinline__ float bf2f(unsigned short u) {
  union { unsigned int i; float f; } v; v.i = ((unsigned int)u) << 16; return v.f;
}
__device__ __forceinline__ unsigned short f2bf(float f) {
  union { float f; unsigned int i; } v; v.f = f;
  unsigned int i = v.i;
  unsigned int r = (i + 0x7fffu + ((i >> 16) & 1u)) >> 16;  // RNE
  return (unsigned short)r;
}

typedef __bf16 bf16x8 __attribute__((ext_vector_type(8)));
typedef float f32x4 __attribute__((ext_vector_type(4)));
typedef float f32x2 __attribute__((ext_vector_type(2)));
union ABfrag { int4 i4; bf16x8 v; };

// ---------- fp8 e4m3fn (OCP): HW path on gfx950, SW fallback ----------
#if __has_builtin(__builtin_amdgcn_cvt_pk_fp8_f32) && __has_builtin(__builtin_amdgcn_cvt_pk_f32_fp8)
#define HW_FP8 1
#else
#define HW_FP8 0
#endif

__device__ __forceinline__ unsigned char f2fp8_sw(float f) {
  union { float f; unsigned int u; } v; v.f = f;
  unsigned int s = (v.u >> 24) & 0x80;
  float a = fabsf(f);
  if (a >= 448.f) return (unsigned char)(s | 0x7E);
  v.f = a;
  int ex = (int)(v.u >> 23);
  unsigned int man = v.u & 0x7FFFFFu;
  if (ex >= 121) {
    unsigned int val = ((unsigned int)(ex - 120) << 3) | (man >> 20);
    unsigned int rem = man & 0xFFFFFu;
    if (rem > 0x80000u || (rem == 0x80000u && (val & 1))) val++;
    if (val > 0x7E) val = 0x7E;
    return (unsigned char)(s | val);
  }
  int q = (int)(a * 512.f + 0.5f);
  if (q > 8) q = 8;
  return (unsigned char)(s | (unsigned int)q);
}
__device__ __forceinline__ float fp8dec_sw(unsigned char c) {
  unsigned int e = (c >> 3) & 15u, m = c & 7u;
  float v;
  if (e) { union { unsigned int u; float f; } x; x.u = ((e + 120) << 23) | (m << 20); v = x.f; }
  else v = (float)m * 0.001953125f;
  return (c & 0x80) ? -v : v;
}
// pack 4 floats -> 4 fp8 bytes in one dword (bytes 0..3 = a0..a3)
__device__ __forceinline__ unsigned int pack4_fp8(float a0, float a1, float a2, float a3) {
#if HW_FP8
  int dw = __builtin_amdgcn_cvt_pk_fp8_f32(a0, a1, 0, false);
  dw = __builtin_amdgcn_cvt_pk_fp8_f32(a2, a3, dw, true);
  return (unsigned int)dw;
#else
  return (unsigned)f2fp8_sw(a0) | ((unsigned)f2fp8_sw(a1) << 8) |
         ((unsigned)f2fp8_sw(a2) << 16) | ((unsigned)f2fp8_sw(a3) << 24);
#endif
}
// select byte rr from each of 4 dwords -> one dword
__device__ __forceinline__ unsigned int bytesel4(uint4 v, int rr) {
#if __has_builtin(__builtin_amdgcn_perm)
  unsigned s = (unsigned)rr | ((unsigned)(rr + 4) << 8);
  unsigned p01 = __builtin_amdgcn_perm(v.y, v.x, s);          // [x[rr], y[rr], ..]
  unsigned p23 = __builtin_amdgcn_perm(v.w, v.z, s);          // [z[rr], w[rr], ..]
  return __builtin_amdgcn_perm(p23, p01, 0x05040100u);        // [x,y,z,w][rr]
#else
  int sh = rr * 8;
  return ((v.x >> sh) & 0xFFu) | (((v.y >> sh) & 0xFFu) << 8) |
         (((v.z >> sh) & 0xFFu) << 16) | (((v.w >> sh) & 0xFFu) << 24);
#endif
}
// decode 16 fp8 -> 8 packed float2 (keeps cvt_pk's natural pair output)
__device__ __forceinline__ void dec16p(int4 g, f32x2 o[8]) {
#if HW_FP8
  o[0] = __builtin_amdgcn_cvt_pk_f32_fp8(g.x, false);
  o[1] = __builtin_amdgcn_cvt_pk_f32_fp8(g.x, true);
  o[2] = __builtin_amdgcn_cvt_pk_f32_fp8(g.y, false);
  o[3] = __builtin_amdgcn_cvt_pk_f32_fp8(g.y, true);
  o[4] = __builtin_amdgcn_cvt_pk_f32_fp8(g.z, false);
  o[5] = __builtin_amdgcn_cvt_pk_f32_fp8(g.z, true);
  o[6] = __builtin_amdgcn_cvt_pk_f32_fp8(g.w, false);
  o[7] = __builtin_amdgcn_cvt_pk_f32_fp8(g.w, true);
#else
  unsigned int w[4] = {(unsigned)g.x, (unsigned)g.y, (unsigned)g.z, (unsigned)g.w};
#pragma unroll
  for (int d = 0; d < 4; ++d) {
    unsigned int x = w[d];
    o[d * 2 + 0] = (f32x2){fp8dec_sw((unsigned char)(x & 0xFF)),
                           fp8dec_sw((unsigned char)((x >> 8) & 0xFF))};
    o[d * 2 + 1] = (f32x2){fp8dec_sw((unsigned char)((x >> 16) & 0xFF)),
                           fp8dec_sw((unsigned char)((x >> 24) & 0xFF))};
  }
#endif
}

__device__ __forceinline__ float lrelu_clamp(float e) {
  e = (e > 0.f) ? e : 0.2f * e;
  return fminf(e, 80.f);
}

// ---------- dtype detection + degAB zeroing (merged) ----------
__global__ __launch_bounds__(256) void k_detect(const unsigned int* __restrict__ x, int* flag,
                                                int* __restrict__ degAB, int ndeg2) {
  if (blockIdx.x == 0) {
    __shared__ int cnt;
    if (threadIdx.x == 0) cnt = 0;
    __syncthreads();
    int c = 0;
    for (int i = threadIdx.x; i < 1024; i += 256) {
      unsigned int lo = x[i] & 0xFFFFu;
      int ex = (int)((lo >> 7) & 0xFF);
      if (ex >= 100 && ex <= 140) c++;
    }
    atomicAdd(&cnt, c);
    __syncthreads();
    if (threadIdx.x == 0) flag[0] = (cnt > 600) ? 1 : 0;  // 1 = bf16 inputs
    return;
  }
  for (int idx = (blockIdx.x - 1) * 256 + threadIdx.x; idx < ndeg2; idx += 8 * 256) degAB[idx] = 0;
}

// ---------- unified prep (+ degree count + attention-weight fold) ----------
// New: Wa fold — es1 = (X@W1)@as1^T(per-head) == X @ Was1 with
// Was1[k][h] = sum_c W1[k, h*64+c] * as1[h, c]. Removes the entire es/ed
// epilogue (serial shfl chains) from the big GEMM kernel.
struct PrepDesc {
  const void* csrc[32]; float* cdst[32]; int cn[32];
  const void* x; float* xc; unsigned short* xp;
  const void* W1; const void* W2; const void* W3; const void* W4;
  unsigned short* P1; unsigned short* P2; unsigned short* P3; unsigned short* P4;
  int* degAB;
  const int* ei;
  const void* av[4];   // as1, ad1, as3, ad3 (raw inputs)
  float* wa[4];        // Was1, Wad1, Was3, Wad3 [128x32]
  int nxb, xtotal, ctotal, E, nn;
};
__global__ __launch_bounds__(256) void k_prep(PrepDesc d, const int* __restrict__ flag) {
  int isbf = *flag;
  int b = blockIdx.x;
  if (b < d.nxb) {
    // vectorized: 8 elements per thread
    int t8 = b * 256 + threadIdx.x;
    int i8 = t8 * 8;
    if (i8 < d.xtotal) {
      float v[8];
      if (isbf) {
        int4 raw = *(const int4*)((const unsigned short*)d.x + i8);
        const unsigned short* u = (const unsigned short*)&raw;
#pragma unroll
        for (int j = 0; j < 8; ++j) v[j] = bf2f(u[j]);
      } else {
        float4 f0 = *(const float4*)((const float*)d.x + i8);
        float4 f1 = *(const float4*)((const float*)d.x + i8 + 4);
        v[0] = f0.x; v[1] = f0.y; v[2] = f0.z; v[3] = f0.w;
        v[4] = f1.x; v[5] = f1.y; v[6] = f1.z; v[7] = f1.w;
      }
      *(float4*)(d.xc + i8)     = (float4){v[0], v[1], v[2], v[3]};
      *(float4*)(d.xc + i8 + 4) = (float4){v[4], v[5], v[6], v[7]};
      int row = i8 >> 7, c0 = i8 & 127;
      int tm = row >> 4, mr = row & 15;
      int s = c0 >> 5, quad = (c0 >> 3) & 3;
      unsigned short o[8];
#pragma unroll
      for (int j = 0; j < 8; ++j) o[j] = f2bf(v[j]);
      size_t idx = (((size_t)tm * 4 + s) * 64 + quad * 16 + mr) * 8;
      *(int4*)(d.xp + idx) = *(const int4*)o;
    }
    return;
  }
  b -= d.nxb;
  if (b < 288) {
    int u = b * 256 + threadIdx.x;
    const void* W; unsigned short* P; int K, N, lu;
    if (u < 32768)      { W = d.W1; P = d.P1; K = 128; N = 2048; lu = u; }
    else if (u < 36864) { W = d.W2; P = d.P2; K = 64;  N = 512;  lu = u - 32768; }
    else if (u < 69632) { W = d.W3; P = d.P3; K = 128; N = 2048; lu = u - 36864; }
    else                { W = d.W4; P = d.P4; K = 64;  N = 512;  lu = u - 69632; }
    int ksteps = K >> 5;
    int g = lu / (ksteps * 64);
    int rem = lu - g * (ksteps * 64);
    int s = rem >> 6, lane = rem & 63;
    int mr = lane & 15, quad = lane >> 4;
    int col = g * 16 + mr;
    int kbase = s * 32 + quad * 8;
#pragma unroll
    for (int j = 0; j < 8; ++j) {
      size_t src = (size_t)(kbase + j) * N + col;
      float v = isbf ? bf2f(((const unsigned short*)W)[src]) : ((const float*)W)[src];
      P[(size_t)lu * 8 + j] = f2bf(v);
    }
    return;
  }
  b -= 288;
  if (b < 4) {
    for (int idx = b * 256 + threadIdx.x; idx < d.ctotal; idx += 4 * 256) {
      int t = 0, off = idx;
      while (off >= d.cn[t]) { off -= d.cn[t]; ++t; }
      float v = isbf ? bf2f(((const unsigned short*)d.csrc[t])[off])
                     : ((const float*)d.csrc[t])[off];
      d.cdst[t][off] = v;
    }
    return;
  }
  b -= 4;
  {
    int degblks = (d.E + 255) >> 8;
    if (b < degblks) {  // degree count (degAB zeroed by k_detect)
      int e = b * 256 + threadIdx.x;
      if (e < d.E) {
        atomicAdd(&d.degAB[d.ei[d.E + e]], 1);
        atomicAdd(&d.degAB[d.nn + d.ei[e]], 1);
      }
      return;
    }
    b -= degblks;
  }
  {  // Wa fold: block b in [0,4): (W, a) -> wa[b];  W row-major [128 x 2048]
    const void* W = (b < 2) ? d.W1 : d.W3;
    const void* A = d.av[b];
    float* out = d.wa[b];
    int k = threadIdx.x >> 1;
    int hb = (threadIdx.x & 1) * 16;
    const unsigned short* Wb = (const unsigned short*)W;
    const float* Wf = (const float*)W;
    const unsigned short* Ab = (const unsigned short*)A;
    const float* Af = (const float*)A;
#pragma unroll
    for (int h16 = 0; h16 < 16; ++h16) {
      int h = hb + h16;
      float acc = 0.f;
      size_t wbase = (size_t)k * 2048 + h * 64;
      int abase = h * 64;
#pragma unroll 8
      for (int c = 0; c < 64; ++c) {
        float wv = isbf ? bf2f(Wb[wbase + c]) : Wf[wbase + c];
        float av = isbf ? bf2f(Ab[abase + c]) : Af[abase + c];
        acc += wv * av;
      }
      out[k * 32 + h] = acc;
    }
  }
}

// ---------- CSR exclusive scan ----------
__global__ __launch_bounds__(1024) void k_exscan2(const int* __restrict__ degA, const int* __restrict__ degB,
                                                  int* __restrict__ rowA, int* __restrict__ rowB,
                                                  int* __restrict__ colA, int* __restrict__ colB,
                                                  int* __restrict__ curA, int* __restrict__ curB, int n) {
  const int* deg = (blockIdx.x == 0) ? degA : degB;
  int* row = (blockIdx.x == 0) ? rowA : rowB;
  int* colx = (blockIdx.x == 0) ? colA : colB;
  int* curx = (blockIdx.x == 0) ? curA : curB;
  __shared__ int wsum[16], wbase[16];
  __shared__ int carry;
  if (threadIdx.x == 0) carry = 0;
  __syncthreads();
  int lane = threadIdx.x & 63, w = threadIdx.x >> 6;
  int chunks = (n + 1023) >> 10;
  for (int ch = 0; ch < chunks; ++ch) {
    int i = (ch << 10) + threadIdx.x;
    int v = (i < n) ? deg[i] : 0;
    int sc = v;
#pragma unroll
    for (int o = 1; o < 64; o <<= 1) { int t = __shfl_up(sc, o); if (lane >= o) sc += t; }
    if (lane == 63) wsum[w] = sc;
    __syncthreads();
    if (threadIdx.x < 16) {
      int v2 = wsum[threadIdx.x], s2 = v2;
#pragma unroll
      for (int o = 1; o < 16; o <<= 1) { int t = __shfl_up(s2, o); if (lane >= o) s2 += t; }
      wbase[threadIdx.x] = s2 - v2;
      if (threadIdx.x == 15) wsum[15] = s2;
    }
    __syncthreads();
    if (i < n) {
      int rv = carry + wbase[w] + (sc - v) + i;
      row[i] = rv;
      colx[rv] = i;
      curx[i] = rv + 1;
    }
    __syncthreads();
    if (threadIdx.x == 0) carry += wsum[15];
    __syncthreads();
  }
  if (threadIdx.x == 0) row[n] = carry + n;
}

// ---------- aux: residual MLP + es/ed GEMV + CSR scatter ----------
struct AuxDesc {
  int resblks, E;
  const int* ei; int* colA; int* colB; int* curA; int* curB;
  const float* xc;
  const float* rp[20];
  const float* wa[4];                 // Was1, Wad1, Was3, Wad3 [128x32]
  float* es1; float* ed1; float* es3; float* ed3;
  void* outbase; size_t eoff; int n;
  const int* flag;
};
__global__ __launch_bounds__(256) void k_aux(AuxDesc d) {
  __shared__ struct { float xs[16][128]; float ha[16][16]; float tt[16][16]; } sm;
  int b = blockIdx.x;
  if (b < d.resblks) {
    int nodebase = b * 16;
    for (int t = threadIdx.x; t < 16 * 128; t += 256)
      sm.xs[t >> 7][t & 127] = d.xc[(size_t)(nodebase + (t >> 7)) * 128 + (t & 127)];
    __syncthreads();
    int ni = threadIdx.x >> 4, c = threadIdx.x & 15;
    // ---- es/ed GEMV: es1/ed1/es3/ed3 [16 nodes x 32 heads] ----
    {
      const float* w0 = d.wa[0]; const float* w1 = d.wa[1];
      const float* w2 = d.wa[2]; const float* w3 = d.wa[3];
      float a0 = 0.f, a1 = 0.f, a2 = 0.f, a3 = 0.f, a4 = 0.f, a5 = 0.f, a6 = 0.f, a7 = 0.f;
#pragma unroll 4
      for (int k = 0; k < 128; ++k) {
        float xv = sm.xs[ni][k];
        int o = k * 32 + c;
        a0 += xv * w0[o]; a1 += xv * w0[o + 16];
        a2 += xv * w1[o]; a3 += xv * w1[o + 16];
        a4 += xv * w2[o]; a5 += xv * w2[o + 16];
        a6 += xv * w3[o]; a7 += xv * w3[o + 16];
      }
      int row = nodebase + ni;
      d.es1[row * 32 + c] = a0; d.es1[row * 32 + c + 16] = a1;
      d.ed1[row * 32 + c] = a2; d.ed1[row * 32 + c + 16] = a3;
      d.es3[row * 32 + c] = a4; d.es3[row * 32 + c + 16] = a5;
      d.ed3[row * 32 + c] = a6; d.ed3[row * 32 + c + 16] = a7;
    }
    // ---- residual MLP ----
    const float* rwa = d.rp[0]; const float* rba = d.rp[1];
    const float* bn1g = d.rp[2]; const float* bn1b = d.rp[3];
    const float* bn1m = d.rp[4]; const float* bn1v = d.rp[5];
    const float* rwb = d.rp[6]; const float* rbb = d.rp[7];
    const float* bn2g = d.rp[8]; const float* bn2b = d.rp[9];
    const float* bn2m = d.rp[10]; const float* bn2v = d.rp[11];
    const float* wsc = d.rp[12]; const float* bsc = d.rp[13];
    const float* bnsg = d.rp[14]; const float* bnsb = d.rp[15];
    const float* bnsm = d.rp[16]; const float* bnsv = d.rp[17];
    const float* wfc = d.rp[18]; const float* bfc = d.rp[19];
    float ya = 0.f, ysc = 0.f;
#pragma unroll 8
    for (int k = 0; k < 128; ++k) {
      float xv = sm.xs[ni][k];
      ya  += xv * rwa[k * 16 + c];
      ysc += xv * wsc[k * 16 + c];
    }
    ya += rba[c]; ysc += bsc[c];
    float s1 = bn1g[c] * rsqrtf(bn1v[c] + 1e-5f);
    ya = (ya - bn1m[c]) * s1 + bn1b[c];
    ya = fmaxf(ya, 0.f);
    float ss = bnsg[c] * rsqrtf(bnsv[c] + 1e-5f);
    ysc = (ysc - bnsm[c]) * ss + bnsb[c];
    sm.ha[ni][c] = ya;
    __syncthreads();
    float h2 = rbb[c];
#pragma unroll
    for (int k = 0; k < 16; ++k) h2 += sm.ha[ni][k] * rwb[k * 16 + c];
    float s2 = bn2g[c] * rsqrtf(bn2v[c] + 1e-5f);
    h2 = (h2 - bn2m[c]) * s2 + bn2b[c];
    sm.tt[ni][c] = fmaxf(h2 + ysc, 0.f);
    __syncthreads();
    float o = bfc[c];
#pragma unroll
    for (int k = 0; k < 16; ++k) o += sm.tt[ni][k] * wfc[k * 16 + c];
    size_t oo = d.eoff + (size_t)(nodebase + ni) * 16 + c;
    if (*d.flag) ((unsigned short*)d.outbase)[oo] = f2bf(o);
    else         ((float*)d.outbase)[oo] = o;
    return;
  }
  b -= d.resblks;
  {  // CSR scatter
    int e = b * 256 + threadIdx.x;
    if (e < d.E) {
      int s = d.ei[e], dd = d.ei[d.E + e];
      d.colA[atomicAdd(&d.curA[dd], 1)] = s;
      d.colB[atomicAdd(&d.curB[s], 1)] = dd;
    }
  }
}

// ---------- 64-row x 64-col per-wave GEMM body ----------
// CH==64 (mm1/mm3): PURE GEMM + fp8 pack/store — es/ed moved to k_aux (algebraic fold).
// CH==16 (mm2/mm4): es/ed kept in-body (only 314 blocks).
#define TILE_DW 288
template<int CH, int KSTEPS>
__device__ __forceinline__ void mm_es64_body(int rg, int cg, int MT,
    const unsigned short* __restrict__ Ap, const unsigned short* __restrict__ Bp,
    unsigned char* __restrict__ C, const float* __restrict__ a_s, const float* __restrict__ a_d,
    float* __restrict__ es, float* __restrict__ ed, int N, unsigned int* tile) {
  const int TI = KSTEPS * 64;              // int4 per 16-row A tile
  int vt = MT - rg * 4; if (vt > 4) vt = 4;  // valid row tiles (block-uniform)
  int wid = threadIdx.x >> 6;
  int tn = cg * 4 + wid;
  int lane = threadIdx.x & 63;
  int mr = lane & 15, quad = lane >> 4;
  const int4* ap = (const int4*)(Ap + (size_t)rg * 4 * TI * 8) + lane;
  const unsigned short* bp = Bp + ((size_t)tn * 4 * KSTEPS) * 512 + lane * 8;
  unsigned int* twave = tile + wid * TILE_DW;
  f32x4 acc[4][4];
#pragma unroll
  for (int rt = 0; rt < 4; ++rt)
#pragma unroll
    for (int nt = 0; nt < 4; ++nt) acc[rt][nt] = (f32x4){0.f, 0.f, 0.f, 0.f};
#pragma unroll
  for (int s = 0; s < KSTEPS; ++s) {
    ABfrag bfr[4];
#pragma unroll
    for (int nt = 0; nt < 4; ++nt) bfr[nt].i4 = *(const int4*)(bp + (size_t)(nt * KSTEPS + s) * 512);
    ABfrag afr[4];
#pragma unroll
    for (int rt = 0; rt < 4; ++rt) {
      int rti = (rt < vt) ? rt : 0;   // clamp: keep tail-row-group reads inside xp
      afr[rt].i4 = ap[rti * TI + s * 64];
    }
#pragma unroll
    for (int nt = 0; nt < 4; ++nt)
#pragma unroll
      for (int rt = 0; rt < 4; ++rt)
        acc[rt][nt] = __builtin_amdgcn_mfma_f32_16x16x32_bf16(afr[rt].v, bfr[nt].v, acc[rt][nt], 0, 0, 0);
  }
  // ---- fp8 pack + transpose + store (wave-private LDS region, no barrier) ----
  int r16 = lane >> 2, seg = lane & 3;
  int qr = r16 >> 2, rr = r16 & 3;
#pragma unroll
  for (int rt = 0; rt < 4; ++rt) {
    if (rt < vt) {
      int tm = rg * 4 + rt;
#pragma unroll
      for (int nt = 0; nt < 4; ++nt) {
        unsigned int dwv = pack4_fp8(acc[rt][nt][0], acc[rt][nt][1], acc[rt][nt][2], acc[rt][nt][3]);
        twave[quad * 72 + nt * 16 + mr] = dwv;   // 2-way bank (free)
      }
      unsigned int out[4];
#pragma unroll
      for (int w = 0; w < 4; ++w) {
        uint4 v = *(const uint4*)&twave[qr * 72 + seg * 16 + 4 * w];
        out[w] = bytesel4(v, rr);
      }
      *(int4*)(C + (size_t)(tm * 16 + r16) * N + tn * 64 + seg * 16) = *(const int4*)out;
    }
  }
  // es/ed — only for the small (CH==16) GEMMs
  if (CH == 16) {
    float ws[4], wd[4];
#pragma unroll
    for (int nt = 0; nt < 4; ++nt) {
      ws[nt] = a_s[(tn * 4 + nt) * 16 + mr];
      wd[nt] = a_d[(tn * 4 + nt) * 16 + mr];
    }
#pragma unroll
    for (int rt = 0; rt < 4; ++rt) {
      if (rt < vt) {
        int tm = rg * 4 + rt;
        float pes[4][4], ped[4][4];
#pragma unroll
        for (int nt = 0; nt < 4; ++nt)
#pragma unroll
          for (int r = 0; r < 4; ++r) { pes[nt][r] = acc[rt][nt][r] * ws[nt]; ped[nt][r] = acc[rt][nt][r] * wd[nt]; }
#pragma unroll
        for (int m = 1; m < 16; m <<= 1)
#pragma unroll
          for (int nt = 0; nt < 4; ++nt)
#pragma unroll
            for (int r = 0; r < 4; ++r) {
              pes[nt][r] += __shfl_xor(pes[nt][r], m);
              ped[nt][r] += __shfl_xor(ped[nt][r], m);
            }
        if (mr == 0) {
#pragma unroll
          for (int nt = 0; nt < 4; ++nt)
#pragma unroll
            for (int r = 0; r < 4; ++r) {
              int row = tm * 16 + quad * 4 + r;
              es[row * 32 + tn * 4 + nt] = pes[nt][r];
              ed[row * 32 + tn * 4 + nt] = ped[nt][r];
            }
        }
      }
    }
  }
}

// ---------- mm1 + mm3 (pure GEMM kernel) ----------
struct MMDesc {
  const unsigned short* Ap;
  const unsigned short* B1; const unsigned short* B3;
  unsigned char* C1; unsigned char* C3;
  int mmblks, mt;
};
__global__ __launch_bounds__(256) void k_mm13(MMDesc d) {
  __shared__ unsigned int tile[4 * TILE_DW];
  int b = blockIdx.x;
  if (b < d.mmblks) {
    mm_es64_body<64,4>(b >> 3, b & 7, d.mt, d.Ap, d.B1, d.C1, nullptr, nullptr, nullptr, nullptr, 2048, tile);
    return;
  }
  b -= d.mmblks;
  mm_es64_body<64,4>(b >> 3, b & 7, d.mt, d.Ap, d.B3, d.C3, nullptr, nullptr, nullptr, nullptr, 2048, tile);
}

// ---------- merged gather64, both flows; ONE WAVE per node ----------
__global__ __launch_bounds__(256) void k_g64(const unsigned char* __restrict__ h1,
                                             const unsigned char* __restrict__ h3,
                                             const float* __restrict__ es1, const float* __restrict__ ed1,
                                             const float* __restrict__ es3, const float* __restrict__ ed3,
                                             const int* __restrict__ rowA, const int* __restrict__ colA,
                                             const int* __restrict__ rowB, const int* __restrict__ colB,
                                             const float* __restrict__ b1, const float* __restrict__ b3,
                                             unsigned short* __restrict__ xsp, unsigned short* __restrict__ xtp,
                                             int n, int gb) {
  int b = blockIdx.x;
  const unsigned char* h; const float *es, *ed, *bias; const int *rowp, *col; unsigned short* outp;
  if (b < gb) { h = h1; es = es1; ed = ed1; rowp = rowA; col = colA; bias = b1; outp = xsp; }
  else { b -= gb; h = h3; es = es3; ed = ed3; rowp = rowB; col = colB; bias = b3; outp = xtp; }
  int wid = threadIdx.x >> 6, lane = threadIdx.x & 63;
  int i = b * 4 + wid;
  if (i >= n) return;
  int hd0 = lane >> 2, hd1 = 16 + hd0;
  float e0 = ed[i * 32 + hd0];
  float e1 = ed[i * 32 + hd1];
  int beg = rowp[i], end = rowp[i + 1];
  int deg = end - beg;                    // >= 1 (self-loop)
  int colv = (lane < deg) ? col[beg + lane] : 0;
  f32x2 acc0[8], acc1[8];
#pragma unroll
  for (int k = 0; k < 8; ++k) { acc0[k] = (f32x2){0.f, 0.f}; acc1[k] = (f32x2){0.f, 0.f}; }
  float Z0 = 0.f, Z1 = 0.f;
  // prologue: fetch edge 0
  int s0 = __shfl(colv, 0);
  const int4* hp0 = (const int4*)(h + (size_t)s0 * 2048);
  int4 ng0 = hp0[lane];
  int4 ng1 = hp0[64 + lane];
  float na = es[s0 * 32 + hd0];
  float nb = es[s0 * 32 + hd1];
  for (int j = 0; j < deg; ++j) {
    int4 g0 = ng0, g1 = ng1;
    float ea = na, eb = nb;
    int jn = j + 1;
    if (jn < deg) {                       // wave-uniform branch
      int sn = (jn < 64) ? __shfl(colv, jn) : col[beg + jn];
      const int4* hq = (const int4*)(h + (size_t)sn * 2048);
      ng0 = hq[lane];
      ng1 = hq[64 + lane];
      na = es[sn * 32 + hd0];
      nb = es[sn * 32 + hd1];
    }
    float q0 = __expf(lrelu_clamp(ea + e0));
    float q1 = __expf(lrelu_clamp(eb + e1));
    Z0 += q0; Z1 += q1;
    f32x2 d0[8], d1[8];
    dec16p(g0, d0); dec16p(g1, d1);
    f32x2 q0v = (f32x2){q0, q0}, q1v = (f32x2){q1, q1};
#pragma unroll
    for (int k = 0; k < 8; ++k) {
      acc0[k] = __builtin_elementwise_fma(q0v, d0[k], acc0[k]);
      acc1[k] = __builtin_elementwise_fma(q1v, d1[k], acc1[k]);
    }
  }
  float zi0 = 1.0f / Z0, zi1 = 1.0f / Z1;
  f32x2 zi0v = (f32x2){zi0, zi0}, zi1v = (f32x2){zi1, zi1};
  f32x2 v2[8];
#pragma unroll
  for (int k = 0; k < 8; ++k)
    v2[k] = __builtin_elementwise_fma(acc1[k], zi1v, acc0[k] * zi0v);
#pragma unroll
  for (int m = 4; m < 64; m <<= 1)
#pragma unroll
    for (int k = 0; k < 8; ++k) {
      v2[k].x += __shfl_xor(v2[k].x, m);
      v2[k].y += __shfl_xor(v2[k].y, m);
    }
  if (lane < 4) {
    float v[16];
#pragma unroll
    for (int k = 0; k < 8; ++k) { v[2 * k] = v2[k].x; v[2 * k + 1] = v2[k].y; }
    int tm = i >> 4, mr = i & 15;
    unsigned short ob[16];
#pragma unroll
    for (int k = 0; k < 16; ++k) {
      float t = v[k] * (1.f / 32.f) + bias[lane * 16 + k];
      t = (t > 0.f) ? t : (__expf(t) - 1.f);   // elu
      ob[k] = f2bf(t);
    }
    int s0w = lane >> 1;
#pragma unroll
    for (int g2 = 0; g2 < 2; ++g2) {
      size_t idx = (((size_t)tm * 2 + s0w) * 64 + ((lane & 1) * 2 + g2) * 16 + mr) * 8;
      *(int4*)(outp + idx) = *(const int4*)(ob + g2 * 8);  // packed-A bf16
    }
  }
}

// ---------- merged mm2 + mm4 (es/ed kept in-body) ----------
__global__ __launch_bounds__(256) void k_mm24(const unsigned short* __restrict__ xsp,
                                              const unsigned short* __restrict__ xtp,
                                              const unsigned short* __restrict__ W2p,
                                              const unsigned short* __restrict__ W4p,
                                              unsigned char* __restrict__ h2, unsigned char* __restrict__ h4,
                                              const float* __restrict__ as2, const float* __restrict__ ad2,
                                              const float* __restrict__ as4, const float* __restrict__ ad4,
                                              float* __restrict__ es2, float* __restrict__ ed2,
                                              float* __restrict__ es4, float* __restrict__ ed4,
                                              int mmblks, int mt) {
  __shared__ unsigned int tile[4 * TILE_DW];
  int b = blockIdx.x;
  if (b < mmblks)  // rg = b/2, cg = b%2 (N=512 -> 2 col groups of 256)
    mm_es64_body<16,2>(b >> 1, b & 1, mt, xsp, W2p, h2, as2, ad2, es2, ed2, 512, tile);
  else {
    b -= mmblks;
    mm_es64_body<16,2>(b >> 1, b & 1, mt, xtp, W4p, h4, as4, ad4, es4, ed4, 512, tile);
  }
}

// ---------- merged gather16, both flows; ONE WAVE per node -> final outputs ----------
__global__ __launch_bounds__(256) void k_g16(const unsigned char* __restrict__ h2,
                                             const unsigned char* __restrict__ h4,
                                             const float* __restrict__ es2, const float* __restrict__ ed2,
                                             const float* __restrict__ es4, const float* __restrict__ ed4,
                                             const int* __restrict__ rowA, const int* __restrict__ colA,
                                             const int* __restrict__ rowB, const int* __restrict__ colB,
                                             const float* __restrict__ b2, const float* __restrict__ b4,
                                             void* __restrict__ outbase, int n, int gb,
                                             const int* __restrict__ flag) {
  int b = blockIdx.x;
  const unsigned char* h; const float *es, *ed, *bias; const int *rowp, *col; size_t eoff;
  if (b < gb) { h = h2; es = es2; ed = ed2; rowp = rowA; col = colA; bias = b2; eoff = 0; }
  else { b -= gb; h = h4; es = es4; ed = ed4; rowp = rowB; col = colB; bias = b4; eoff = (size_t)n * 16; }
  int wid = threadIdx.x >> 6, lane = threadIdx.x & 63;
  int i = b * 4 + wid;
  if (i >= n) return;
  int hh = lane & 31, j2 = lane >> 5;
  float ev = ed[i * 32 + hh];
  int beg = rowp[i], end = rowp[i + 1];
  int deg = end - beg;
  int colv = (lane < deg) ? col[beg + lane] : 0;
  f32x2 acc[8];
#pragma unroll
  for (int k = 0; k < 8; ++k) acc[k] = (f32x2){0.f, 0.f};
  float Z = 0.f;
  int j = j2;
  int4 ng = (int4){0, 0, 0, 0};
  float ne = 0.f;
  if (j < deg) {
    int s = __shfl(colv, j);
    ng = ((const int4*)(h + (size_t)s * 512))[hh];
    ne = es[s * 32 + hh];
  }
  for (; j < deg; j += 2) {
    int4 g = ng; float ee = ne;
    int jn = j + 2;
    if (jn < deg) {
      int sn = (jn < 64) ? __shfl(colv, jn) : col[beg + jn];
      ng = ((const int4*)(h + (size_t)sn * 512))[hh];
      ne = es[sn * 32 + hh];
    }
    float q = __expf(lrelu_clamp(ee + ev));
    Z += q;
    f32x2 d[8];
    dec16p(g, d);
    f32x2 qv = (f32x2){q, q};
#pragma unroll
    for (int k = 0; k < 8; ++k) acc[k] = __builtin_elementwise_fma(qv, d[k], acc[k]);
  }
  Z += __shfl_xor(Z, 32);
  float zi = 1.0f / Z;
  f32x2 ziv = (f32x2){zi, zi};
  f32x2 v2[8];
#pragma unroll
  for (int k = 0; k < 8; ++k) v2[k] = acc[k] * ziv;
#pragma unroll
  for (int m = 1; m < 64; m <<= 1)
#pragma unroll
    for (int k = 0; k < 8; ++k) {
      v2[k].x += __shfl_xor(v2[k].x, m);
      v2[k].y += __shfl_xor(v2[k].y, m);
    }
  if (lane == 0) {
    float v[16];
#pragma unroll
    for (int k = 0; k < 8; ++k) { v[2 * k] = v2[k].x; v[2 * k + 1] = v2[k].y; }
    int isbf = *flag;
    if (isbf) {
      unsigned short ob[16];
#pragma unroll
      for (int k = 0; k < 16; ++k) {
        float t = v[k] * (1.f / 32.f) + bias[k];
        t = (t > 0.f) ? t : (__expf(t) - 1.f);
        ob[k] = f2bf(t);
      }
      unsigned short* o = (unsigned short*)outbase + eoff + (size_t)i * 16;
      *(int4*)o = *(const int4*)ob;
      *(int4*)(o + 8) = *(const int4*)(ob + 8);
    } else {
      float* o = (float*)outbase + eoff + (size_t)i * 16;
#pragma unroll
      for (int k = 0; k < 16; ++k) {
        float t = v[k] * (1.f / 32.f) + bias[k];
        t = (t > 0.f) ? t : (__expf(t) - 1.f);
        o[k] = t;
      }
    }
  }
}

extern "C" void kernel_launch(void* const* d_in, const int* in_sizes, int n_in,
                              void* d_out, int out_size, void* d_ws, size_t ws_size,
                              hipStream_t stream) {
  const int n = in_sizes[0] / 128;   // 10000
  const int E = in_sizes[1] / 2;     // 80000
  const int* ei = (const int*)d_in[1];

  char* wsp = (char*)d_ws; size_t off = 0;
  auto alloc = [&](size_t bytes) -> void* {
    void* p = wsp + off; off = (off + bytes + 255) & ~(size_t)255; return p;
  };
  int* flag = (int*)alloc(4);
  float* xc = (float*)alloc((size_t)n * 128 * 4);
  unsigned short* xp = (unsigned short*)alloc((size_t)n * 128 * 2);
  unsigned short* W1p = (unsigned short*)alloc((size_t)2048 * 128 * 2);
  unsigned short* W2p = (unsigned short*)alloc((size_t)512 * 64 * 2);
  unsigned short* W3p = (unsigned short*)alloc((size_t)2048 * 128 * 2);
  unsigned short* W4p = (unsigned short*)alloc((size_t)512 * 64 * 2);
  unsigned char* h1 = (unsigned char*)alloc((size_t)n * 2048);   // fp8
  unsigned char* h3 = (unsigned char*)alloc((size_t)n * 2048);
  unsigned char* h2 = (unsigned char*)alloc((size_t)n * 512);
  unsigned char* h4 = (unsigned char*)alloc((size_t)n * 512);
  float* es1 = (float*)alloc((size_t)n * 32 * 4);
  float* ed1 = (float*)alloc((size_t)n * 32 * 4);
  float* es3 = (float*)alloc((size_t)n * 32 * 4);
  float* ed3 = (float*)alloc((size_t)n * 32 * 4);
  float* es2 = (float*)alloc((size_t)n * 32 * 4);
  float* ed2 = (float*)alloc((size_t)n * 32 * 4);
  float* es4 = (float*)alloc((size_t)n * 32 * 4);
  float* ed4 = (float*)alloc((size_t)n * 32 * 4);
  unsigned short* xsp = (unsigned short*)alloc((size_t)n * 64 * 2);
  unsigned short* xtp = (unsigned short*)alloc((size_t)n * 64 * 2);
  int* rowA = (int*)alloc((size_t)(n + 1) * 4);
  int* rowB = (int*)alloc((size_t)(n + 1) * 4);
  int* colA = (int*)alloc((size_t)(E + n) * 4);
  int* colB = (int*)alloc((size_t)(E + n) * 4);
  int* degAB = (int*)alloc((size_t)2 * n * 4);
  int* degA = degAB, * degB = degAB + n;
  int* curA = (int*)alloc((size_t)n * 4);
  int* curB = (int*)alloc((size_t)n * 4);
  float* was1 = (float*)alloc((size_t)128 * 32 * 4);
  float* wad1 = (float*)alloc((size_t)128 * 32 * 4);
  float* was3 = (float*)alloc((size_t)128 * 32 * 4);
  float* wad3 = (float*)alloc((size_t)128 * 32 * 4);

  static const int cidx[32] = {3,4,5, 7,8,9, 11,12,13, 15,16,17,
                               18,19,20,21,22,23,24,25,26,27,28,29,
                               30,31,32,33,34,35,36,37};
  PrepDesc pd;
  float* canon[38] = {nullptr};
  pd.ctotal = 0;
  for (int t = 0; t < 32; ++t) {
    int ii = cidx[t];
    canon[ii] = (float*)alloc((size_t)in_sizes[ii] * 4);
    pd.csrc[t] = d_in[ii];
    pd.cdst[t] = canon[ii];
    pd.cn[t] = in_sizes[ii];
    pd.ctotal += in_sizes[ii];
  }
  pd.x = d_in[0]; pd.xc = xc; pd.xp = xp;
  pd.W1 = d_in[2]; pd.W2 = d_in[6]; pd.W3 = d_in[10]; pd.W4 = d_in[14];
  pd.P1 = W1p; pd.P2 = W2p; pd.P3 = W3p; pd.P4 = W4p;
  pd.degAB = degAB;
  pd.ei = ei;
  pd.av[0] = d_in[3]; pd.av[1] = d_in[4]; pd.av[2] = d_in[11]; pd.av[3] = d_in[12];
  pd.wa[0] = was1; pd.wa[1] = wad1; pd.wa[2] = was3; pd.wa[3] = wad3;
  pd.nxb = (n * 128 / 8 + 255) / 256;   // vectorized 8/thread
  pd.xtotal = n * 128;
  pd.E = E;
  pd.nn = n;
  (void)ws_size; (void)n_in; (void)out_size;

  const int degblks = (E + 255) / 256;  // 313

  // ---- detect + zero degAB (merged) ----
  k_detect<<<9, 256, 0, stream>>>((const unsigned int*)d_in[0], flag, degAB, 2 * n);
  // ---- unified prep + degree count + Wa fold (merged) ----
  k_prep<<<pd.nxb + 288 + 4 + degblks + 4, 256, 0, stream>>>(pd, flag);
  // ---- CSR scan (both flows) ----
  k_exscan2<<<2, 1024, 0, stream>>>(degA, degB, rowA, rowB, colA, colB, curA, curB, n);

  const int mt = n / 16;              // 625
  const int nrg = (mt + 3) / 4;       // 157 row-groups of 64 rows
  const int mmblks64 = nrg * 8;       // per GEMM (N=2048 -> 8 col groups)
  const int mmblks16 = nrg * 2;       // per GEMM (N=512  -> 2 col groups)
  const int gb = (n + 3) / 4;         // 2500

  // ---- stage 1a: residual + es/ed GEMV + scatter ----
  AuxDesc ad;
  ad.resblks = mt; ad.E = E;
  ad.ei = ei; ad.colA = colA; ad.colB = colB; ad.curA = curA; ad.curB = curB;
  ad.xc = xc;
  for (int t = 0; t < 20; ++t) ad.rp[t] = canon[18 + t];
  ad.wa[0] = was1; ad.wa[1] = wad1; ad.wa[2] = was3; ad.wa[3] = wad3;
  ad.es1 = es1; ad.ed1 = ed1; ad.es3 = es3; ad.ed3 = ed3;
  ad.outbase = d_out; ad.eoff = (size_t)2 * n * 16; ad.n = n; ad.flag = flag;
  k_aux<<<mt + degblks, 256, 0, stream>>>(ad);

  // ---- stage 1b: mm1 + mm3 (pure GEMM) ----
  MMDesc md;
  md.Ap = xp; md.B1 = W1p; md.B3 = W3p; md.C1 = h1; md.C3 = h3;
  md.mmblks = mmblks64; md.mt = mt;
  k_mm13<<<2 * mmblks64, 256, 0, stream>>>(md);

  // ---- stage 2: gather64 both flows ----
  k_g64<<<2 * gb, 256, 0, stream>>>(h1, h3, es1, ed1, es3, ed3,
                                    rowA, colA, rowB, colB,
                                    canon[5], canon[13], xsp, xtp, n, gb);
  // ---- stage 3: mm2 + mm4 ----
  k_mm24<<<2 * mmblks16, 256, 0, stream>>>(xsp, xtp, W2p, W4p, h2, h4,
                                           canon[7], canon[8], canon[15], canon[16],
                                           es2, ed2, es4, ed4, mmblks16, mt);
  // ---- stage 4: gather16 both flows -> outputs 0,1 ----
  k_g16<<<2 * gb, 256, 0, stream>>>(h2, h4, es2, ed2, es4, ed4,
                                    rowA, colA, rowB, colB,
                                    canon[9], canon[17], d_out, n, gb, flag);
}

// Round 8
// 324.770 us; speedup vs baseline: 1.4243x; 1.4243x over previous
//
#include <hip/hip_runtime.h>
#include <stdint.h>

// ---------- bf16 helpers ----------
__device__ __forceinline__ float bf2f(unsigned short u) {
  union { unsigned int i; float f; } v; v.i = ((unsigned int)u) << 16; return v.f;
}
__device__ __forceinline__ unsigned short f2bf(float f) {
  union { float f; unsigned int i; } v; v.f = f;
  unsigned int i = v.i;
  unsigned int r = (i + 0x7fffu + ((i >> 16) & 1u)) >> 16;  // RNE
  return (unsigned short)r;
}

typedef __bf16 bf16x8 __attribute__((ext_vector_type(8)));
typedef float f32x4 __attribute__((ext_vector_type(4)));
typedef float f32x2 __attribute__((ext_vector_type(2)));
union ABfrag { int4 i4; bf16x8 v; };

// ---------- fp8 e4m3fn (OCP): HW path on gfx950, SW fallback ----------
#if __has_builtin(__builtin_amdgcn_cvt_pk_fp8_f32) && __has_builtin(__builtin_amdgcn_cvt_pk_f32_fp8)
#define HW_FP8 1
#else
#define HW_FP8 0
#endif

__device__ __forceinline__ unsigned char f2fp8_sw(float f) {
  union { float f; unsigned int u; } v; v.f = f;
  unsigned int s = (v.u >> 24) & 0x80;
  float a = fabsf(f);
  if (a >= 448.f) return (unsigned char)(s | 0x7E);
  v.f = a;
  int ex = (int)(v.u >> 23);
  unsigned int man = v.u & 0x7FFFFFu;
  if (ex >= 121) {
    unsigned int val = ((unsigned int)(ex - 120) << 3) | (man >> 20);
    unsigned int rem = man & 0xFFFFFu;
    if (rem > 0x80000u || (rem == 0x80000u && (val & 1))) val++;
    if (val > 0x7E) val = 0x7E;
    return (unsigned char)(s | val);
  }
  int q = (int)(a * 512.f + 0.5f);
  if (q > 8) q = 8;
  return (unsigned char)(s | (unsigned int)q);
}
__device__ __forceinline__ float fp8dec_sw(unsigned char c) {
  unsigned int e = (c >> 3) & 15u, m = c & 7u;
  float v;
  if (e) { union { unsigned int u; float f; } x; x.u = ((e + 120) << 23) | (m << 20); v = x.f; }
  else v = (float)m * 0.001953125f;
  return (c & 0x80) ? -v : v;
}
// pack 4 floats -> 4 fp8 bytes in one dword (bytes 0..3 = a0..a3)
__device__ __forceinline__ unsigned int pack4_fp8(float a0, float a1, float a2, float a3) {
#if HW_FP8
  int dw = __builtin_amdgcn_cvt_pk_fp8_f32(a0, a1, 0, false);
  dw = __builtin_amdgcn_cvt_pk_fp8_f32(a2, a3, dw, true);
  return (unsigned int)dw;
#else
  return (unsigned)f2fp8_sw(a0) | ((unsigned)f2fp8_sw(a1) << 8) |
         ((unsigned)f2fp8_sw(a2) << 16) | ((unsigned)f2fp8_sw(a3) << 24);
#endif
}
// select byte rr from each of 4 dwords -> one dword
__device__ __forceinline__ unsigned int bytesel4(uint4 v, int rr) {
#if __has_builtin(__builtin_amdgcn_perm)
  unsigned s = (unsigned)rr | ((unsigned)(rr + 4) << 8);
  unsigned p01 = __builtin_amdgcn_perm(v.y, v.x, s);          // [x[rr], y[rr], ..]
  unsigned p23 = __builtin_amdgcn_perm(v.w, v.z, s);          // [z[rr], w[rr], ..]
  return __builtin_amdgcn_perm(p23, p01, 0x05040100u);        // [x,y,z,w][rr]
#else
  int sh = rr * 8;
  return ((v.x >> sh) & 0xFFu) | (((v.y >> sh) & 0xFFu) << 8) |
         (((v.z >> sh) & 0xFFu) << 16) | (((v.w >> sh) & 0xFFu) << 24);
#endif
}
// decode 16 fp8 -> 8 packed float2 (keeps cvt_pk's natural pair output)
__device__ __forceinline__ void dec16p(int4 g, f32x2 o[8]) {
#if HW_FP8
  o[0] = __builtin_amdgcn_cvt_pk_f32_fp8(g.x, false);
  o[1] = __builtin_amdgcn_cvt_pk_f32_fp8(g.x, true);
  o[2] = __builtin_amdgcn_cvt_pk_f32_fp8(g.y, false);
  o[3] = __builtin_amdgcn_cvt_pk_f32_fp8(g.y, true);
  o[4] = __builtin_amdgcn_cvt_pk_f32_fp8(g.z, false);
  o[5] = __builtin_amdgcn_cvt_pk_f32_fp8(g.z, true);
  o[6] = __builtin_amdgcn_cvt_pk_f32_fp8(g.w, false);
  o[7] = __builtin_amdgcn_cvt_pk_f32_fp8(g.w, true);
#else
  unsigned int w[4] = {(unsigned)g.x, (unsigned)g.y, (unsigned)g.z, (unsigned)g.w};
#pragma unroll
  for (int d = 0; d < 4; ++d) {
    unsigned int x = w[d];
    o[d * 2 + 0] = (f32x2){fp8dec_sw((unsigned char)(x & 0xFF)),
                           fp8dec_sw((unsigned char)((x >> 8) & 0xFF))};
    o[d * 2 + 1] = (f32x2){fp8dec_sw((unsigned char)((x >> 16) & 0xFF)),
                           fp8dec_sw((unsigned char)((x >> 24) & 0xFF))};
  }
#endif
}

__device__ __forceinline__ float lrelu_clamp(float e) {
  e = (e > 0.f) ? e : 0.2f * e;
  return fminf(e, 80.f);
}

// ---------- dtype detection + degAB zeroing (merged) ----------
__global__ __launch_bounds__(256) void k_detect(const unsigned int* __restrict__ x, int* flag,
                                                int* __restrict__ degAB, int ndeg2) {
  if (blockIdx.x == 0) {
    __shared__ int cnt;
    if (threadIdx.x == 0) cnt = 0;
    __syncthreads();
    int c = 0;
    for (int i = threadIdx.x; i < 1024; i += 256) {
      unsigned int lo = x[i] & 0xFFFFu;
      int ex = (int)((lo >> 7) & 0xFF);
      if (ex >= 100 && ex <= 140) c++;
    }
    atomicAdd(&cnt, c);
    __syncthreads();
    if (threadIdx.x == 0) flag[0] = (cnt > 600) ? 1 : 0;  // 1 = bf16 inputs
    return;
  }
  for (int idx = (blockIdx.x - 1) * 256 + threadIdx.x; idx < ndeg2; idx += 8 * 256) degAB[idx] = 0;
}

// ---------- unified prep (+ degree count + attention-weight fold v2) ----------
// Wa fold: es1 = (X@W1)@as1^T(per-head) == X @ Was1 with
// Was1[k][h] = sum_c W1[k, h*64+c] * as1[h, c].
// v2: 64 blocks, one (k,h) output per thread, vectorized 64-elem dot
// (v1's 4-block serial version was a 158us tail — round-7 lesson).
struct PrepDesc {
  const void* csrc[32]; float* cdst[32]; int cn[32];
  const void* x; float* xc; unsigned short* xp;
  const void* W1; const void* W2; const void* W3; const void* W4;
  unsigned short* P1; unsigned short* P2; unsigned short* P3; unsigned short* P4;
  int* degAB;
  const int* ei;
  const void* av[4];   // as1, ad1, as3, ad3 (raw inputs)
  float* wa[4];        // Was1, Wad1, Was3, Wad3 [128x32]
  int nxb, xtotal, ctotal, E, nn;
};
__global__ __launch_bounds__(256) void k_prep(PrepDesc d, const int* __restrict__ flag) {
  int isbf = *flag;
  int b = blockIdx.x;
  if (b < d.nxb) {
    // vectorized: 8 elements per thread
    int t8 = b * 256 + threadIdx.x;
    int i8 = t8 * 8;
    if (i8 < d.xtotal) {
      float v[8];
      if (isbf) {
        int4 raw = *(const int4*)((const unsigned short*)d.x + i8);
        const unsigned short* u = (const unsigned short*)&raw;
#pragma unroll
        for (int j = 0; j < 8; ++j) v[j] = bf2f(u[j]);
      } else {
        float4 f0 = *(const float4*)((const float*)d.x + i8);
        float4 f1 = *(const float4*)((const float*)d.x + i8 + 4);
        v[0] = f0.x; v[1] = f0.y; v[2] = f0.z; v[3] = f0.w;
        v[4] = f1.x; v[5] = f1.y; v[6] = f1.z; v[7] = f1.w;
      }
      *(float4*)(d.xc + i8)     = (float4){v[0], v[1], v[2], v[3]};
      *(float4*)(d.xc + i8 + 4) = (float4){v[4], v[5], v[6], v[7]};
      int row = i8 >> 7, c0 = i8 & 127;
      int tm = row >> 4, mr = row & 15;
      int s = c0 >> 5, quad = (c0 >> 3) & 3;
      unsigned short o[8];
#pragma unroll
      for (int j = 0; j < 8; ++j) o[j] = f2bf(v[j]);
      size_t idx = (((size_t)tm * 4 + s) * 64 + quad * 16 + mr) * 8;
      *(int4*)(d.xp + idx) = *(const int4*)o;
    }
    return;
  }
  b -= d.nxb;
  if (b < 288) {
    int u = b * 256 + threadIdx.x;
    const void* W; unsigned short* P; int K, N, lu;
    if (u < 32768)      { W = d.W1; P = d.P1; K = 128; N = 2048; lu = u; }
    else if (u < 36864) { W = d.W2; P = d.P2; K = 64;  N = 512;  lu = u - 32768; }
    else if (u < 69632) { W = d.W3; P = d.P3; K = 128; N = 2048; lu = u - 36864; }
    else                { W = d.W4; P = d.P4; K = 64;  N = 512;  lu = u - 69632; }
    int ksteps = K >> 5;
    int g = lu / (ksteps * 64);
    int rem = lu - g * (ksteps * 64);
    int s = rem >> 6, lane = rem & 63;
    int mr = lane & 15, quad = lane >> 4;
    int col = g * 16 + mr;
    int kbase = s * 32 + quad * 8;
#pragma unroll
    for (int j = 0; j < 8; ++j) {
      size_t src = (size_t)(kbase + j) * N + col;
      float v = isbf ? bf2f(((const unsigned short*)W)[src]) : ((const float*)W)[src];
      P[(size_t)lu * 8 + j] = f2bf(v);
    }
    return;
  }
  b -= 288;
  if (b < 4) {
    for (int idx = b * 256 + threadIdx.x; idx < d.ctotal; idx += 4 * 256) {
      int t = 0, off = idx;
      while (off >= d.cn[t]) { off -= d.cn[t]; ++t; }
      float v = isbf ? bf2f(((const unsigned short*)d.csrc[t])[off])
                     : ((const float*)d.csrc[t])[off];
      d.cdst[t][off] = v;
    }
    return;
  }
  b -= 4;
  {
    int degblks = (d.E + 255) >> 8;
    if (b < degblks) {  // degree count (degAB zeroed by k_detect)
      int e = b * 256 + threadIdx.x;
      if (e < d.E) {
        atomicAdd(&d.degAB[d.ei[d.E + e]], 1);
        atomicAdd(&d.degAB[d.nn + d.ei[e]], 1);
      }
      return;
    }
    b -= degblks;
  }
  {  // Wa fold v2: b in [0,64): matrix m = b>>4, k-block = b&15
    int m = b >> 4, kb = b & 15;
    const void* W = (m < 2) ? d.W1 : d.W3;
    const void* A = d.av[m];
    float* out = d.wa[m];
    int k = kb * 8 + (threadIdx.x >> 5);   // 8 k per block
    int h = threadIdx.x & 31;              // 32 heads
    size_t wbase = (size_t)k * 2048 + h * 64;
    size_t abase = (size_t)h * 64;
    float acc = 0.f;
    if (isbf) {
      const unsigned short* Wb = (const unsigned short*)W;
      const unsigned short* Ab = (const unsigned short*)A;
#pragma unroll
      for (int v8 = 0; v8 < 8; ++v8) {
        int4 wv = *(const int4*)(Wb + wbase + v8 * 8);
        int4 av = *(const int4*)(Ab + abase + v8 * 8);
        const unsigned short* wu = (const unsigned short*)&wv;
        const unsigned short* au = (const unsigned short*)&av;
#pragma unroll
        for (int j = 0; j < 8; ++j) acc += bf2f(wu[j]) * bf2f(au[j]);
      }
    } else {
      const float* Wf = (const float*)W;
      const float* Af = (const float*)A;
#pragma unroll
      for (int v4 = 0; v4 < 16; ++v4) {
        float4 wv = *(const float4*)(Wf + wbase + v4 * 4);
        float4 av = *(const float4*)(Af + abase + v4 * 4);
        acc += wv.x * av.x + wv.y * av.y + wv.z * av.z + wv.w * av.w;
      }
    }
    out[k * 32 + h] = acc;
  }
}

// ---------- CSR exclusive scan ----------
__global__ __launch_bounds__(1024) void k_exscan2(const int* __restrict__ degA, const int* __restrict__ degB,
                                                  int* __restrict__ rowA, int* __restrict__ rowB,
                                                  int* __restrict__ colA, int* __restrict__ colB,
                                                  int* __restrict__ curA, int* __restrict__ curB, int n) {
  const int* deg = (blockIdx.x == 0) ? degA : degB;
  int* row = (blockIdx.x == 0) ? rowA : rowB;
  int* colx = (blockIdx.x == 0) ? colA : colB;
  int* curx = (blockIdx.x == 0) ? curA : curB;
  __shared__ int wsum[16], wbase[16];
  __shared__ int carry;
  if (threadIdx.x == 0) carry = 0;
  __syncthreads();
  int lane = threadIdx.x & 63, w = threadIdx.x >> 6;
  int chunks = (n + 1023) >> 10;
  for (int ch = 0; ch < chunks; ++ch) {
    int i = (ch << 10) + threadIdx.x;
    int v = (i < n) ? deg[i] : 0;
    int sc = v;
#pragma unroll
    for (int o = 1; o < 64; o <<= 1) { int t = __shfl_up(sc, o); if (lane >= o) sc += t; }
    if (lane == 63) wsum[w] = sc;
    __syncthreads();
    if (threadIdx.x < 16) {
      int v2 = wsum[threadIdx.x], s2 = v2;
#pragma unroll
      for (int o = 1; o < 16; o <<= 1) { int t = __shfl_up(s2, o); if (lane >= o) s2 += t; }
      wbase[threadIdx.x] = s2 - v2;
      if (threadIdx.x == 15) wsum[15] = s2;
    }
    __syncthreads();
    if (i < n) {
      int rv = carry + wbase[w] + (sc - v) + i;
      row[i] = rv;
      colx[rv] = i;
      curx[i] = rv + 1;
    }
    __syncthreads();
    if (threadIdx.x == 0) carry += wsum[15];
    __syncthreads();
  }
  if (threadIdx.x == 0) row[n] = carry + n;
}

// ---------- aux: residual MLP + es/ed GEMV + CSR scatter ----------
struct AuxDesc {
  int resblks, E;
  const int* ei; int* colA; int* colB; int* curA; int* curB;
  const float* xc;
  const float* rp[20];
  const float* wa[4];                 // Was1, Wad1, Was3, Wad3 [128x32]
  float* es1; float* ed1; float* es3; float* ed3;
  void* outbase; size_t eoff; int n;
  const int* flag;
};
__global__ __launch_bounds__(256) void k_aux(AuxDesc d) {
  __shared__ struct { float xs[16][128]; float ha[16][16]; float tt[16][16]; } sm;
  int b = blockIdx.x;
  if (b < d.resblks) {
    int nodebase = b * 16;
    for (int t = threadIdx.x; t < 16 * 128; t += 256)
      sm.xs[t >> 7][t & 127] = d.xc[(size_t)(nodebase + (t >> 7)) * 128 + (t & 127)];
    __syncthreads();
    int ni = threadIdx.x >> 4, c = threadIdx.x & 15;
    // ---- es/ed GEMV: es1/ed1/es3/ed3 [16 nodes x 32 heads] ----
    {
      const float* w0 = d.wa[0]; const float* w1 = d.wa[1];
      const float* w2 = d.wa[2]; const float* w3 = d.wa[3];
      float a0 = 0.f, a1 = 0.f, a2 = 0.f, a3 = 0.f, a4 = 0.f, a5 = 0.f, a6 = 0.f, a7 = 0.f;
#pragma unroll 4
      for (int k = 0; k < 128; ++k) {
        float xv = sm.xs[ni][k];
        int o = k * 32 + c;
        a0 += xv * w0[o]; a1 += xv * w0[o + 16];
        a2 += xv * w1[o]; a3 += xv * w1[o + 16];
        a4 += xv * w2[o]; a5 += xv * w2[o + 16];
        a6 += xv * w3[o]; a7 += xv * w3[o + 16];
      }
      int row = nodebase + ni;
      d.es1[row * 32 + c] = a0; d.es1[row * 32 + c + 16] = a1;
      d.ed1[row * 32 + c] = a2; d.ed1[row * 32 + c + 16] = a3;
      d.es3[row * 32 + c] = a4; d.es3[row * 32 + c + 16] = a5;
      d.ed3[row * 32 + c] = a6; d.ed3[row * 32 + c + 16] = a7;
    }
    // ---- residual MLP ----
    const float* rwa = d.rp[0]; const float* rba = d.rp[1];
    const float* bn1g = d.rp[2]; const float* bn1b = d.rp[3];
    const float* bn1m = d.rp[4]; const float* bn1v = d.rp[5];
    const float* rwb = d.rp[6]; const float* rbb = d.rp[7];
    const float* bn2g = d.rp[8]; const float* bn2b = d.rp[9];
    const float* bn2m = d.rp[10]; const float* bn2v = d.rp[11];
    const float* wsc = d.rp[12]; const float* bsc = d.rp[13];
    const float* bnsg = d.rp[14]; const float* bnsb = d.rp[15];
    const float* bnsm = d.rp[16]; const float* bnsv = d.rp[17];
    const float* wfc = d.rp[18]; const float* bfc = d.rp[19];
    float ya = 0.f, ysc = 0.f;
#pragma unroll 8
    for (int k = 0; k < 128; ++k) {
      float xv = sm.xs[ni][k];
      ya  += xv * rwa[k * 16 + c];
      ysc += xv * wsc[k * 16 + c];
    }
    ya += rba[c]; ysc += bsc[c];
    float s1 = bn1g[c] * rsqrtf(bn1v[c] + 1e-5f);
    ya = (ya - bn1m[c]) * s1 + bn1b[c];
    ya = fmaxf(ya, 0.f);
    float ss = bnsg[c] * rsqrtf(bnsv[c] + 1e-5f);
    ysc = (ysc - bnsm[c]) * ss + bnsb[c];
    sm.ha[ni][c] = ya;
    __syncthreads();
    float h2 = rbb[c];
#pragma unroll
    for (int k = 0; k < 16; ++k) h2 += sm.ha[ni][k] * rwb[k * 16 + c];
    float s2 = bn2g[c] * rsqrtf(bn2v[c] + 1e-5f);
    h2 = (h2 - bn2m[c]) * s2 + bn2b[c];
    sm.tt[ni][c] = fmaxf(h2 + ysc, 0.f);
    __syncthreads();
    float o = bfc[c];
#pragma unroll
    for (int k = 0; k < 16; ++k) o += sm.tt[ni][k] * wfc[k * 16 + c];
    size_t oo = d.eoff + (size_t)(nodebase + ni) * 16 + c;
    if (*d.flag) ((unsigned short*)d.outbase)[oo] = f2bf(o);
    else         ((float*)d.outbase)[oo] = o;
    return;
  }
  b -= d.resblks;
  {  // CSR scatter
    int e = b * 256 + threadIdx.x;
    if (e < d.E) {
      int s = d.ei[e], dd = d.ei[d.E + e];
      d.colA[atomicAdd(&d.curA[dd], 1)] = s;
      d.colB[atomicAdd(&d.curB[s], 1)] = dd;
    }
  }
}

// ---------- 64-row x 64-col per-wave GEMM body ----------
// CH==64 (mm1/mm3): PURE GEMM + fp8 pack/store — es/ed moved to k_aux (algebraic fold).
// CH==16 (mm2/mm4): es/ed kept in-body (only 314 blocks).
#define TILE_DW 288
template<int CH, int KSTEPS>
__device__ __forceinline__ void mm_es64_body(int rg, int cg, int MT,
    const unsigned short* __restrict__ Ap, const unsigned short* __restrict__ Bp,
    unsigned char* __restrict__ C, const float* __restrict__ a_s, const float* __restrict__ a_d,
    float* __restrict__ es, float* __restrict__ ed, int N, unsigned int* tile) {
  const int TI = KSTEPS * 64;              // int4 per 16-row A tile
  int vt = MT - rg * 4; if (vt > 4) vt = 4;  // valid row tiles (block-uniform)
  int wid = threadIdx.x >> 6;
  int tn = cg * 4 + wid;
  int lane = threadIdx.x & 63;
  int mr = lane & 15, quad = lane >> 4;
  const int4* ap = (const int4*)(Ap + (size_t)rg * 4 * TI * 8) + lane;
  const unsigned short* bp = Bp + ((size_t)tn * 4 * KSTEPS) * 512 + lane * 8;
  unsigned int* twave = tile + wid * TILE_DW;
  f32x4 acc[4][4];
#pragma unroll
  for (int rt = 0; rt < 4; ++rt)
#pragma unroll
    for (int nt = 0; nt < 4; ++nt) acc[rt][nt] = (f32x4){0.f, 0.f, 0.f, 0.f};
#pragma unroll
  for (int s = 0; s < KSTEPS; ++s) {
    ABfrag bfr[4];
#pragma unroll
    for (int nt = 0; nt < 4; ++nt) bfr[nt].i4 = *(const int4*)(bp + (size_t)(nt * KSTEPS + s) * 512);
    ABfrag afr[4];
#pragma unroll
    for (int rt = 0; rt < 4; ++rt) {
      int rti = (rt < vt) ? rt : 0;   // clamp: keep tail-row-group reads inside xp
      afr[rt].i4 = ap[rti * TI + s * 64];
    }
#pragma unroll
    for (int nt = 0; nt < 4; ++nt)
#pragma unroll
      for (int rt = 0; rt < 4; ++rt)
        acc[rt][nt] = __builtin_amdgcn_mfma_f32_16x16x32_bf16(afr[rt].v, bfr[nt].v, acc[rt][nt], 0, 0, 0);
  }
  // ---- fp8 pack + transpose + store (wave-private LDS region, no barrier) ----
  int r16 = lane >> 2, seg = lane & 3;
  int qr = r16 >> 2, rr = r16 & 3;
#pragma unroll
  for (int rt = 0; rt < 4; ++rt) {
    if (rt < vt) {
      int tm = rg * 4 + rt;
#pragma unroll
      for (int nt = 0; nt < 4; ++nt) {
        unsigned int dwv = pack4_fp8(acc[rt][nt][0], acc[rt][nt][1], acc[rt][nt][2], acc[rt][nt][3]);
        twave[quad * 72 + nt * 16 + mr] = dwv;   // 2-way bank (free)
      }
      unsigned int out[4];
#pragma unroll
      for (int w = 0; w < 4; ++w) {
        uint4 v = *(const uint4*)&twave[qr * 72 + seg * 16 + 4 * w];
        out[w] = bytesel4(v, rr);
      }
      *(int4*)(C + (size_t)(tm * 16 + r16) * N + tn * 64 + seg * 16) = *(const int4*)out;
    }
  }
  // es/ed — only for the small (CH==16) GEMMs
  if (CH == 16) {
    float ws[4], wd[4];
#pragma unroll
    for (int nt = 0; nt < 4; ++nt) {
      ws[nt] = a_s[(tn * 4 + nt) * 16 + mr];
      wd[nt] = a_d[(tn * 4 + nt) * 16 + mr];
    }
#pragma unroll
    for (int rt = 0; rt < 4; ++rt) {
      if (rt < vt) {
        int tm = rg * 4 + rt;
        float pes[4][4], ped[4][4];
#pragma unroll
        for (int nt = 0; nt < 4; ++nt)
#pragma unroll
          for (int r = 0; r < 4; ++r) { pes[nt][r] = acc[rt][nt][r] * ws[nt]; ped[nt][r] = acc[rt][nt][r] * wd[nt]; }
#pragma unroll
        for (int m = 1; m < 16; m <<= 1)
#pragma unroll
          for (int nt = 0; nt < 4; ++nt)
#pragma unroll
            for (int r = 0; r < 4; ++r) {
              pes[nt][r] += __shfl_xor(pes[nt][r], m);
              ped[nt][r] += __shfl_xor(ped[nt][r], m);
            }
        if (mr == 0) {
#pragma unroll
          for (int nt = 0; nt < 4; ++nt)
#pragma unroll
            for (int r = 0; r < 4; ++r) {
              int row = tm * 16 + quad * 4 + r;
              es[row * 32 + tn * 4 + nt] = pes[nt][r];
              ed[row * 32 + tn * 4 + nt] = ped[nt][r];
            }
        }
      }
    }
  }
}

// ---------- mm1 + mm3 (pure GEMM kernel) ----------
struct MMDesc {
  const unsigned short* Ap;
  const unsigned short* B1; const unsigned short* B3;
  unsigned char* C1; unsigned char* C3;
  int mmblks, mt;
};
__global__ __launch_bounds__(256) void k_mm13(MMDesc d) {
  __shared__ unsigned int tile[4 * TILE_DW];
  int b = blockIdx.x;
  if (b < d.mmblks) {
    mm_es64_body<64,4>(b >> 3, b & 7, d.mt, d.Ap, d.B1, d.C1, nullptr, nullptr, nullptr, nullptr, 2048, tile);
    return;
  }
  b -= d.mmblks;
  mm_es64_body<64,4>(b >> 3, b & 7, d.mt, d.Ap, d.B3, d.C3, nullptr, nullptr, nullptr, nullptr, 2048, tile);
}

// ---------- merged gather64, both flows; ONE WAVE per node ----------
__global__ __launch_bounds__(256) void k_g64(const unsigned char* __restrict__ h1,
                                             const unsigned char* __restrict__ h3,
                                             const float* __restrict__ es1, const float* __restrict__ ed1,
                                             const float* __restrict__ es3, const float* __restrict__ ed3,
                                             const int* __restrict__ rowA, const int* __restrict__ colA,
                                             const int* __restrict__ rowB, const int* __restrict__ colB,
                                             const float* __restrict__ b1, const float* __restrict__ b3,
                                             unsigned short* __restrict__ xsp, unsigned short* __restrict__ xtp,
                                             int n, int gb) {
  int b = blockIdx.x;
  const unsigned char* h; const float *es, *ed, *bias; const int *rowp, *col; unsigned short* outp;
  if (b < gb) { h = h1; es = es1; ed = ed1; rowp = rowA; col = colA; bias = b1; outp = xsp; }
  else { b -= gb; h = h3; es = es3; ed = ed3; rowp = rowB; col = colB; bias = b3; outp = xtp; }
  int wid = threadIdx.x >> 6, lane = threadIdx.x & 63;
  int i = b * 4 + wid;
  if (i >= n) return;
  int hd0 = lane >> 2, hd1 = 16 + hd0;
  float e0 = ed[i * 32 + hd0];
  float e1 = ed[i * 32 + hd1];
  int beg = rowp[i], end = rowp[i + 1];
  int deg = end - beg;                    // >= 1 (self-loop)
  int colv = (lane < deg) ? col[beg + lane] : 0;
  f32x2 acc0[8], acc1[8];
#pragma unroll
  for (int k = 0; k < 8; ++k) { acc0[k] = (f32x2){0.f, 0.f}; acc1[k] = (f32x2){0.f, 0.f}; }
  float Z0 = 0.f, Z1 = 0.f;
  // prologue: fetch edge 0
  int s0 = __shfl(colv, 0);
  const int4* hp0 = (const int4*)(h + (size_t)s0 * 2048);
  int4 ng0 = hp0[lane];
  int4 ng1 = hp0[64 + lane];
  float na = es[s0 * 32 + hd0];
  float nb = es[s0 * 32 + hd1];
  for (int j = 0; j < deg; ++j) {
    int4 g0 = ng0, g1 = ng1;
    float ea = na, eb = nb;
    int jn = j + 1;
    if (jn < deg) {                       // wave-uniform branch
      int sn = (jn < 64) ? __shfl(colv, jn) : col[beg + jn];
      const int4* hq = (const int4*)(h + (size_t)sn * 2048);
      ng0 = hq[lane];
      ng1 = hq[64 + lane];
      na = es[sn * 32 + hd0];
      nb = es[sn * 32 + hd1];
    }
    float q0 = __expf(lrelu_clamp(ea + e0));
    float q1 = __expf(lrelu_clamp(eb + e1));
    Z0 += q0; Z1 += q1;
    f32x2 d0[8], d1[8];
    dec16p(g0, d0); dec16p(g1, d1);
    f32x2 q0v = (f32x2){q0, q0}, q1v = (f32x2){q1, q1};
#pragma unroll
    for (int k = 0; k < 8; ++k) {
      acc0[k] = __builtin_elementwise_fma(q0v, d0[k], acc0[k]);
      acc1[k] = __builtin_elementwise_fma(q1v, d1[k], acc1[k]);
    }
  }
  float zi0 = 1.0f / Z0, zi1 = 1.0f / Z1;
  f32x2 zi0v = (f32x2){zi0, zi0}, zi1v = (f32x2){zi1, zi1};
  f32x2 v2[8];
#pragma unroll
  for (int k = 0; k < 8; ++k)
    v2[k] = __builtin_elementwise_fma(acc1[k], zi1v, acc0[k] * zi0v);
#pragma unroll
  for (int m = 4; m < 64; m <<= 1)
#pragma unroll
    for (int k = 0; k < 8; ++k) {
      v2[k].x += __shfl_xor(v2[k].x, m);
      v2[k].y += __shfl_xor(v2[k].y, m);
    }
  if (lane < 4) {
    float v[16];
#pragma unroll
    for (int k = 0; k < 8; ++k) { v[2 * k] = v2[k].x; v[2 * k + 1] = v2[k].y; }
    int tm = i >> 4, mr = i & 15;
    unsigned short ob[16];
#pragma unroll
    for (int k = 0; k < 16; ++k) {
      float t = v[k] * (1.f / 32.f) + bias[lane * 16 + k];
      t = (t > 0.f) ? t : (__expf(t) - 1.f);   // elu
      ob[k] = f2bf(t);
    }
    int s0w = lane >> 1;
#pragma unroll
    for (int g2 = 0; g2 < 2; ++g2) {
      size_t idx = (((size_t)tm * 2 + s0w) * 64 + ((lane & 1) * 2 + g2) * 16 + mr) * 8;
      *(int4*)(outp + idx) = *(const int4*)(ob + g2 * 8);  // packed-A bf16
    }
  }
}

// ---------- merged mm2 + mm4 (es/ed kept in-body) ----------
__global__ __launch_bounds__(256) void k_mm24(const unsigned short* __restrict__ xsp,
                                              const unsigned short* __restrict__ xtp,
                                              const unsigned short* __restrict__ W2p,
                                              const unsigned short* __restrict__ W4p,
                                              unsigned char* __restrict__ h2, unsigned char* __restrict__ h4,
                                              const float* __restrict__ as2, const float* __restrict__ ad2,
                                              const float* __restrict__ as4, const float* __restrict__ ad4,
                                              float* __restrict__ es2, float* __restrict__ ed2,
                                              float* __restrict__ es4, float* __restrict__ ed4,
                                              int mmblks, int mt) {
  __shared__ unsigned int tile[4 * TILE_DW];
  int b = blockIdx.x;
  if (b < mmblks)  // rg = b/2, cg = b%2 (N=512 -> 2 col groups of 256)
    mm_es64_body<16,2>(b >> 1, b & 1, mt, xsp, W2p, h2, as2, ad2, es2, ed2, 512, tile);
  else {
    b -= mmblks;
    mm_es64_body<16,2>(b >> 1, b & 1, mt, xtp, W4p, h4, as4, ad4, es4, ed4, 512, tile);
  }
}

// ---------- merged gather16, both flows; ONE WAVE per node -> final outputs ----------
__global__ __launch_bounds__(256) void k_g16(const unsigned char* __restrict__ h2,
                                             const unsigned char* __restrict__ h4,
                                             const float* __restrict__ es2, const float* __restrict__ ed2,
                                             const float* __restrict__ es4, const float* __restrict__ ed4,
                                             const int* __restrict__ rowA, const int* __restrict__ colA,
                                             const int* __restrict__ rowB, const int* __restrict__ colB,
                                             const float* __restrict__ b2, const float* __restrict__ b4,
                                             void* __restrict__ outbase, int n, int gb,
                                             const int* __restrict__ flag) {
  int b = blockIdx.x;
  const unsigned char* h; const float *es, *ed, *bias; const int *rowp, *col; size_t eoff;
  if (b < gb) { h = h2; es = es2; ed = ed2; rowp = rowA; col = colA; bias = b2; eoff = 0; }
  else { b -= gb; h = h4; es = es4; ed = ed4; rowp = rowB; col = colB; bias = b4; eoff = (size_t)n * 16; }
  int wid = threadIdx.x >> 6, lane = threadIdx.x & 63;
  int i = b * 4 + wid;
  if (i >= n) return;
  int hh = lane & 31, j2 = lane >> 5;
  float ev = ed[i * 32 + hh];
  int beg = rowp[i], end = rowp[i + 1];
  int deg = end - beg;
  int colv = (lane < deg) ? col[beg + lane] : 0;
  f32x2 acc[8];
#pragma unroll
  for (int k = 0; k < 8; ++k) acc[k] = (f32x2){0.f, 0.f};
  float Z = 0.f;
  int j = j2;
  int4 ng = (int4){0, 0, 0, 0};
  float ne = 0.f;
  if (j < deg) {
    int s = __shfl(colv, j);
    ng = ((const int4*)(h + (size_t)s * 512))[hh];
    ne = es[s * 32 + hh];
  }
  for (; j < deg; j += 2) {
    int4 g = ng; float ee = ne;
    int jn = j + 2;
    if (jn < deg) {
      int sn = (jn < 64) ? __shfl(colv, jn) : col[beg + jn];
      ng = ((const int4*)(h + (size_t)sn * 512))[hh];
      ne = es[sn * 32 + hh];
    }
    float q = __expf(lrelu_clamp(ee + ev));
    Z += q;
    f32x2 d[8];
    dec16p(g, d);
    f32x2 qv = (f32x2){q, q};
#pragma unroll
    for (int k = 0; k < 8; ++k) acc[k] = __builtin_elementwise_fma(qv, d[k], acc[k]);
  }
  Z += __shfl_xor(Z, 32);
  float zi = 1.0f / Z;
  f32x2 ziv = (f32x2){zi, zi};
  f32x2 v2[8];
#pragma unroll
  for (int k = 0; k < 8; ++k) v2[k] = acc[k] * ziv;
#pragma unroll
  for (int m = 1; m < 64; m <<= 1)
#pragma unroll
    for (int k = 0; k < 8; ++k) {
      v2[k].x += __shfl_xor(v2[k].x, m);
      v2[k].y += __shfl_xor(v2[k].y, m);
    }
  if (lane == 0) {
    float v[16];
#pragma unroll
    for (int k = 0; k < 8; ++k) { v[2 * k] = v2[k].x; v[2 * k + 1] = v2[k].y; }
    int isbf = *flag;
    if (isbf) {
      unsigned short ob[16];
#pragma unroll
      for (int k = 0; k < 16; ++k) {
        float t = v[k] * (1.f / 32.f) + bias[k];
        t = (t > 0.f) ? t : (__expf(t) - 1.f);
        ob[k] = f2bf(t);
      }
      unsigned short* o = (unsigned short*)outbase + eoff + (size_t)i * 16;
      *(int4*)o = *(const int4*)ob;
      *(int4*)(o + 8) = *(const int4*)(ob + 8);
    } else {
      float* o = (float*)outbase + eoff + (size_t)i * 16;
#pragma unroll
      for (int k = 0; k < 16; ++k) {
        float t = v[k] * (1.f / 32.f) + bias[k];
        t = (t > 0.f) ? t : (__expf(t) - 1.f);
        o[k] = t;
      }
    }
  }
}

extern "C" void kernel_launch(void* const* d_in, const int* in_sizes, int n_in,
                              void* d_out, int out_size, void* d_ws, size_t ws_size,
                              hipStream_t stream) {
  const int n = in_sizes[0] / 128;   // 10000
  const int E = in_sizes[1] / 2;     // 80000
  const int* ei = (const int*)d_in[1];

  char* wsp = (char*)d_ws; size_t off = 0;
  auto alloc = [&](size_t bytes) -> void* {
    void* p = wsp + off; off = (off + bytes + 255) & ~(size_t)255; return p;
  };
  int* flag = (int*)alloc(4);
  float* xc = (float*)alloc((size_t)n * 128 * 4);
  unsigned short* xp = (unsigned short*)alloc((size_t)n * 128 * 2);
  unsigned short* W1p = (unsigned short*)alloc((size_t)2048 * 128 * 2);
  unsigned short* W2p = (unsigned short*)alloc((size_t)512 * 64 * 2);
  unsigned short* W3p = (unsigned short*)alloc((size_t)2048 * 128 * 2);
  unsigned short* W4p = (unsigned short*)alloc((size_t)512 * 64 * 2);
  unsigned char* h1 = (unsigned char*)alloc((size_t)n * 2048);   // fp8
  unsigned char* h3 = (unsigned char*)alloc((size_t)n * 2048);
  unsigned char* h2 = (unsigned char*)alloc((size_t)n * 512);
  unsigned char* h4 = (unsigned char*)alloc((size_t)n * 512);
  float* es1 = (float*)alloc((size_t)n * 32 * 4);
  float* ed1 = (float*)alloc((size_t)n * 32 * 4);
  float* es3 = (float*)alloc((size_t)n * 32 * 4);
  float* ed3 = (float*)alloc((size_t)n * 32 * 4);
  float* es2 = (float*)alloc((size_t)n * 32 * 4);
  float* ed2 = (float*)alloc((size_t)n * 32 * 4);
  float* es4 = (float*)alloc((size_t)n * 32 * 4);
  float* ed4 = (float*)alloc((size_t)n * 32 * 4);
  unsigned short* xsp = (unsigned short*)alloc((size_t)n * 64 * 2);
  unsigned short* xtp = (unsigned short*)alloc((size_t)n * 64 * 2);
  int* rowA = (int*)alloc((size_t)(n + 1) * 4);
  int* rowB = (int*)alloc((size_t)(n + 1) * 4);
  int* colA = (int*)alloc((size_t)(E + n) * 4);
  int* colB = (int*)alloc((size_t)(E + n) * 4);
  int* degAB = (int*)alloc((size_t)2 * n * 4);
  int* degA = degAB, * degB = degAB + n;
  int* curA = (int*)alloc((size_t)n * 4);
  int* curB = (int*)alloc((size_t)n * 4);
  float* was1 = (float*)alloc((size_t)128 * 32 * 4);
  float* wad1 = (float*)alloc((size_t)128 * 32 * 4);
  float* was3 = (float*)alloc((size_t)128 * 32 * 4);
  float* wad3 = (float*)alloc((size_t)128 * 32 * 4);

  static const int cidx[32] = {3,4,5, 7,8,9, 11,12,13, 15,16,17,
                               18,19,20,21,22,23,24,25,26,27,28,29,
                               30,31,32,33,34,35,36,37};
  PrepDesc pd;
  float* canon[38] = {nullptr};
  pd.ctotal = 0;
  for (int t = 0; t < 32; ++t) {
    int ii = cidx[t];
    canon[ii] = (float*)alloc((size_t)in_sizes[ii] * 4);
    pd.csrc[t] = d_in[ii];
    pd.cdst[t] = canon[ii];
    pd.cn[t] = in_sizes[ii];
    pd.ctotal += in_sizes[ii];
  }
  pd.x = d_in[0]; pd.xc = xc; pd.xp = xp;
  pd.W1 = d_in[2]; pd.W2 = d_in[6]; pd.W3 = d_in[10]; pd.W4 = d_in[14];
  pd.P1 = W1p; pd.P2 = W2p; pd.P3 = W3p; pd.P4 = W4p;
  pd.degAB = degAB;
  pd.ei = ei;
  pd.av[0] = d_in[3]; pd.av[1] = d_in[4]; pd.av[2] = d_in[11]; pd.av[3] = d_in[12];
  pd.wa[0] = was1; pd.wa[1] = wad1; pd.wa[2] = was3; pd.wa[3] = wad3;
  pd.nxb = (n * 128 / 8 + 255) / 256;   // vectorized 8/thread
  pd.xtotal = n * 128;
  pd.E = E;
  pd.nn = n;
  (void)ws_size; (void)n_in; (void)out_size;

  const int degblks = (E + 255) / 256;  // 313

  // ---- detect + zero degAB (merged) ----
  k_detect<<<9, 256, 0, stream>>>((const unsigned int*)d_in[0], flag, degAB, 2 * n);
  // ---- unified prep + degree count + Wa fold v2 (merged) ----
  k_prep<<<pd.nxb + 288 + 4 + degblks + 64, 256, 0, stream>>>(pd, flag);
  // ---- CSR scan (both flows) ----
  k_exscan2<<<2, 1024, 0, stream>>>(degA, degB, rowA, rowB, colA, colB, curA, curB, n);

  const int mt = n / 16;              // 625
  const int nrg = (mt + 3) / 4;       // 157 row-groups of 64 rows
  const int mmblks64 = nrg * 8;       // per GEMM (N=2048 -> 8 col groups)
  const int mmblks16 = nrg * 2;       // per GEMM (N=512  -> 2 col groups)
  const int gb = (n + 3) / 4;         // 2500

  // ---- stage 1a: residual + es/ed GEMV + scatter ----
  AuxDesc ad;
  ad.resblks = mt; ad.E = E;
  ad.ei = ei; ad.colA = colA; ad.colB = colB; ad.curA = curA; ad.curB = curB;
  ad.xc = xc;
  for (int t = 0; t < 20; ++t) ad.rp[t] = canon[18 + t];
  ad.wa[0] = was1; ad.wa[1] = wad1; ad.wa[2] = was3; ad.wa[3] = wad3;
  ad.es1 = es1; ad.ed1 = ed1; ad.es3 = es3; ad.ed3 = ed3;
  ad.outbase = d_out; ad.eoff = (size_t)2 * n * 16; ad.n = n; ad.flag = flag;
  k_aux<<<mt + degblks, 256, 0, stream>>>(ad);

  // ---- stage 1b: mm1 + mm3 (pure GEMM) ----
  MMDesc md;
  md.Ap = xp; md.B1 = W1p; md.B3 = W3p; md.C1 = h1; md.C3 = h3;
  md.mmblks = mmblks64; md.mt = mt;
  k_mm13<<<2 * mmblks64, 256, 0, stream>>>(md);

  // ---- stage 2: gather64 both flows ----
  k_g64<<<2 * gb, 256, 0, stream>>>(h1, h3, es1, ed1, es3, ed3,
                                    rowA, colA, rowB, colB,
                                    canon[5], canon[13], xsp, xtp, n, gb);
  // ---- stage 3: mm2 + mm4 ----
  k_mm24<<<2 * mmblks16, 256, 0, stream>>>(xsp, xtp, W2p, W4p, h2, h4,
                                           canon[7], canon[8], canon[15], canon[16],
                                           es2, ed2, es4, ed4, mmblks16, mt);
  // ---- stage 4: gather16 both flows -> outputs 0,1 ----
  k_g16<<<2 * gb, 256, 0, stream>>>(h2, h4, es2, ed2, es4, ed4,
                                    rowA, colA, rowB, colB,
                                    canon[9], canon[17], d_out, n, gb, flag);
}

// Round 9
// 320.897 us; speedup vs baseline: 1.4415x; 1.0121x over previous
//
#include <hip/hip_runtime.h>
#include <stdint.h>

// ---------- bf16 helpers ----------
__device__ __forceinline__ float bf2f(unsigned short u) {
  union { unsigned int i; float f; } v; v.i = ((unsigned int)u) << 16; return v.f;
}
__device__ __forceinline__ unsigned short f2bf(float f) {
  union { float f; unsigned int i; } v; v.f = f;
  unsigned int i = v.i;
  unsigned int r = (i + 0x7fffu + ((i >> 16) & 1u)) >> 16;  // RNE
  return (unsigned short)r;
}

typedef __bf16 bf16x8 __attribute__((ext_vector_type(8)));
typedef float f32x4 __attribute__((ext_vector_type(4)));
typedef float f32x2 __attribute__((ext_vector_type(2)));
union ABfrag { int4 i4; bf16x8 v; };

// ---------- fp8 e4m3fn (OCP): HW path on gfx950, SW fallback ----------
#if __has_builtin(__builtin_amdgcn_cvt_pk_fp8_f32) && __has_builtin(__builtin_amdgcn_cvt_pk_f32_fp8)
#define HW_FP8 1
#else
#define HW_FP8 0
#endif

__device__ __forceinline__ unsigned char f2fp8_sw(float f) {
  union { float f; unsigned int u; } v; v.f = f;
  unsigned int s = (v.u >> 24) & 0x80;
  float a = fabsf(f);
  if (a >= 448.f) return (unsigned char)(s | 0x7E);
  v.f = a;
  int ex = (int)(v.u >> 23);
  unsigned int man = v.u & 0x7FFFFFu;
  if (ex >= 121) {
    unsigned int val = ((unsigned int)(ex - 120) << 3) | (man >> 20);
    unsigned int rem = man & 0xFFFFFu;
    if (rem > 0x80000u || (rem == 0x80000u && (val & 1))) val++;
    if (val > 0x7E) val = 0x7E;
    return (unsigned char)(s | val);
  }
  int q = (int)(a * 512.f + 0.5f);
  if (q > 8) q = 8;
  return (unsigned char)(s | (unsigned int)q);
}
__device__ __forceinline__ float fp8dec_sw(unsigned char c) {
  unsigned int e = (c >> 3) & 15u, m = c & 7u;
  float v;
  if (e) { union { unsigned int u; float f; } x; x.u = ((e + 120) << 23) | (m << 20); v = x.f; }
  else v = (float)m * 0.001953125f;
  return (c & 0x80) ? -v : v;
}
// pack 4 floats -> 4 fp8 bytes in one dword (bytes 0..3 = a0..a3)
__device__ __forceinline__ unsigned int pack4_fp8(float a0, float a1, float a2, float a3) {
#if HW_FP8
  int dw = __builtin_amdgcn_cvt_pk_fp8_f32(a0, a1, 0, false);
  dw = __builtin_amdgcn_cvt_pk_fp8_f32(a2, a3, dw, true);
  return (unsigned int)dw;
#else
  return (unsigned)f2fp8_sw(a0) | ((unsigned)f2fp8_sw(a1) << 8) |
         ((unsigned)f2fp8_sw(a2) << 16) | ((unsigned)f2fp8_sw(a3) << 24);
#endif
}
// select byte rr from each of 4 dwords -> one dword
__device__ __forceinline__ unsigned int bytesel4(uint4 v, int rr) {
#if __has_builtin(__builtin_amdgcn_perm)
  unsigned s = (unsigned)rr | ((unsigned)(rr + 4) << 8);
  unsigned p01 = __builtin_amdgcn_perm(v.y, v.x, s);
  unsigned p23 = __builtin_amdgcn_perm(v.w, v.z, s);
  return __builtin_amdgcn_perm(p23, p01, 0x05040100u);
#else
  int sh = rr * 8;
  return ((v.x >> sh) & 0xFFu) | (((v.y >> sh) & 0xFFu) << 8) |
         (((v.z >> sh) & 0xFFu) << 16) | (((v.w >> sh) & 0xFFu) << 24);
#endif
}
// decode 16 fp8 -> 8 packed float2 (keeps cvt_pk's natural pair output)
__device__ __forceinline__ void dec16p(int4 g, f32x2 o[8]) {
#if HW_FP8
  o[0] = __builtin_amdgcn_cvt_pk_f32_fp8(g.x, false);
  o[1] = __builtin_amdgcn_cvt_pk_f32_fp8(g.x, true);
  o[2] = __builtin_amdgcn_cvt_pk_f32_fp8(g.y, false);
  o[3] = __builtin_amdgcn_cvt_pk_f32_fp8(g.y, true);
  o[4] = __builtin_amdgcn_cvt_pk_f32_fp8(g.z, false);
  o[5] = __builtin_amdgcn_cvt_pk_f32_fp8(g.z, true);
  o[6] = __builtin_amdgcn_cvt_pk_f32_fp8(g.w, false);
  o[7] = __builtin_amdgcn_cvt_pk_f32_fp8(g.w, true);
#else
  unsigned int w[4] = {(unsigned)g.x, (unsigned)g.y, (unsigned)g.z, (unsigned)g.w};
#pragma unroll
  for (int d = 0; d < 4; ++d) {
    unsigned int x = w[d];
    o[d * 2 + 0] = (f32x2){fp8dec_sw((unsigned char)(x & 0xFF)),
                           fp8dec_sw((unsigned char)((x >> 8) & 0xFF))};
    o[d * 2 + 1] = (f32x2){fp8dec_sw((unsigned char)((x >> 16) & 0xFF)),
                           fp8dec_sw((unsigned char)((x >> 24) & 0xFF))};
  }
#endif
}

__device__ __forceinline__ float lrelu_clamp(float e) {
  e = (e > 0.f) ? e : 0.2f * e;
  return fminf(e, 80.f);
}

// ---------- dtype detection + degAB zeroing (merged) ----------
__global__ __launch_bounds__(256) void k_detect(const unsigned int* __restrict__ x, int* flag,
                                                int* __restrict__ degAB, int ndeg2) {
  if (blockIdx.x == 0) {
    __shared__ int cnt;
    if (threadIdx.x == 0) cnt = 0;
    __syncthreads();
    int c = 0;
    for (int i = threadIdx.x; i < 1024; i += 256) {
      unsigned int lo = x[i] & 0xFFFFu;
      int ex = (int)((lo >> 7) & 0xFF);
      if (ex >= 100 && ex <= 140) c++;
    }
    atomicAdd(&cnt, c);
    __syncthreads();
    if (threadIdx.x == 0) flag[0] = (cnt > 600) ? 1 : 0;  // 1 = bf16 inputs
    return;
  }
  for (int idx = (blockIdx.x - 1) * 256 + threadIdx.x; idx < ndeg2; idx += 8 * 256) degAB[idx] = 0;
}

// ---------- unified prep (+ degree count + attention-weight fold v2) ----------
struct PrepDesc {
  const void* csrc[32]; float* cdst[32]; int cn[32];
  const void* x; float* xc; unsigned short* xp;
  const void* W1; const void* W2; const void* W3; const void* W4;
  unsigned short* P1; unsigned short* P2; unsigned short* P3; unsigned short* P4;
  int* degAB;
  const int* ei;
  const void* av[4];   // as1, ad1, as3, ad3 (raw inputs)
  float* wa[4];        // Was1, Wad1, Was3, Wad3 [128x32]
  int nxb, xtotal, ctotal, E, nn;
};
__global__ __launch_bounds__(256) void k_prep(PrepDesc d, const int* __restrict__ flag) {
  int isbf = *flag;
  int b = blockIdx.x;
  if (b < d.nxb) {
    int t8 = b * 256 + threadIdx.x;
    int i8 = t8 * 8;
    if (i8 < d.xtotal) {
      float v[8];
      if (isbf) {
        int4 raw = *(const int4*)((const unsigned short*)d.x + i8);
        const unsigned short* u = (const unsigned short*)&raw;
#pragma unroll
        for (int j = 0; j < 8; ++j) v[j] = bf2f(u[j]);
      } else {
        float4 f0 = *(const float4*)((const float*)d.x + i8);
        float4 f1 = *(const float4*)((const float*)d.x + i8 + 4);
        v[0] = f0.x; v[1] = f0.y; v[2] = f0.z; v[3] = f0.w;
        v[4] = f1.x; v[5] = f1.y; v[6] = f1.z; v[7] = f1.w;
      }
      *(float4*)(d.xc + i8)     = (float4){v[0], v[1], v[2], v[3]};
      *(float4*)(d.xc + i8 + 4) = (float4){v[4], v[5], v[6], v[7]};
      int row = i8 >> 7, c0 = i8 & 127;
      int tm = row >> 4, mr = row & 15;
      int s = c0 >> 5, quad = (c0 >> 3) & 3;
      unsigned short o[8];
#pragma unroll
      for (int j = 0; j < 8; ++j) o[j] = f2bf(v[j]);
      size_t idx = (((size_t)tm * 4 + s) * 64 + quad * 16 + mr) * 8;
      *(int4*)(d.xp + idx) = *(const int4*)o;
    }
    return;
  }
  b -= d.nxb;
  if (b < 288) {
    int u = b * 256 + threadIdx.x;
    const void* W; unsigned short* P; int K, N, lu;
    if (u < 32768)      { W = d.W1; P = d.P1; K = 128; N = 2048; lu = u; }
    else if (u < 36864) { W = d.W2; P = d.P2; K = 64;  N = 512;  lu = u - 32768; }
    else if (u < 69632) { W = d.W3; P = d.P3; K = 128; N = 2048; lu = u - 36864; }
    else                { W = d.W4; P = d.P4; K = 64;  N = 512;  lu = u - 69632; }
    int ksteps = K >> 5;
    int g = lu / (ksteps * 64);
    int rem = lu - g * (ksteps * 64);
    int s = rem >> 6, lane = rem & 63;
    int mr = lane & 15, quad = lane >> 4;
    int col = g * 16 + mr;
    int kbase = s * 32 + quad * 8;
#pragma unroll
    for (int j = 0; j < 8; ++j) {
      size_t src = (size_t)(kbase + j) * N + col;
      float v = isbf ? bf2f(((const unsigned short*)W)[src]) : ((const float*)W)[src];
      P[(size_t)lu * 8 + j] = f2bf(v);
    }
    return;
  }
  b -= 288;
  if (b < 4) {
    for (int idx = b * 256 + threadIdx.x; idx < d.ctotal; idx += 4 * 256) {
      int t = 0, off = idx;
      while (off >= d.cn[t]) { off -= d.cn[t]; ++t; }
      float v = isbf ? bf2f(((const unsigned short*)d.csrc[t])[off])
                     : ((const float*)d.csrc[t])[off];
      d.cdst[t][off] = v;
    }
    return;
  }
  b -= 4;
  {
    int degblks = (d.E + 255) >> 8;
    if (b < degblks) {  // degree count (degAB zeroed by k_detect)
      int e = b * 256 + threadIdx.x;
      if (e < d.E) {
        atomicAdd(&d.degAB[d.ei[d.E + e]], 1);
        atomicAdd(&d.degAB[d.nn + d.ei[e]], 1);
      }
      return;
    }
    b -= degblks;
  }
  {  // Wa fold v2: b in [0,64): matrix m = b>>4, k-block = b&15
    int m = b >> 4, kb = b & 15;
    const void* W = (m < 2) ? d.W1 : d.W3;
    const void* A = d.av[m];
    float* out = d.wa[m];
    int k = kb * 8 + (threadIdx.x >> 5);   // 8 k per block
    int h = threadIdx.x & 31;              // 32 heads
    size_t wbase = (size_t)k * 2048 + h * 64;
    size_t abase = (size_t)h * 64;
    float acc = 0.f;
    if (isbf) {
      const unsigned short* Wb = (const unsigned short*)W;
      const unsigned short* Ab = (const unsigned short*)A;
#pragma unroll
      for (int v8 = 0; v8 < 8; ++v8) {
        int4 wv = *(const int4*)(Wb + wbase + v8 * 8);
        int4 av = *(const int4*)(Ab + abase + v8 * 8);
        const unsigned short* wu = (const unsigned short*)&wv;
        const unsigned short* au = (const unsigned short*)&av;
#pragma unroll
        for (int j = 0; j < 8; ++j) acc += bf2f(wu[j]) * bf2f(au[j]);
      }
    } else {
      const float* Wf = (const float*)W;
      const float* Af = (const float*)A;
#pragma unroll
      for (int v4 = 0; v4 < 16; ++v4) {
        float4 wv = *(const float4*)(Wf + wbase + v4 * 4);
        float4 av = *(const float4*)(Af + abase + v4 * 4);
        acc += wv.x * av.x + wv.y * av.y + wv.z * av.z + wv.w * av.w;
      }
    }
    out[k * 32 + h] = acc;
  }
}

// ---------- CSR exclusive scan ----------
__global__ __launch_bounds__(1024) void k_exscan2(const int* __restrict__ degA, const int* __restrict__ degB,
                                                  int* __restrict__ rowA, int* __restrict__ rowB,
                                                  int* __restrict__ colA, int* __restrict__ colB,
                                                  int* __restrict__ curA, int* __restrict__ curB, int n) {
  const int* deg = (blockIdx.x == 0) ? degA : degB;
  int* row = (blockIdx.x == 0) ? rowA : rowB;
  int* colx = (blockIdx.x == 0) ? colA : colB;
  int* curx = (blockIdx.x == 0) ? curA : curB;
  __shared__ int wsum[16], wbase[16];
  __shared__ int carry;
  if (threadIdx.x == 0) carry = 0;
  __syncthreads();
  int lane = threadIdx.x & 63, w = threadIdx.x >> 6;
  int chunks = (n + 1023) >> 10;
  for (int ch = 0; ch < chunks; ++ch) {
    int i = (ch << 10) + threadIdx.x;
    int v = (i < n) ? deg[i] : 0;
    int sc = v;
#pragma unroll
    for (int o = 1; o < 64; o <<= 1) { int t = __shfl_up(sc, o); if (lane >= o) sc += t; }
    if (lane == 63) wsum[w] = sc;
    __syncthreads();
    if (threadIdx.x < 16) {
      int v2 = wsum[threadIdx.x], s2 = v2;
#pragma unroll
      for (int o = 1; o < 16; o <<= 1) { int t = __shfl_up(s2, o); if (lane >= o) s2 += t; }
      wbase[threadIdx.x] = s2 - v2;
      if (threadIdx.x == 15) wsum[15] = s2;
    }
    __syncthreads();
    if (i < n) {
      int rv = carry + wbase[w] + (sc - v) + i;
      row[i] = rv;
      colx[rv] = i;
      curx[i] = rv + 1;
    }
    __syncthreads();
    if (threadIdx.x == 0) carry += wsum[15];
    __syncthreads();
  }
  if (threadIdx.x == 0) row[n] = carry + n;
}

// ---------- 64-row x 64-col per-wave GEMM body ----------
#define TILE_DW 288
template<int CH, int KSTEPS>
__device__ __forceinline__ void mm_es64_body(int rg, int cg, int MT,
    const unsigned short* __restrict__ Ap, const unsigned short* __restrict__ Bp,
    unsigned char* __restrict__ C, const float* __restrict__ a_s, const float* __restrict__ a_d,
    float* __restrict__ es, float* __restrict__ ed, int N, unsigned int* tile) {
  const int TI = KSTEPS * 64;
  int vt = MT - rg * 4; if (vt > 4) vt = 4;
  int wid = threadIdx.x >> 6;
  int tn = cg * 4 + wid;
  int lane = threadIdx.x & 63;
  int mr = lane & 15, quad = lane >> 4;
  const int4* ap = (const int4*)(Ap + (size_t)rg * 4 * TI * 8) + lane;
  const unsigned short* bp = Bp + ((size_t)tn * 4 * KSTEPS) * 512 + lane * 8;
  unsigned int* twave = tile + wid * TILE_DW;
  f32x4 acc[4][4];
#pragma unroll
  for (int rt = 0; rt < 4; ++rt)
#pragma unroll
    for (int nt = 0; nt < 4; ++nt) acc[rt][nt] = (f32x4){0.f, 0.f, 0.f, 0.f};
#pragma unroll
  for (int s = 0; s < KSTEPS; ++s) {
    ABfrag bfr[4];
#pragma unroll
    for (int nt = 0; nt < 4; ++nt) bfr[nt].i4 = *(const int4*)(bp + (size_t)(nt * KSTEPS + s) * 512);
    ABfrag afr[4];
#pragma unroll
    for (int rt = 0; rt < 4; ++rt) {
      int rti = (rt < vt) ? rt : 0;   // clamp: keep tail-row-group reads inside xp
      afr[rt].i4 = ap[rti * TI + s * 64];
    }
#pragma unroll
    for (int nt = 0; nt < 4; ++nt)
#pragma unroll
      for (int rt = 0; rt < 4; ++rt)
        acc[rt][nt] = __builtin_amdgcn_mfma_f32_16x16x32_bf16(afr[rt].v, bfr[nt].v, acc[rt][nt], 0, 0, 0);
  }
  int r16 = lane >> 2, seg = lane & 3;
  int qr = r16 >> 2, rr = r16 & 3;
#pragma unroll
  for (int rt = 0; rt < 4; ++rt) {
    if (rt < vt) {
      int tm = rg * 4 + rt;
#pragma unroll
      for (int nt = 0; nt < 4; ++nt) {
        unsigned int dwv = pack4_fp8(acc[rt][nt][0], acc[rt][nt][1], acc[rt][nt][2], acc[rt][nt][3]);
        twave[quad * 72 + nt * 16 + mr] = dwv;   // 2-way bank (free)
      }
      unsigned int out[4];
#pragma unroll
      for (int w = 0; w < 4; ++w) {
        uint4 v = *(const uint4*)&twave[qr * 72 + seg * 16 + 4 * w];
        out[w] = bytesel4(v, rr);
      }
      *(int4*)(C + (size_t)(tm * 16 + r16) * N + tn * 64 + seg * 16) = *(const int4*)out;
    }
  }
  if (CH == 16) {
    float ws[4], wd[4];
#pragma unroll
    for (int nt = 0; nt < 4; ++nt) {
      ws[nt] = a_s[(tn * 4 + nt) * 16 + mr];
      wd[nt] = a_d[(tn * 4 + nt) * 16 + mr];
    }
#pragma unroll
    for (int rt = 0; rt < 4; ++rt) {
      if (rt < vt) {
        int tm = rg * 4 + rt;
        float pes[4][4], ped[4][4];
#pragma unroll
        for (int nt = 0; nt < 4; ++nt)
#pragma unroll
          for (int r = 0; r < 4; ++r) { pes[nt][r] = acc[rt][nt][r] * ws[nt]; ped[nt][r] = acc[rt][nt][r] * wd[nt]; }
#pragma unroll
        for (int m = 1; m < 16; m <<= 1)
#pragma unroll
          for (int nt = 0; nt < 4; ++nt)
#pragma unroll
            for (int r = 0; r < 4; ++r) {
              pes[nt][r] += __shfl_xor(pes[nt][r], m);
              ped[nt][r] += __shfl_xor(ped[nt][r], m);
            }
        if (mr == 0) {
#pragma unroll
          for (int nt = 0; nt < 4; ++nt)
#pragma unroll
            for (int r = 0; r < 4; ++r) {
              int row = tm * 16 + quad * 4 + r;
              es[row * 32 + tn * 4 + nt] = pes[nt][r];
              ed[row * 32 + tn * 4 + nt] = ped[nt][r];
            }
        }
      }
    }
  }
}

// ---------- merged: residual+GEMV -> scatter -> mm1 -> mm3 ----------
// es1/ed1/es3/ed3 written INTERLEAVED: [row][2h] = {head h, head h+16}
// so k_g64 loads one float2 per edge per array.
union SM13 {
  struct { float xs[16][128]; float ha[16][16]; float tt[16][16]; } res;
  unsigned int tile[4 * TILE_DW];
};
struct MM13XDesc {
  int resblks, sblks, mmblks, mt, E;
  const int* ei; int* colA; int* colB; int* curA; int* curB;
  const float* xc;
  const float* rp[20];
  const float* wa[4];
  float* es1; float* ed1; float* es3; float* ed3;
  void* outbase; size_t eoff; int n;
  const int* flag;
  const unsigned short* Ap;
  const unsigned short* B1; const unsigned short* B3;
  unsigned char* C1; unsigned char* C3;
};
__global__ __launch_bounds__(256) void k_mm13x(MM13XDesc d) {
  __shared__ SM13 sm;
  int b = blockIdx.x;
  if (b < d.resblks) {
    int nodebase = b * 16;
    for (int t = threadIdx.x; t < 16 * 128; t += 256)
      sm.res.xs[t >> 7][t & 127] = d.xc[(size_t)(nodebase + (t >> 7)) * 128 + (t & 127)];
    __syncthreads();
    int ni = threadIdx.x >> 4, c = threadIdx.x & 15;
    // ---- es/ed GEMV (interleaved write: [2c]={head c, head c+16}) ----
    {
      const float* w0 = d.wa[0]; const float* w1 = d.wa[1];
      const float* w2 = d.wa[2]; const float* w3 = d.wa[3];
      float a0 = 0.f, a1 = 0.f, a2 = 0.f, a3 = 0.f, a4 = 0.f, a5 = 0.f, a6 = 0.f, a7 = 0.f;
#pragma unroll 4
      for (int k = 0; k < 128; ++k) {
        float xv = sm.res.xs[ni][k];
        int o = k * 32 + c;
        a0 += xv * w0[o]; a1 += xv * w0[o + 16];
        a2 += xv * w1[o]; a3 += xv * w1[o + 16];
        a4 += xv * w2[o]; a5 += xv * w2[o + 16];
        a6 += xv * w3[o]; a7 += xv * w3[o + 16];
      }
      int row = nodebase + ni;
      *(float2*)&d.es1[row * 32 + 2 * c] = (float2){a0, a1};
      *(float2*)&d.ed1[row * 32 + 2 * c] = (float2){a2, a3};
      *(float2*)&d.es3[row * 32 + 2 * c] = (float2){a4, a5};
      *(float2*)&d.ed3[row * 32 + 2 * c] = (float2){a6, a7};
    }
    // ---- residual MLP ----
    const float* rwa = d.rp[0]; const float* rba = d.rp[1];
    const float* bn1g = d.rp[2]; const float* bn1b = d.rp[3];
    const float* bn1m = d.rp[4]; const float* bn1v = d.rp[5];
    const float* rwb = d.rp[6]; const float* rbb = d.rp[7];
    const float* bn2g = d.rp[8]; const float* bn2b = d.rp[9];
    const float* bn2m = d.rp[10]; const float* bn2v = d.rp[11];
    const float* wsc = d.rp[12]; const float* bsc = d.rp[13];
    const float* bnsg = d.rp[14]; const float* bnsb = d.rp[15];
    const float* bnsm = d.rp[16]; const float* bnsv = d.rp[17];
    const float* wfc = d.rp[18]; const float* bfc = d.rp[19];
    float ya = 0.f, ysc = 0.f;
#pragma unroll 8
    for (int k = 0; k < 128; ++k) {
      float xv = sm.res.xs[ni][k];
      ya  += xv * rwa[k * 16 + c];
      ysc += xv * wsc[k * 16 + c];
    }
    ya += rba[c]; ysc += bsc[c];
    float s1 = bn1g[c] * rsqrtf(bn1v[c] + 1e-5f);
    ya = (ya - bn1m[c]) * s1 + bn1b[c];
    ya = fmaxf(ya, 0.f);
    float ss = bnsg[c] * rsqrtf(bnsv[c] + 1e-5f);
    ysc = (ysc - bnsm[c]) * ss + bnsb[c];
    sm.res.ha[ni][c] = ya;
    __syncthreads();
    float h2 = rbb[c];
#pragma unroll
    for (int k = 0; k < 16; ++k) h2 += sm.res.ha[ni][k] * rwb[k * 16 + c];
    float s2 = bn2g[c] * rsqrtf(bn2v[c] + 1e-5f);
    h2 = (h2 - bn2m[c]) * s2 + bn2b[c];
    sm.res.tt[ni][c] = fmaxf(h2 + ysc, 0.f);
    __syncthreads();
    float o = bfc[c];
#pragma unroll
    for (int k = 0; k < 16; ++k) o += sm.res.tt[ni][k] * wfc[k * 16 + c];
    size_t oo = d.eoff + (size_t)(nodebase + ni) * 16 + c;
    if (*d.flag) ((unsigned short*)d.outbase)[oo] = f2bf(o);
    else         ((float*)d.outbase)[oo] = o;
    return;
  }
  b -= d.resblks;
  if (b < d.sblks) {  // CSR scatter
    int e = b * 256 + threadIdx.x;
    if (e < d.E) {
      int s = d.ei[e], dd = d.ei[d.E + e];
      d.colA[atomicAdd(&d.curA[dd], 1)] = s;
      d.colB[atomicAdd(&d.curB[s], 1)] = dd;
    }
    return;
  }
  b -= d.sblks;
  if (b < d.mmblks) {
    mm_es64_body<64,4>(b >> 3, b & 7, d.mt, d.Ap, d.B1, d.C1, nullptr, nullptr, nullptr, nullptr, 2048, sm.tile);
    return;
  }
  b -= d.mmblks;
  mm_es64_body<64,4>(b >> 3, b & 7, d.mt, d.Ap, d.B3, d.C3, nullptr, nullptr, nullptr, nullptr, 2048, sm.tile);
}

// ---------- merged gather64; ONE WAVE per node; 2-deep pipeline ----------
// es/ed are INTERLEAVED [row][2h]={h, h+16}: one float2 load per edge per array.
__global__ __launch_bounds__(256) void k_g64(const unsigned char* __restrict__ h1,
                                             const unsigned char* __restrict__ h3,
                                             const float* __restrict__ es1, const float* __restrict__ ed1,
                                             const float* __restrict__ es3, const float* __restrict__ ed3,
                                             const int* __restrict__ rowA, const int* __restrict__ colA,
                                             const int* __restrict__ rowB, const int* __restrict__ colB,
                                             const float* __restrict__ b1, const float* __restrict__ b3,
                                             unsigned short* __restrict__ xsp, unsigned short* __restrict__ xtp,
                                             int n, int gb) {
  int b = blockIdx.x;
  const unsigned char* h; const float *es, *ed, *bias; const int *rowp, *col; unsigned short* outp;
  if (b < gb) { h = h1; es = es1; ed = ed1; rowp = rowA; col = colA; bias = b1; outp = xsp; }
  else { b -= gb; h = h3; es = es3; ed = ed3; rowp = rowB; col = colB; bias = b3; outp = xtp; }
  int wid = threadIdx.x >> 6, lane = threadIdx.x & 63;
  int i = b * 4 + wid;
  if (i >= n) return;
  int hd0 = lane >> 2;
  const float2* esp = (const float2*)es;
  const float2* edp = (const float2*)ed;
  float2 e01 = edp[i * 16 + hd0];
  int beg = rowp[i], end = rowp[i + 1];
  int deg = end - beg;                    // >= 1 (self-loop)
  int colv = (lane < deg) ? col[beg + lane] : 0;
  f32x2 acc0[8], acc1[8];
#pragma unroll
  for (int k = 0; k < 8; ++k) { acc0[k] = (f32x2){0.f, 0.f}; acc1[k] = (f32x2){0.f, 0.f}; }
  float Z0 = 0.f, Z1 = 0.f;
  // prologue: slots A (edge 0), B (edge 1)
  int sA = __shfl(colv, 0);
  const int4* hp = (const int4*)(h + (size_t)sA * 2048);
  int4 gA0 = hp[lane], gA1 = hp[64 + lane];
  float2 eA = esp[sA * 16 + hd0];
  int4 gB0 = gA0, gB1 = gA1; float2 eB = eA;
  if (deg > 1) {
    int sB = __shfl(colv, 1);
    const int4* hq = (const int4*)(h + (size_t)sB * 2048);
    gB0 = hq[lane]; gB1 = hq[64 + lane];
    eB = esp[sB * 16 + hd0];
  }
  int j = 0;
  while (true) {
    {  // consume slot A (edge j)
      float q0 = __expf(lrelu_clamp(eA.x + e01.x));
      float q1 = __expf(lrelu_clamp(eA.y + e01.y));
      Z0 += q0; Z1 += q1;
      f32x2 d0[8], d1[8];
      dec16p(gA0, d0); dec16p(gA1, d1);
      f32x2 q0v = (f32x2){q0, q0}, q1v = (f32x2){q1, q1};
#pragma unroll
      for (int k = 0; k < 8; ++k) {
        acc0[k] = __builtin_elementwise_fma(q0v, d0[k], acc0[k]);
        acc1[k] = __builtin_elementwise_fma(q1v, d1[k], acc1[k]);
      }
    }
    int jp = j + 2;
    if (jp < deg) {  // prefetch edge j+2 into A (wave-uniform)
      int sn = (jp < 64) ? __shfl(colv, jp) : col[beg + jp];
      const int4* hq = (const int4*)(h + (size_t)sn * 2048);
      gA0 = hq[lane]; gA1 = hq[64 + lane];
      eA = esp[sn * 16 + hd0];
    }
    if (++j >= deg) break;
    {  // consume slot B (edge j)
      float q0 = __expf(lrelu_clamp(eB.x + e01.x));
      float q1 = __expf(lrelu_clamp(eB.y + e01.y));
      Z0 += q0; Z1 += q1;
      f32x2 d0[8], d1[8];
      dec16p(gB0, d0); dec16p(gB1, d1);
      f32x2 q0v = (f32x2){q0, q0}, q1v = (f32x2){q1, q1};
#pragma unroll
      for (int k = 0; k < 8; ++k) {
        acc0[k] = __builtin_elementwise_fma(q0v, d0[k], acc0[k]);
        acc1[k] = __builtin_elementwise_fma(q1v, d1[k], acc1[k]);
      }
    }
    jp = j + 2;
    if (jp < deg) {  // prefetch edge j+2 into B
      int sn = (jp < 64) ? __shfl(colv, jp) : col[beg + jp];
      const int4* hq = (const int4*)(h + (size_t)sn * 2048);
      gB0 = hq[lane]; gB1 = hq[64 + lane];
      eB = esp[sn * 16 + hd0];
    }
    if (++j >= deg) break;
  }
  float zi0 = 1.0f / Z0, zi1 = 1.0f / Z1;
  f32x2 zi0v = (f32x2){zi0, zi0}, zi1v = (f32x2){zi1, zi1};
  f32x2 v2[8];
#pragma unroll
  for (int k = 0; k < 8; ++k)
    v2[k] = __builtin_elementwise_fma(acc1[k], zi1v, acc0[k] * zi0v);
#pragma unroll
  for (int m = 4; m < 64; m <<= 1)
#pragma unroll
    for (int k = 0; k < 8; ++k) {
      v2[k].x += __shfl_xor(v2[k].x, m);
      v2[k].y += __shfl_xor(v2[k].y, m);
    }
  if (lane < 4) {
    float v[16];
#pragma unroll
    for (int k = 0; k < 8; ++k) { v[2 * k] = v2[k].x; v[2 * k + 1] = v2[k].y; }
    int tm = i >> 4, mr = i & 15;
    unsigned short ob[16];
#pragma unroll
    for (int k = 0; k < 16; ++k) {
      float t = v[k] * (1.f / 32.f) + bias[lane * 16 + k];
      t = (t > 0.f) ? t : (__expf(t) - 1.f);   // elu
      ob[k] = f2bf(t);
    }
    int s0w = lane >> 1;
#pragma unroll
    for (int g2 = 0; g2 < 2; ++g2) {
      size_t idx = (((size_t)tm * 2 + s0w) * 64 + ((lane & 1) * 2 + g2) * 16 + mr) * 8;
      *(int4*)(outp + idx) = *(const int4*)(ob + g2 * 8);  // packed-A bf16
    }
  }
}

// ---------- merged mm2 + mm4 (es/ed kept in-body, original layout) ----------
__global__ __launch_bounds__(256) void k_mm24(const unsigned short* __restrict__ xsp,
                                              const unsigned short* __restrict__ xtp,
                                              const unsigned short* __restrict__ W2p,
                                              const unsigned short* __restrict__ W4p,
                                              unsigned char* __restrict__ h2, unsigned char* __restrict__ h4,
                                              const float* __restrict__ as2, const float* __restrict__ ad2,
                                              const float* __restrict__ as4, const float* __restrict__ ad4,
                                              float* __restrict__ es2, float* __restrict__ ed2,
                                              float* __restrict__ es4, float* __restrict__ ed4,
                                              int mmblks, int mt) {
  __shared__ unsigned int tile[4 * TILE_DW];
  int b = blockIdx.x;
  if (b < mmblks)
    mm_es64_body<16,2>(b >> 1, b & 1, mt, xsp, W2p, h2, as2, ad2, es2, ed2, 512, tile);
  else {
    b -= mmblks;
    mm_es64_body<16,2>(b >> 1, b & 1, mt, xtp, W4p, h4, as4, ad4, es4, ed4, 512, tile);
  }
}

// ---------- merged gather16; ONE WAVE per node; 2-deep pipeline ----------
__global__ __launch_bounds__(256) void k_g16(const unsigned char* __restrict__ h2,
                                             const unsigned char* __restrict__ h4,
                                             const float* __restrict__ es2, const float* __restrict__ ed2,
                                             const float* __restrict__ es4, const float* __restrict__ ed4,
                                             const int* __restrict__ rowA, const int* __restrict__ colA,
                                             const int* __restrict__ rowB, const int* __restrict__ colB,
                                             const float* __restrict__ b2, const float* __restrict__ b4,
                                             void* __restrict__ outbase, int n, int gb,
                                             const int* __restrict__ flag) {
  int b = blockIdx.x;
  const unsigned char* h; const float *es, *ed, *bias; const int *rowp, *col; size_t eoff;
  if (b < gb) { h = h2; es = es2; ed = ed2; rowp = rowA; col = colA; bias = b2; eoff = 0; }
  else { b -= gb; h = h4; es = es4; ed = ed4; rowp = rowB; col = colB; bias = b4; eoff = (size_t)n * 16; }
  int wid = threadIdx.x >> 6, lane = threadIdx.x & 63;
  int i = b * 4 + wid;
  if (i >= n) return;
  int hh = lane & 31, j2 = lane >> 5;
  float ev = ed[i * 32 + hh];
  int beg = rowp[i], end = rowp[i + 1];
  int deg = end - beg;
  int colv = (lane < deg) ? col[beg + lane] : 0;
  f32x2 acc[8];
#pragma unroll
  for (int k = 0; k < 8; ++k) acc[k] = (f32x2){0.f, 0.f};
  float Z = 0.f;
  int j = j2;
  // prologue: slot A (own edge j), slot B (own edge j+2)
  int4 gA = (int4){0, 0, 0, 0}; float eA = 0.f;
  if (j < deg) {
    int s = __shfl(colv, j);
    gA = ((const int4*)(h + (size_t)s * 512))[hh];
    eA = es[s * 32 + hh];
  }
  int4 gB = (int4){0, 0, 0, 0}; float eB = 0.f;
  if (j + 2 < deg) {
    int s = __shfl(colv, j + 2);
    gB = ((const int4*)(h + (size_t)s * 512))[hh];
    eB = es[s * 32 + hh];
  }
  while (j < deg) {
    {  // consume A (edge j)
      float q = __expf(lrelu_clamp(eA + ev));
      Z += q;
      f32x2 d[8];
      dec16p(gA, d);
      f32x2 qv = (f32x2){q, q};
#pragma unroll
      for (int k = 0; k < 8; ++k) acc[k] = __builtin_elementwise_fma(qv, d[k], acc[k]);
    }
    int jp = j + 4;
    if (jp < deg) {
      int s = (jp < 64) ? __shfl(colv, jp) : col[beg + jp];
      gA = ((const int4*)(h + (size_t)s * 512))[hh];
      eA = es[s * 32 + hh];
    }
    j += 2;
    if (j >= deg) break;
    {  // consume B (edge j)
      float q = __expf(lrelu_clamp(eB + ev));
      Z += q;
      f32x2 d[8];
      dec16p(gB, d);
      f32x2 qv = (f32x2){q, q};
#pragma unroll
      for (int k = 0; k < 8; ++k) acc[k] = __builtin_elementwise_fma(qv, d[k], acc[k]);
    }
    jp = j + 4;
    if (jp < deg) {
      int s = (jp < 64) ? __shfl(colv, jp) : col[beg + jp];
      gB = ((const int4*)(h + (size_t)s * 512))[hh];
      eB = es[s * 32 + hh];
    }
    j += 2;
  }
  Z += __shfl_xor(Z, 32);
  float zi = 1.0f / Z;
  f32x2 ziv = (f32x2){zi, zi};
  f32x2 v2[8];
#pragma unroll
  for (int k = 0; k < 8; ++k) v2[k] = acc[k] * ziv;
#pragma unroll
  for (int m = 1; m < 64; m <<= 1)
#pragma unroll
    for (int k = 0; k < 8; ++k) {
      v2[k].x += __shfl_xor(v2[k].x, m);
      v2[k].y += __shfl_xor(v2[k].y, m);
    }
  if (lane == 0) {
    float v[16];
#pragma unroll
    for (int k = 0; k < 8; ++k) { v[2 * k] = v2[k].x; v[2 * k + 1] = v2[k].y; }
    int isbf = *flag;
    if (isbf) {
      unsigned short ob[16];
#pragma unroll
      for (int k = 0; k < 16; ++k) {
        float t = v[k] * (1.f / 32.f) + bias[k];
        t = (t > 0.f) ? t : (__expf(t) - 1.f);
        ob[k] = f2bf(t);
      }
      unsigned short* o = (unsigned short*)outbase + eoff + (size_t)i * 16;
      *(int4*)o = *(const int4*)ob;
      *(int4*)(o + 8) = *(const int4*)(ob + 8);
    } else {
      float* o = (float*)outbase + eoff + (size_t)i * 16;
#pragma unroll
      for (int k = 0; k < 16; ++k) {
        float t = v[k] * (1.f / 32.f) + bias[k];
        t = (t > 0.f) ? t : (__expf(t) - 1.f);
        o[k] = t;
      }
    }
  }
}

extern "C" void kernel_launch(void* const* d_in, const int* in_sizes, int n_in,
                              void* d_out, int out_size, void* d_ws, size_t ws_size,
                              hipStream_t stream) {
  const int n = in_sizes[0] / 128;   // 10000
  const int E = in_sizes[1] / 2;     // 80000
  const int* ei = (const int*)d_in[1];

  char* wsp = (char*)d_ws; size_t off = 0;
  auto alloc = [&](size_t bytes) -> void* {
    void* p = wsp + off; off = (off + bytes + 255) & ~(size_t)255; return p;
  };
  int* flag = (int*)alloc(4);
  float* xc = (float*)alloc((size_t)n * 128 * 4);
  unsigned short* xp = (unsigned short*)alloc((size_t)n * 128 * 2);
  unsigned short* W1p = (unsigned short*)alloc((size_t)2048 * 128 * 2);
  unsigned short* W2p = (unsigned short*)alloc((size_t)512 * 64 * 2);
  unsigned short* W3p = (unsigned short*)alloc((size_t)2048 * 128 * 2);
  unsigned short* W4p = (unsigned short*)alloc((size_t)512 * 64 * 2);
  unsigned char* h1 = (unsigned char*)alloc((size_t)n * 2048);   // fp8
  unsigned char* h3 = (unsigned char*)alloc((size_t)n * 2048);
  unsigned char* h2 = (unsigned char*)alloc((size_t)n * 512);
  unsigned char* h4 = (unsigned char*)alloc((size_t)n * 512);
  float* es1 = (float*)alloc((size_t)n * 32 * 4);
  float* ed1 = (float*)alloc((size_t)n * 32 * 4);
  float* es3 = (float*)alloc((size_t)n * 32 * 4);
  float* ed3 = (float*)alloc((size_t)n * 32 * 4);
  float* es2 = (float*)alloc((size_t)n * 32 * 4);
  float* ed2 = (float*)alloc((size_t)n * 32 * 4);
  float* es4 = (float*)alloc((size_t)n * 32 * 4);
  float* ed4 = (float*)alloc((size_t)n * 32 * 4);
  unsigned short* xsp = (unsigned short*)alloc((size_t)n * 64 * 2);
  unsigned short* xtp = (unsigned short*)alloc((size_t)n * 64 * 2);
  int* rowA = (int*)alloc((size_t)(n + 1) * 4);
  int* rowB = (int*)alloc((size_t)(n + 1) * 4);
  int* colA = (int*)alloc((size_t)(E + n) * 4);
  int* colB = (int*)alloc((size_t)(E + n) * 4);
  int* degAB = (int*)alloc((size_t)2 * n * 4);
  int* degA = degAB, * degB = degAB + n;
  int* curA = (int*)alloc((size_t)n * 4);
  int* curB = (int*)alloc((size_t)n * 4);
  float* was1 = (float*)alloc((size_t)128 * 32 * 4);
  float* wad1 = (float*)alloc((size_t)128 * 32 * 4);
  float* was3 = (float*)alloc((size_t)128 * 32 * 4);
  float* wad3 = (float*)alloc((size_t)128 * 32 * 4);

  static const int cidx[32] = {3,4,5, 7,8,9, 11,12,13, 15,16,17,
                               18,19,20,21,22,23,24,25,26,27,28,29,
                               30,31,32,33,34,35,36,37};
  PrepDesc pd;
  float* canon[38] = {nullptr};
  pd.ctotal = 0;
  for (int t = 0; t < 32; ++t) {
    int ii = cidx[t];
    canon[ii] = (float*)alloc((size_t)in_sizes[ii] * 4);
    pd.csrc[t] = d_in[ii];
    pd.cdst[t] = canon[ii];
    pd.cn[t] = in_sizes[ii];
    pd.ctotal += in_sizes[ii];
  }
  pd.x = d_in[0]; pd.xc = xc; pd.xp = xp;
  pd.W1 = d_in[2]; pd.W2 = d_in[6]; pd.W3 = d_in[10]; pd.W4 = d_in[14];
  pd.P1 = W1p; pd.P2 = W2p; pd.P3 = W3p; pd.P4 = W4p;
  pd.degAB = degAB;
  pd.ei = ei;
  pd.av[0] = d_in[3]; pd.av[1] = d_in[4]; pd.av[2] = d_in[11]; pd.av[3] = d_in[12];
  pd.wa[0] = was1; pd.wa[1] = wad1; pd.wa[2] = was3; pd.wa[3] = wad3;
  pd.nxb = (n * 128 / 8 + 255) / 256;   // vectorized 8/thread
  pd.xtotal = n * 128;
  pd.E = E;
  pd.nn = n;
  (void)ws_size; (void)n_in; (void)out_size;

  const int degblks = (E + 255) / 256;  // 313

  // ---- detect + zero degAB ----
  k_detect<<<9, 256, 0, stream>>>((const unsigned int*)d_in[0], flag, degAB, 2 * n);
  // ---- unified prep + degree count + Wa fold ----
  k_prep<<<pd.nxb + 288 + 4 + degblks + 64, 256, 0, stream>>>(pd, flag);
  // ---- CSR scan ----
  k_exscan2<<<2, 1024, 0, stream>>>(degA, degB, rowA, rowB, colA, colB, curA, curB, n);

  const int mt = n / 16;              // 625
  const int nrg = (mt + 3) / 4;       // 157
  const int mmblks64 = nrg * 8;
  const int mmblks16 = nrg * 2;
  const int gb = (n + 3) / 4;         // 2500

  // ---- stage 1: residual+GEMV -> scatter -> mm1 -> mm3 (merged) ----
  MM13XDesc md;
  md.resblks = mt; md.sblks = degblks; md.mmblks = mmblks64; md.mt = mt; md.E = E;
  md.ei = ei; md.colA = colA; md.colB = colB; md.curA = curA; md.curB = curB;
  md.xc = xc;
  for (int t = 0; t < 20; ++t) md.rp[t] = canon[18 + t];
  md.wa[0] = was1; md.wa[1] = wad1; md.wa[2] = was3; md.wa[3] = wad3;
  md.es1 = es1; md.ed1 = ed1; md.es3 = es3; md.ed3 = ed3;
  md.outbase = d_out; md.eoff = (size_t)2 * n * 16; md.n = n; md.flag = flag;
  md.Ap = xp; md.B1 = W1p; md.B3 = W3p; md.C1 = h1; md.C3 = h3;
  k_mm13x<<<mt + degblks + 2 * mmblks64, 256, 0, stream>>>(md);

  // ---- stage 2: gather64 both flows (2-deep pipeline, float2 es/ed) ----
  k_g64<<<2 * gb, 256, 0, stream>>>(h1, h3, es1, ed1, es3, ed3,
                                    rowA, colA, rowB, colB,
                                    canon[5], canon[13], xsp, xtp, n, gb);
  // ---- stage 3: mm2 + mm4 ----
  k_mm24<<<2 * mmblks16, 256, 0, stream>>>(xsp, xtp, W2p, W4p, h2, h4,
                                           canon[7], canon[8], canon[15], canon[16],
                                           es2, ed2, es4, ed4, mmblks16, mt);
  // ---- stage 4: gather16 both flows -> outputs 0,1 ----
  k_g16<<<2 * gb, 256, 0, stream>>>(h2, h4, es2, ed2, es4, ed4,
                                    rowA, colA, rowB, colB,
                                    canon[9], canon[17], d_out, n, gb, flag);
}

// Round 10
// 314.234 us; speedup vs baseline: 1.4720x; 1.0212x over previous
//
#include <hip/hip_runtime.h>
#include <stdint.h>

// ---------- bf16 helpers ----------
__device__ __forceinline__ float bf2f(unsigned short u) {
  union { unsigned int i; float f; } v; v.i = ((unsigned int)u) << 16; return v.f;
}
__device__ __forceinline__ unsigned short f2bf(float f) {
  union { float f; unsigned int i; } v; v.f = f;
  unsigned int i = v.i;
  unsigned int r = (i + 0x7fffu + ((i >> 16) & 1u)) >> 16;  // RNE
  return (unsigned short)r;
}

typedef __bf16 bf16x8 __attribute__((ext_vector_type(8)));
typedef float f32x4 __attribute__((ext_vector_type(4)));
typedef float f32x2 __attribute__((ext_vector_type(2)));
union ABfrag { int4 i4; bf16x8 v; };

// ---------- fp8 e4m3fn (OCP): HW path on gfx950, SW fallback ----------
#if __has_builtin(__builtin_amdgcn_cvt_pk_fp8_f32) && __has_builtin(__builtin_amdgcn_cvt_pk_f32_fp8)
#define HW_FP8 1
#else
#define HW_FP8 0
#endif

__device__ __forceinline__ unsigned char f2fp8_sw(float f) {
  union { float f; unsigned int u; } v; v.f = f;
  unsigned int s = (v.u >> 24) & 0x80;
  float a = fabsf(f);
  if (a >= 448.f) return (unsigned char)(s | 0x7E);
  v.f = a;
  int ex = (int)(v.u >> 23);
  unsigned int man = v.u & 0x7FFFFFu;
  if (ex >= 121) {
    unsigned int val = ((unsigned int)(ex - 120) << 3) | (man >> 20);
    unsigned int rem = man & 0xFFFFFu;
    if (rem > 0x80000u || (rem == 0x80000u && (val & 1))) val++;
    if (val > 0x7E) val = 0x7E;
    return (unsigned char)(s | val);
  }
  int q = (int)(a * 512.f + 0.5f);
  if (q > 8) q = 8;
  return (unsigned char)(s | (unsigned int)q);
}
__device__ __forceinline__ float fp8dec_sw(unsigned char c) {
  unsigned int e = (c >> 3) & 15u, m = c & 7u;
  float v;
  if (e) { union { unsigned int u; float f; } x; x.u = ((e + 120) << 23) | (m << 20); v = x.f; }
  else v = (float)m * 0.001953125f;
  return (c & 0x80) ? -v : v;
}
// pack 4 floats -> 4 fp8 bytes in one dword (bytes 0..3 = a0..a3)
__device__ __forceinline__ unsigned int pack4_fp8(float a0, float a1, float a2, float a3) {
#if HW_FP8
  int dw = __builtin_amdgcn_cvt_pk_fp8_f32(a0, a1, 0, false);
  dw = __builtin_amdgcn_cvt_pk_fp8_f32(a2, a3, dw, true);
  return (unsigned int)dw;
#else
  return (unsigned)f2fp8_sw(a0) | ((unsigned)f2fp8_sw(a1) << 8) |
         ((unsigned)f2fp8_sw(a2) << 16) | ((unsigned)f2fp8_sw(a3) << 24);
#endif
}
// select byte rr from each of 4 dwords -> one dword
__device__ __forceinline__ unsigned int bytesel4(uint4 v, int rr) {
#if __has_builtin(__builtin_amdgcn_perm)
  unsigned s = (unsigned)rr | ((unsigned)(rr + 4) << 8);
  unsigned p01 = __builtin_amdgcn_perm(v.y, v.x, s);
  unsigned p23 = __builtin_amdgcn_perm(v.w, v.z, s);
  return __builtin_amdgcn_perm(p23, p01, 0x05040100u);
#else
  int sh = rr * 8;
  return ((v.x >> sh) & 0xFFu) | (((v.y >> sh) & 0xFFu) << 8) |
         (((v.z >> sh) & 0xFFu) << 16) | (((v.w >> sh) & 0xFFu) << 24);
#endif
}
// decode 16 fp8 -> 8 packed float2 (keeps cvt_pk's natural pair output)
__device__ __forceinline__ void dec16p(int4 g, f32x2 o[8]) {
#if HW_FP8
  o[0] = __builtin_amdgcn_cvt_pk_f32_fp8(g.x, false);
  o[1] = __builtin_amdgcn_cvt_pk_f32_fp8(g.x, true);
  o[2] = __builtin_amdgcn_cvt_pk_f32_fp8(g.y, false);
  o[3] = __builtin_amdgcn_cvt_pk_f32_fp8(g.y, true);
  o[4] = __builtin_amdgcn_cvt_pk_f32_fp8(g.z, false);
  o[5] = __builtin_amdgcn_cvt_pk_f32_fp8(g.z, true);
  o[6] = __builtin_amdgcn_cvt_pk_f32_fp8(g.w, false);
  o[7] = __builtin_amdgcn_cvt_pk_f32_fp8(g.w, true);
#else
  unsigned int w[4] = {(unsigned)g.x, (unsigned)g.y, (unsigned)g.z, (unsigned)g.w};
#pragma unroll
  for (int d = 0; d < 4; ++d) {
    unsigned int x = w[d];
    o[d * 2 + 0] = (f32x2){fp8dec_sw((unsigned char)(x & 0xFF)),
                           fp8dec_sw((unsigned char)((x >> 8) & 0xFF))};
    o[d * 2 + 1] = (f32x2){fp8dec_sw((unsigned char)((x >> 16) & 0xFF)),
                           fp8dec_sw((unsigned char)((x >> 24) & 0xFF))};
  }
#endif
}

__device__ __forceinline__ float lrelu_clamp(float e) {
  e = (e > 0.f) ? e : 0.2f * e;
  return fminf(e, 80.f);
}

// ---------- dtype detection + degAB zeroing (merged) ----------
__global__ __launch_bounds__(256) void k_detect(const unsigned int* __restrict__ x, int* flag,
                                                int* __restrict__ degAB, int ndeg2) {
  if (blockIdx.x == 0) {
    __shared__ int cnt;
    if (threadIdx.x == 0) cnt = 0;
    __syncthreads();
    int c = 0;
    for (int i = threadIdx.x; i < 1024; i += 256) {
      unsigned int lo = x[i] & 0xFFFFu;
      int ex = (int)((lo >> 7) & 0xFF);
      if (ex >= 100 && ex <= 140) c++;
    }
    atomicAdd(&cnt, c);
    __syncthreads();
    if (threadIdx.x == 0) flag[0] = (cnt > 600) ? 1 : 0;  // 1 = bf16 inputs
    return;
  }
  for (int idx = (blockIdx.x - 1) * 256 + threadIdx.x; idx < ndeg2; idx += 8 * 256) degAB[idx] = 0;
}

// ---------- unified prep (+ degree count + attention-weight fold) ----------
struct PrepDesc {
  const void* csrc[32]; float* cdst[32]; int cn[32];
  const void* x; float* xc; unsigned short* xp;
  const void* W1; const void* W2; const void* W3; const void* W4;
  unsigned short* P1; unsigned short* P2; unsigned short* P3; unsigned short* P4;
  int* degAB;
  const int* ei;
  const void* av[4];   // as1, ad1, as3, ad3 (raw inputs)
  float* wa[4];        // Was1, Wad1, Was3, Wad3 [128x32]
  int nxb, xtotal, ctotal, E, nn;
};
__global__ __launch_bounds__(256) void k_prep(PrepDesc d, const int* __restrict__ flag) {
  int isbf = *flag;
  int b = blockIdx.x;
  if (b < d.nxb) {
    int t8 = b * 256 + threadIdx.x;
    int i8 = t8 * 8;
    if (i8 < d.xtotal) {
      float v[8];
      if (isbf) {
        int4 raw = *(const int4*)((const unsigned short*)d.x + i8);
        const unsigned short* u = (const unsigned short*)&raw;
#pragma unroll
        for (int j = 0; j < 8; ++j) v[j] = bf2f(u[j]);
      } else {
        float4 f0 = *(const float4*)((const float*)d.x + i8);
        float4 f1 = *(const float4*)((const float*)d.x + i8 + 4);
        v[0] = f0.x; v[1] = f0.y; v[2] = f0.z; v[3] = f0.w;
        v[4] = f1.x; v[5] = f1.y; v[6] = f1.z; v[7] = f1.w;
      }
      *(float4*)(d.xc + i8)     = (float4){v[0], v[1], v[2], v[3]};
      *(float4*)(d.xc + i8 + 4) = (float4){v[4], v[5], v[6], v[7]};
      int row = i8 >> 7, c0 = i8 & 127;
      int tm = row >> 4, mr = row & 15;
      int s = c0 >> 5, quad = (c0 >> 3) & 3;
      unsigned short o[8];
#pragma unroll
      for (int j = 0; j < 8; ++j) o[j] = f2bf(v[j]);
      size_t idx = (((size_t)tm * 4 + s) * 64 + quad * 16 + mr) * 8;
      *(int4*)(d.xp + idx) = *(const int4*)o;
    }
    return;
  }
  b -= d.nxb;
  if (b < 288) {
    int u = b * 256 + threadIdx.x;
    const void* W; unsigned short* P; int K, N, lu;
    if (u < 32768)      { W = d.W1; P = d.P1; K = 128; N = 2048; lu = u; }
    else if (u < 36864) { W = d.W2; P = d.P2; K = 64;  N = 512;  lu = u - 32768; }
    else if (u < 69632) { W = d.W3; P = d.P3; K = 128; N = 2048; lu = u - 36864; }
    else                { W = d.W4; P = d.P4; K = 64;  N = 512;  lu = u - 69632; }
    int ksteps = K >> 5;
    int g = lu / (ksteps * 64);
    int rem = lu - g * (ksteps * 64);
    int s = rem >> 6, lane = rem & 63;
    int mr = lane & 15, quad = lane >> 4;
    int col = g * 16 + mr;
    int kbase = s * 32 + quad * 8;
#pragma unroll
    for (int j = 0; j < 8; ++j) {
      size_t src = (size_t)(kbase + j) * N + col;
      float v = isbf ? bf2f(((const unsigned short*)W)[src]) : ((const float*)W)[src];
      P[(size_t)lu * 8 + j] = f2bf(v);
    }
    return;
  }
  b -= 288;
  if (b < 32) {  // canon copy: one block per tensor, direct indexing (no search)
    int t = b;
    int nels = d.cn[t];
    const void* src = d.csrc[t];
    float* dst = d.cdst[t];
    for (int idx = threadIdx.x; idx < nels; idx += 256) {
      float v = isbf ? bf2f(((const unsigned short*)src)[idx])
                     : ((const float*)src)[idx];
      dst[idx] = v;
    }
    return;
  }
  b -= 32;
  {
    int degblks = (d.E + 255) >> 8;
    if (b < degblks) {  // degree count (degAB zeroed by k_detect)
      int e = b * 256 + threadIdx.x;
      if (e < d.E) {
        atomicAdd(&d.degAB[d.ei[d.E + e]], 1);
        atomicAdd(&d.degAB[d.nn + d.ei[e]], 1);
      }
      return;
    }
    b -= degblks;
  }
  {  // Wa fold: b in [0,64): matrix m = b>>4, k-block = b&15
    int m = b >> 4, kb = b & 15;
    const void* W = (m < 2) ? d.W1 : d.W3;
    const void* A = d.av[m];
    float* out = d.wa[m];
    int k = kb * 8 + (threadIdx.x >> 5);   // 8 k per block
    int h = threadIdx.x & 31;              // 32 heads
    size_t wbase = (size_t)k * 2048 + h * 64;
    size_t abase = (size_t)h * 64;
    float acc = 0.f;
    if (isbf) {
      const unsigned short* Wb = (const unsigned short*)W;
      const unsigned short* Ab = (const unsigned short*)A;
#pragma unroll
      for (int v8 = 0; v8 < 8; ++v8) {
        int4 wv = *(const int4*)(Wb + wbase + v8 * 8);
        int4 av = *(const int4*)(Ab + abase + v8 * 8);
        const unsigned short* wu = (const unsigned short*)&wv;
        const unsigned short* au = (const unsigned short*)&av;
#pragma unroll
        for (int j = 0; j < 8; ++j) acc += bf2f(wu[j]) * bf2f(au[j]);
      }
    } else {
      const float* Wf = (const float*)W;
      const float* Af = (const float*)A;
#pragma unroll
      for (int v4 = 0; v4 < 16; ++v4) {
        float4 wv = *(const float4*)(Wf + wbase + v4 * 4);
        float4 av = *(const float4*)(Af + abase + v4 * 4);
        acc += wv.x * av.x + wv.y * av.y + wv.z * av.z + wv.w * av.w;
      }
    }
    out[k * 32 + h] = acc;
  }
}

// ---------- CSR exclusive scan ----------
__global__ __launch_bounds__(1024) void k_exscan2(const int* __restrict__ degA, const int* __restrict__ degB,
                                                  int* __restrict__ rowA, int* __restrict__ rowB,
                                                  int* __restrict__ colA, int* __restrict__ colB,
                                                  int* __restrict__ curA, int* __restrict__ curB, int n) {
  const int* deg = (blockIdx.x == 0) ? degA : degB;
  int* row = (blockIdx.x == 0) ? rowA : rowB;
  int* colx = (blockIdx.x == 0) ? colA : colB;
  int* curx = (blockIdx.x == 0) ? curA : curB;
  __shared__ int wsum[16], wbase[16];
  __shared__ int carry;
  if (threadIdx.x == 0) carry = 0;
  __syncthreads();
  int lane = threadIdx.x & 63, w = threadIdx.x >> 6;
  int chunks = (n + 1023) >> 10;
  for (int ch = 0; ch < chunks; ++ch) {
    int i = (ch << 10) + threadIdx.x;
    int v = (i < n) ? deg[i] : 0;
    int sc = v;
#pragma unroll
    for (int o = 1; o < 64; o <<= 1) { int t = __shfl_up(sc, o); if (lane >= o) sc += t; }
    if (lane == 63) wsum[w] = sc;
    __syncthreads();
    if (threadIdx.x < 16) {
      int v2 = wsum[threadIdx.x], s2 = v2;
#pragma unroll
      for (int o = 1; o < 16; o <<= 1) { int t = __shfl_up(s2, o); if (lane >= o) s2 += t; }
      wbase[threadIdx.x] = s2 - v2;
      if (threadIdx.x == 15) wsum[15] = s2;
    }
    __syncthreads();
    if (i < n) {
      int rv = carry + wbase[w] + (sc - v) + i;
      row[i] = rv;
      colx[rv] = i;
      curx[i] = rv + 1;
    }
    __syncthreads();
    if (threadIdx.x == 0) carry += wsum[15];
    __syncthreads();
  }
  if (threadIdx.x == 0) row[n] = carry + n;
}

// ---------- 64-row x 64-col per-wave GEMM body ----------
#define TILE_DW 288
template<int CH, int KSTEPS>
__device__ __forceinline__ void mm_es64_body(int rg, int cg, int MT,
    const unsigned short* __restrict__ Ap, const unsigned short* __restrict__ Bp,
    unsigned char* __restrict__ C, const float* __restrict__ a_s, const float* __restrict__ a_d,
    float* __restrict__ es, float* __restrict__ ed, int N, unsigned int* tile) {
  const int TI = KSTEPS * 64;
  int vt = MT - rg * 4; if (vt > 4) vt = 4;
  int wid = threadIdx.x >> 6;
  int tn = cg * 4 + wid;
  int lane = threadIdx.x & 63;
  int mr = lane & 15, quad = lane >> 4;
  const int4* ap = (const int4*)(Ap + (size_t)rg * 4 * TI * 8) + lane;
  const unsigned short* bp = Bp + ((size_t)tn * 4 * KSTEPS) * 512 + lane * 8;
  unsigned int* twave = tile + wid * TILE_DW;
  f32x4 acc[4][4];
#pragma unroll
  for (int rt = 0; rt < 4; ++rt)
#pragma unroll
    for (int nt = 0; nt < 4; ++nt) acc[rt][nt] = (f32x4){0.f, 0.f, 0.f, 0.f};
#pragma unroll
  for (int s = 0; s < KSTEPS; ++s) {
    ABfrag bfr[4];
#pragma unroll
    for (int nt = 0; nt < 4; ++nt) bfr[nt].i4 = *(const int4*)(bp + (size_t)(nt * KSTEPS + s) * 512);
    ABfrag afr[4];
#pragma unroll
    for (int rt = 0; rt < 4; ++rt) {
      int rti = (rt < vt) ? rt : 0;   // clamp: keep tail-row-group reads inside xp
      afr[rt].i4 = ap[rti * TI + s * 64];
    }
#pragma unroll
    for (int nt = 0; nt < 4; ++nt)
#pragma unroll
      for (int rt = 0; rt < 4; ++rt)
        acc[rt][nt] = __builtin_amdgcn_mfma_f32_16x16x32_bf16(afr[rt].v, bfr[nt].v, acc[rt][nt], 0, 0, 0);
  }
  int r16 = lane >> 2, seg = lane & 3;
  int qr = r16 >> 2, rr = r16 & 3;
#pragma unroll
  for (int rt = 0; rt < 4; ++rt) {
    if (rt < vt) {
      int tm = rg * 4 + rt;
#pragma unroll
      for (int nt = 0; nt < 4; ++nt) {
        unsigned int dwv = pack4_fp8(acc[rt][nt][0], acc[rt][nt][1], acc[rt][nt][2], acc[rt][nt][3]);
        twave[quad * 72 + nt * 16 + mr] = dwv;   // 2-way bank (free)
      }
      unsigned int out[4];
#pragma unroll
      for (int w = 0; w < 4; ++w) {
        uint4 v = *(const uint4*)&twave[qr * 72 + seg * 16 + 4 * w];
        out[w] = bytesel4(v, rr);
      }
      *(int4*)(C + (size_t)(tm * 16 + r16) * N + tn * 64 + seg * 16) = *(const int4*)out;
    }
  }
  if (CH == 16) {
    float ws[4], wd[4];
#pragma unroll
    for (int nt = 0; nt < 4; ++nt) {
      ws[nt] = a_s[(tn * 4 + nt) * 16 + mr];
      wd[nt] = a_d[(tn * 4 + nt) * 16 + mr];
    }
#pragma unroll
    for (int rt = 0; rt < 4; ++rt) {
      if (rt < vt) {
        int tm = rg * 4 + rt;
        float pes[4][4], ped[4][4];
#pragma unroll
        for (int nt = 0; nt < 4; ++nt)
#pragma unroll
          for (int r = 0; r < 4; ++r) { pes[nt][r] = acc[rt][nt][r] * ws[nt]; ped[nt][r] = acc[rt][nt][r] * wd[nt]; }
#pragma unroll
        for (int m = 1; m < 16; m <<= 1)
#pragma unroll
          for (int nt = 0; nt < 4; ++nt)
#pragma unroll
            for (int r = 0; r < 4; ++r) {
              pes[nt][r] += __shfl_xor(pes[nt][r], m);
              ped[nt][r] += __shfl_xor(ped[nt][r], m);
            }
        if (mr == 0) {
#pragma unroll
          for (int nt = 0; nt < 4; ++nt)
#pragma unroll
            for (int r = 0; r < 4; ++r) {
              int row = tm * 16 + quad * 4 + r;
              es[row * 32 + tn * 4 + nt] = pes[nt][r];
              ed[row * 32 + tn * 4 + nt] = ped[nt][r];
            }
        }
      }
    }
  }
}

// ---------- merged: residual+GEMV -> scatter -> mm1 -> mm3 ----------
union SM13 {
  struct { float xs[16][128]; float ha[16][16]; float tt[16][16]; } res;
  unsigned int tile[4 * TILE_DW];
};
struct MM13XDesc {
  int resblks, sblks, mmblks, mt, E;
  const int* ei; int* colA; int* colB; int* curA; int* curB;
  const float* xc;
  const float* rp[20];
  const float* wa[4];
  float* es1; float* ed1; float* es3; float* ed3;
  void* outbase; size_t eoff; int n;
  const int* flag;
  const unsigned short* Ap;
  const unsigned short* B1; const unsigned short* B3;
  unsigned char* C1; unsigned char* C3;
};
__global__ __launch_bounds__(256) void k_mm13x(MM13XDesc d) {
  __shared__ SM13 sm;
  int b = blockIdx.x;
  if (b < d.resblks) {
    int nodebase = b * 16;
    for (int t = threadIdx.x; t < 16 * 128; t += 256)
      sm.res.xs[t >> 7][t & 127] = d.xc[(size_t)(nodebase + (t >> 7)) * 128 + (t & 127)];
    __syncthreads();
    int ni = threadIdx.x >> 4, c = threadIdx.x & 15;
    // ---- es/ed GEMV (plain layout [row*32+h]) ----
    {
      const float* w0 = d.wa[0]; const float* w1 = d.wa[1];
      const float* w2 = d.wa[2]; const float* w3 = d.wa[3];
      float a0 = 0.f, a1 = 0.f, a2 = 0.f, a3 = 0.f, a4 = 0.f, a5 = 0.f, a6 = 0.f, a7 = 0.f;
#pragma unroll 4
      for (int k = 0; k < 128; ++k) {
        float xv = sm.res.xs[ni][k];
        int o = k * 32 + c;
        a0 += xv * w0[o]; a1 += xv * w0[o + 16];
        a2 += xv * w1[o]; a3 += xv * w1[o + 16];
        a4 += xv * w2[o]; a5 += xv * w2[o + 16];
        a6 += xv * w3[o]; a7 += xv * w3[o + 16];
      }
      int row = nodebase + ni;
      d.es1[row * 32 + c] = a0; d.es1[row * 32 + c + 16] = a1;
      d.ed1[row * 32 + c] = a2; d.ed1[row * 32 + c + 16] = a3;
      d.es3[row * 32 + c] = a4; d.es3[row * 32 + c + 16] = a5;
      d.ed3[row * 32 + c] = a6; d.ed3[row * 32 + c + 16] = a7;
    }
    // ---- residual MLP ----
    const float* rwa = d.rp[0]; const float* rba = d.rp[1];
    const float* bn1g = d.rp[2]; const float* bn1b = d.rp[3];
    const float* bn1m = d.rp[4]; const float* bn1v = d.rp[5];
    const float* rwb = d.rp[6]; const float* rbb = d.rp[7];
    const float* bn2g = d.rp[8]; const float* bn2b = d.rp[9];
    const float* bn2m = d.rp[10]; const float* bn2v = d.rp[11];
    const float* wsc = d.rp[12]; const float* bsc = d.rp[13];
    const float* bnsg = d.rp[14]; const float* bnsb = d.rp[15];
    const float* bnsm = d.rp[16]; const float* bnsv = d.rp[17];
    const float* wfc = d.rp[18]; const float* bfc = d.rp[19];
    float ya = 0.f, ysc = 0.f;
#pragma unroll 8
    for (int k = 0; k < 128; ++k) {
      float xv = sm.res.xs[ni][k];
      ya  += xv * rwa[k * 16 + c];
      ysc += xv * wsc[k * 16 + c];
    }
    ya += rba[c]; ysc += bsc[c];
    float s1 = bn1g[c] * rsqrtf(bn1v[c] + 1e-5f);
    ya = (ya - bn1m[c]) * s1 + bn1b[c];
    ya = fmaxf(ya, 0.f);
    float ss = bnsg[c] * rsqrtf(bnsv[c] + 1e-5f);
    ysc = (ysc - bnsm[c]) * ss + bnsb[c];
    sm.res.ha[ni][c] = ya;
    __syncthreads();
    float h2 = rbb[c];
#pragma unroll
    for (int k = 0; k < 16; ++k) h2 += sm.res.ha[ni][k] * rwb[k * 16 + c];
    float s2 = bn2g[c] * rsqrtf(bn2v[c] + 1e-5f);
    h2 = (h2 - bn2m[c]) * s2 + bn2b[c];
    sm.res.tt[ni][c] = fmaxf(h2 + ysc, 0.f);
    __syncthreads();
    float o = bfc[c];
#pragma unroll
    for (int k = 0; k < 16; ++k) o += sm.res.tt[ni][k] * wfc[k * 16 + c];
    size_t oo = d.eoff + (size_t)(nodebase + ni) * 16 + c;
    if (*d.flag) ((unsigned short*)d.outbase)[oo] = f2bf(o);
    else         ((float*)d.outbase)[oo] = o;
    return;
  }
  b -= d.resblks;
  if (b < d.sblks) {  // CSR scatter
    int e = b * 256 + threadIdx.x;
    if (e < d.E) {
      int s = d.ei[e], dd = d.ei[d.E + e];
      d.colA[atomicAdd(&d.curA[dd], 1)] = s;
      d.colB[atomicAdd(&d.curB[s], 1)] = dd;
    }
    return;
  }
  b -= d.sblks;
  if (b < d.mmblks) {
    mm_es64_body<64,4>(b >> 3, b & 7, d.mt, d.Ap, d.B1, d.C1, nullptr, nullptr, nullptr, nullptr, 2048, sm.tile);
    return;
  }
  b -= d.mmblks;
  mm_es64_body<64,4>(b >> 3, b & 7, d.mt, d.Ap, d.B3, d.C3, nullptr, nullptr, nullptr, nullptr, 2048, sm.tile);
}

// ---------- merged gather64; TWO WAVES per node (one per 1KB half-row) ----------
// Block = 4 waves = 2 nodes x 2 halves. Each wave handles 16 heads (half*16 + lane>>2),
// iterates edges with 1-deep prefetch, reduces its half, combines via LDS.
__global__ __launch_bounds__(256) void k_g64(const unsigned char* __restrict__ h1,
                                             const unsigned char* __restrict__ h3,
                                             const float* __restrict__ es1, const float* __restrict__ ed1,
                                             const float* __restrict__ es3, const float* __restrict__ ed3,
                                             const int* __restrict__ rowA, const int* __restrict__ colA,
                                             const int* __restrict__ rowB, const int* __restrict__ colB,
                                             const float* __restrict__ b1, const float* __restrict__ b3,
                                             unsigned short* __restrict__ xsp, unsigned short* __restrict__ xtp,
                                             int n, int gb) {
  __shared__ float part[2][2][64];   // [node_in_block][half][64 ch]
  int b = blockIdx.x;
  const unsigned char* h; const float *es, *ed, *bias; const int *rowp, *col; unsigned short* outp;
  if (b < gb) { h = h1; es = es1; ed = ed1; rowp = rowA; col = colA; bias = b1; outp = xsp; }
  else { b -= gb; h = h3; es = es3; ed = ed3; rowp = rowB; col = colB; bias = b3; outp = xtp; }
  int wid = threadIdx.x >> 6, lane = threadIdx.x & 63;
  int nb = wid >> 1, half = wid & 1;
  int i = b * 2 + nb;
  bool active = (i < n);
  int hd = half * 16 + (lane >> 2);
  float e0 = 0.f;
  int beg = 0, deg = 0;
  if (active) {
    e0 = ed[i * 32 + hd];
    beg = rowp[i];
    deg = rowp[i + 1] - beg;              // >= 1 (self-loop)
  }
  int colv = (lane < deg) ? col[beg + lane] : 0;
  f32x2 acc[8];
#pragma unroll
  for (int k = 0; k < 8; ++k) acc[k] = (f32x2){0.f, 0.f};
  float Z = 0.f;
  if (active) {
    int s0 = __shfl(colv, 0);
    const int4* hp = (const int4*)(h + (size_t)s0 * 2048 + (size_t)half * 1024);
    int4 ng = hp[lane];
    float ne = es[s0 * 32 + hd];
    for (int j = 0; j < deg; ++j) {
      int4 g = ng; float ee = ne;
      int jn = j + 1;
      if (jn < deg) {                     // wave-uniform branch
        int sn = (jn < 64) ? __shfl(colv, jn) : col[beg + jn];
        const int4* hq = (const int4*)(h + (size_t)sn * 2048 + (size_t)half * 1024);
        ng = hq[lane];
        ne = es[sn * 32 + hd];
      }
      float q = __expf(lrelu_clamp(ee + e0));
      Z += q;
      f32x2 d[8];
      dec16p(g, d);
      f32x2 qv = (f32x2){q, q};
#pragma unroll
      for (int k = 0; k < 8; ++k) acc[k] = __builtin_elementwise_fma(qv, d[k], acc[k]);
    }
  }
  float zi = active ? (1.0f / Z) : 0.f;
  f32x2 ziv = (f32x2){zi, zi};
  f32x2 v2[8];
#pragma unroll
  for (int k = 0; k < 8; ++k) v2[k] = acc[k] * ziv;
  // reduce across this half's 16 head-groups (lanes sharing lane&3)
#pragma unroll
  for (int m = 4; m < 64; m <<= 1)
#pragma unroll
    for (int k = 0; k < 8; ++k) {
      v2[k].x += __shfl_xor(v2[k].x, m);
      v2[k].y += __shfl_xor(v2[k].y, m);
    }
  if (lane < 4) {
#pragma unroll
    for (int k = 0; k < 8; ++k)
      *(float2*)&part[nb][half][lane * 16 + 2 * k] = (float2){v2[k].x, v2[k].y};
  }
  __syncthreads();
  if (half == 0 && lane < 4 && active) {
    float v[16];
#pragma unroll
    for (int k = 0; k < 16; ++k)
      v[k] = part[nb][0][lane * 16 + k] + part[nb][1][lane * 16 + k];
    int tm = i >> 4, mr = i & 15;
    unsigned short ob[16];
#pragma unroll
    for (int k = 0; k < 16; ++k) {
      float t = v[k] * (1.f / 32.f) + bias[lane * 16 + k];
      t = (t > 0.f) ? t : (__expf(t) - 1.f);   // elu
      ob[k] = f2bf(t);
    }
    int s0w = lane >> 1;
#pragma unroll
    for (int g2 = 0; g2 < 2; ++g2) {
      size_t idx = (((size_t)tm * 2 + s0w) * 64 + ((lane & 1) * 2 + g2) * 16 + mr) * 8;
      *(int4*)(outp + idx) = *(const int4*)(ob + g2 * 8);  // packed-A bf16
    }
  }
}

// ---------- merged mm2 + mm4 (es/ed kept in-body) ----------
__global__ __launch_bounds__(256) void k_mm24(const unsigned short* __restrict__ xsp,
                                              const unsigned short* __restrict__ xtp,
                                              const unsigned short* __restrict__ W2p,
                                              const unsigned short* __restrict__ W4p,
                                              unsigned char* __restrict__ h2, unsigned char* __restrict__ h4,
                                              const float* __restrict__ as2, const float* __restrict__ ad2,
                                              const float* __restrict__ as4, const float* __restrict__ ad4,
                                              float* __restrict__ es2, float* __restrict__ ed2,
                                              float* __restrict__ es4, float* __restrict__ ed4,
                                              int mmblks, int mt) {
  __shared__ unsigned int tile[4 * TILE_DW];
  int b = blockIdx.x;
  if (b < mmblks)
    mm_es64_body<16,2>(b >> 1, b & 1, mt, xsp, W2p, h2, as2, ad2, es2, ed2, 512, tile);
  else {
    b -= mmblks;
    mm_es64_body<16,2>(b >> 1, b & 1, mt, xtp, W4p, h4, as4, ad4, es4, ed4, 512, tile);
  }
}

// ---------- merged gather16; ONE WAVE per node (round-8 form) ----------
__global__ __launch_bounds__(256) void k_g16(const unsigned char* __restrict__ h2,
                                             const unsigned char* __restrict__ h4,
                                             const float* __restrict__ es2, const float* __restrict__ ed2,
                                             const float* __restrict__ es4, const float* __restrict__ ed4,
                                             const int* __restrict__ rowA, const int* __restrict__ colA,
                                             const int* __restrict__ rowB, const int* __restrict__ colB,
                                             const float* __restrict__ b2, const float* __restrict__ b4,
                                             void* __restrict__ outbase, int n, int gb,
                                             const int* __restrict__ flag) {
  int b = blockIdx.x;
  const unsigned char* h; const float *es, *ed, *bias; const int *rowp, *col; size_t eoff;
  if (b < gb) { h = h2; es = es2; ed = ed2; rowp = rowA; col = colA; bias = b2; eoff = 0; }
  else { b -= gb; h = h4; es = es4; ed = ed4; rowp = rowB; col = colB; bias = b4; eoff = (size_t)n * 16; }
  int wid = threadIdx.x >> 6, lane = threadIdx.x & 63;
  int i = b * 4 + wid;
  if (i >= n) return;
  int hh = lane & 31, j2 = lane >> 5;
  float ev = ed[i * 32 + hh];
  int beg = rowp[i], end = rowp[i + 1];
  int deg = end - beg;
  int colv = (lane < deg) ? col[beg + lane] : 0;
  f32x2 acc[8];
#pragma unroll
  for (int k = 0; k < 8; ++k) acc[k] = (f32x2){0.f, 0.f};
  float Z = 0.f;
  int j = j2;
  int4 ng = (int4){0, 0, 0, 0};
  float ne = 0.f;
  if (j < deg) {
    int s = __shfl(colv, j);
    ng = ((const int4*)(h + (size_t)s * 512))[hh];
    ne = es[s * 32 + hh];
  }
  for (; j < deg; j += 2) {
    int4 g = ng; float ee = ne;
    int jn = j + 2;
    if (jn < deg) {
      int sn = (jn < 64) ? __shfl(colv, jn) : col[beg + jn];
      ng = ((const int4*)(h + (size_t)sn * 512))[hh];
      ne = es[sn * 32 + hh];
    }
    float q = __expf(lrelu_clamp(ee + ev));
    Z += q;
    f32x2 d[8];
    dec16p(g, d);
    f32x2 qv = (f32x2){q, q};
#pragma unroll
    for (int k = 0; k < 8; ++k) acc[k] = __builtin_elementwise_fma(qv, d[k], acc[k]);
  }
  Z += __shfl_xor(Z, 32);
  float zi = 1.0f / Z;
  f32x2 ziv = (f32x2){zi, zi};
  f32x2 v2[8];
#pragma unroll
  for (int k = 0; k < 8; ++k) v2[k] = acc[k] * ziv;
#pragma unroll
  for (int m = 1; m < 64; m <<= 1)
#pragma unroll
    for (int k = 0; k < 8; ++k) {
      v2[k].x += __shfl_xor(v2[k].x, m);
      v2[k].y += __shfl_xor(v2[k].y, m);
    }
  if (lane == 0) {
    float v[16];
#pragma unroll
    for (int k = 0; k < 8; ++k) { v[2 * k] = v2[k].x; v[2 * k + 1] = v2[k].y; }
    int isbf = *flag;
    if (isbf) {
      unsigned short ob[16];
#pragma unroll
      for (int k = 0; k < 16; ++k) {
        float t = v[k] * (1.f / 32.f) + bias[k];
        t = (t > 0.f) ? t : (__expf(t) - 1.f);
        ob[k] = f2bf(t);
      }
      unsigned short* o = (unsigned short*)outbase + eoff + (size_t)i * 16;
      *(int4*)o = *(const int4*)ob;
      *(int4*)(o + 8) = *(const int4*)(ob + 8);
    } else {
      float* o = (float*)outbase + eoff + (size_t)i * 16;
#pragma unroll
      for (int k = 0; k < 16; ++k) {
        float t = v[k] * (1.f / 32.f) + bias[k];
        t = (t > 0.f) ? t : (__expf(t) - 1.f);
        o[k] = t;
      }
    }
  }
}

extern "C" void kernel_launch(void* const* d_in, const int* in_sizes, int n_in,
                              void* d_out, int out_size, void* d_ws, size_t ws_size,
                              hipStream_t stream) {
  const int n = in_sizes[0] / 128;   // 10000
  const int E = in_sizes[1] / 2;     // 80000
  const int* ei = (const int*)d_in[1];

  char* wsp = (char*)d_ws; size_t off = 0;
  auto alloc = [&](size_t bytes) -> void* {
    void* p = wsp + off; off = (off + bytes + 255) & ~(size_t)255; return p;
  };
  int* flag = (int*)alloc(4);
  float* xc = (float*)alloc((size_t)n * 128 * 4);
  unsigned short* xp = (unsigned short*)alloc((size_t)n * 128 * 2);
  unsigned short* W1p = (unsigned short*)alloc((size_t)2048 * 128 * 2);
  unsigned short* W2p = (unsigned short*)alloc((size_t)512 * 64 * 2);
  unsigned short* W3p = (unsigned short*)alloc((size_t)2048 * 128 * 2);
  unsigned short* W4p = (unsigned short*)alloc((size_t)512 * 64 * 2);
  unsigned char* h1 = (unsigned char*)alloc((size_t)n * 2048);   // fp8
  unsigned char* h3 = (unsigned char*)alloc((size_t)n * 2048);
  unsigned char* h2 = (unsigned char*)alloc((size_t)n * 512);
  unsigned char* h4 = (unsigned char*)alloc((size_t)n * 512);
  float* es1 = (float*)alloc((size_t)n * 32 * 4);
  float* ed1 = (float*)alloc((size_t)n * 32 * 4);
  float* es3 = (float*)alloc((size_t)n * 32 * 4);
  float* ed3 = (float*)alloc((size_t)n * 32 * 4);
  float* es2 = (float*)alloc((size_t)n * 32 * 4);
  float* ed2 = (float*)alloc((size_t)n * 32 * 4);
  float* es4 = (float*)alloc((size_t)n * 32 * 4);
  float* ed4 = (float*)alloc((size_t)n * 32 * 4);
  unsigned short* xsp = (unsigned short*)alloc((size_t)n * 64 * 2);
  unsigned short* xtp = (unsigned short*)alloc((size_t)n * 64 * 2);
  int* rowA = (int*)alloc((size_t)(n + 1) * 4);
  int* rowB = (int*)alloc((size_t)(n + 1) * 4);
  int* colA = (int*)alloc((size_t)(E + n) * 4);
  int* colB = (int*)alloc((size_t)(E + n) * 4);
  int* degAB = (int*)alloc((size_t)2 * n * 4);
  int* degA = degAB, * degB = degAB + n;
  int* curA = (int*)alloc((size_t)n * 4);
  int* curB = (int*)alloc((size_t)n * 4);
  float* was1 = (float*)alloc((size_t)128 * 32 * 4);
  float* wad1 = (float*)alloc((size_t)128 * 32 * 4);
  float* was3 = (float*)alloc((size_t)128 * 32 * 4);
  float* wad3 = (float*)alloc((size_t)128 * 32 * 4);

  static const int cidx[32] = {3,4,5, 7,8,9, 11,12,13, 15,16,17,
                               18,19,20,21,22,23,24,25,26,27,28,29,
                               30,31,32,33,34,35,36,37};
  PrepDesc pd;
  float* canon[38] = {nullptr};
  pd.ctotal = 0;
  for (int t = 0; t < 32; ++t) {
    int ii = cidx[t];
    canon[ii] = (float*)alloc((size_t)in_sizes[ii] * 4);
    pd.csrc[t] = d_in[ii];
    pd.cdst[t] = canon[ii];
    pd.cn[t] = in_sizes[ii];
    pd.ctotal += in_sizes[ii];
  }
  pd.x = d_in[0]; pd.xc = xc; pd.xp = xp;
  pd.W1 = d_in[2]; pd.W2 = d_in[6]; pd.W3 = d_in[10]; pd.W4 = d_in[14];
  pd.P1 = W1p; pd.P2 = W2p; pd.P3 = W3p; pd.P4 = W4p;
  pd.degAB = degAB;
  pd.ei = ei;
  pd.av[0] = d_in[3]; pd.av[1] = d_in[4]; pd.av[2] = d_in[11]; pd.av[3] = d_in[12];
  pd.wa[0] = was1; pd.wa[1] = wad1; pd.wa[2] = was3; pd.wa[3] = wad3;
  pd.nxb = (n * 128 / 8 + 255) / 256;   // vectorized 8/thread
  pd.xtotal = n * 128;
  pd.E = E;
  pd.nn = n;
  (void)ws_size; (void)n_in; (void)out_size;

  const int degblks = (E + 255) / 256;  // 313

  // ---- detect + zero degAB ----
  k_detect<<<9, 256, 0, stream>>>((const unsigned int*)d_in[0], flag, degAB, 2 * n);
  // ---- unified prep + canon(32 direct blocks) + degree count + Wa fold ----
  k_prep<<<pd.nxb + 288 + 32 + degblks + 64, 256, 0, stream>>>(pd, flag);
  // ---- CSR scan ----
  k_exscan2<<<2, 1024, 0, stream>>>(degA, degB, rowA, rowB, colA, colB, curA, curB, n);

  const int mt = n / 16;              // 625
  const int nrg = (mt + 3) / 4;       // 157
  const int mmblks64 = nrg * 8;
  const int mmblks16 = nrg * 2;
  const int gb2 = (n + 1) / 2;        // 5000 (2 nodes per block)
  const int gb = (n + 3) / 4;         // 2500

  // ---- stage 1: residual+GEMV -> scatter -> mm1 -> mm3 (merged) ----
  MM13XDesc md;
  md.resblks = mt; md.sblks = degblks; md.mmblks = mmblks64; md.mt = mt; md.E = E;
  md.ei = ei; md.colA = colA; md.colB = colB; md.curA = curA; md.curB = curB;
  md.xc = xc;
  for (int t = 0; t < 20; ++t) md.rp[t] = canon[18 + t];
  md.wa[0] = was1; md.wa[1] = wad1; md.wa[2] = was3; md.wa[3] = wad3;
  md.es1 = es1; md.ed1 = ed1; md.es3 = es3; md.ed3 = ed3;
  md.outbase = d_out; md.eoff = (size_t)2 * n * 16; md.n = n; md.flag = flag;
  md.Ap = xp; md.B1 = W1p; md.B3 = W3p; md.C1 = h1; md.C3 = h3;
  k_mm13x<<<mt + degblks + 2 * mmblks64, 256, 0, stream>>>(md);

  // ---- stage 2: gather64 both flows (2 waves per node) ----
  k_g64<<<2 * gb2, 256, 0, stream>>>(h1, h3, es1, ed1, es3, ed3,
                                     rowA, colA, rowB, colB,
                                     canon[5], canon[13], xsp, xtp, n, gb2);
  // ---- stage 3: mm2 + mm4 ----
  k_mm24<<<2 * mmblks16, 256, 0, stream>>>(xsp, xtp, W2p, W4p, h2, h4,
                                           canon[7], canon[8], canon[15], canon[16],
                                           es2, ed2, es4, ed4, mmblks16, mt);
  // ---- stage 4: gather16 both flows -> outputs 0,1 ----
  k_g16<<<2 * gb, 256, 0, stream>>>(h2, h4, es2, ed2, es4, ed4,
                                    rowA, colA, rowB, colB,
                                    canon[9], canon[17], d_out, n, gb, flag);
}

// Round 11
// 306.478 us; speedup vs baseline: 1.5093x; 1.0253x over previous
//
#include <hip/hip_runtime.h>
#include <stdint.h>

// ---------- bf16 helpers ----------
__device__ __forceinline__ float bf2f(unsigned short u) {
  union { unsigned int i; float f; } v; v.i = ((unsigned int)u) << 16; return v.f;
}
__device__ __forceinline__ unsigned short f2bf(float f) {
  union { float f; unsigned int i; } v; v.f = f;
  unsigned int i = v.i;
  unsigned int r = (i + 0x7fffu + ((i >> 16) & 1u)) >> 16;  // RNE
  return (unsigned short)r;
}

typedef __bf16 bf16x8 __attribute__((ext_vector_type(8)));
typedef float f32x4 __attribute__((ext_vector_type(4)));
typedef float f32x2 __attribute__((ext_vector_type(2)));
union ABfrag { int4 i4; bf16x8 v; };

// ---------- fp8 e4m3fn (OCP): HW path on gfx950, SW fallback ----------
#if __has_builtin(__builtin_amdgcn_cvt_pk_fp8_f32) && __has_builtin(__builtin_amdgcn_cvt_pk_f32_fp8)
#define HW_FP8 1
#else
#define HW_FP8 0
#endif

__device__ __forceinline__ unsigned char f2fp8_sw(float f) {
  union { float f; unsigned int u; } v; v.f = f;
  unsigned int s = (v.u >> 24) & 0x80;
  float a = fabsf(f);
  if (a >= 448.f) return (unsigned char)(s | 0x7E);
  v.f = a;
  int ex = (int)(v.u >> 23);
  unsigned int man = v.u & 0x7FFFFFu;
  if (ex >= 121) {
    unsigned int val = ((unsigned int)(ex - 120) << 3) | (man >> 20);
    unsigned int rem = man & 0xFFFFFu;
    if (rem > 0x80000u || (rem == 0x80000u && (val & 1))) val++;
    if (val > 0x7E) val = 0x7E;
    return (unsigned char)(s | val);
  }
  int q = (int)(a * 512.f + 0.5f);
  if (q > 8) q = 8;
  return (unsigned char)(s | (unsigned int)q);
}
__device__ __forceinline__ float fp8dec_sw(unsigned char c) {
  unsigned int e = (c >> 3) & 15u, m = c & 7u;
  float v;
  if (e) { union { unsigned int u; float f; } x; x.u = ((e + 120) << 23) | (m << 20); v = x.f; }
  else v = (float)m * 0.001953125f;
  return (c & 0x80) ? -v : v;
}
// pack 4 floats -> 4 fp8 bytes in one dword (bytes 0..3 = a0..a3)
__device__ __forceinline__ unsigned int pack4_fp8(float a0, float a1, float a2, float a3) {
#if HW_FP8
  int dw = __builtin_amdgcn_cvt_pk_fp8_f32(a0, a1, 0, false);
  dw = __builtin_amdgcn_cvt_pk_fp8_f32(a2, a3, dw, true);
  return (unsigned int)dw;
#else
  return (unsigned)f2fp8_sw(a0) | ((unsigned)f2fp8_sw(a1) << 8) |
         ((unsigned)f2fp8_sw(a2) << 16) | ((unsigned)f2fp8_sw(a3) << 24);
#endif
}
// select byte rr from each of 4 dwords -> one dword
__device__ __forceinline__ unsigned int bytesel4(uint4 v, int rr) {
#if __has_builtin(__builtin_amdgcn_perm)
  unsigned s = (unsigned)rr | ((unsigned)(rr + 4) << 8);
  unsigned p01 = __builtin_amdgcn_perm(v.y, v.x, s);
  unsigned p23 = __builtin_amdgcn_perm(v.w, v.z, s);
  return __builtin_amdgcn_perm(p23, p01, 0x05040100u);
#else
  int sh = rr * 8;
  return ((v.x >> sh) & 0xFFu) | (((v.y >> sh) & 0xFFu) << 8) |
         (((v.z >> sh) & 0xFFu) << 16) | (((v.w >> sh) & 0xFFu) << 24);
#endif
}
// decode 16 fp8 -> 8 packed float2 (keeps cvt_pk's natural pair output)
__device__ __forceinline__ void dec16p(int4 g, f32x2 o[8]) {
#if HW_FP8
  o[0] = __builtin_amdgcn_cvt_pk_f32_fp8(g.x, false);
  o[1] = __builtin_amdgcn_cvt_pk_f32_fp8(g.x, true);
  o[2] = __builtin_amdgcn_cvt_pk_f32_fp8(g.y, false);
  o[3] = __builtin_amdgcn_cvt_pk_f32_fp8(g.y, true);
  o[4] = __builtin_amdgcn_cvt_pk_f32_fp8(g.z, false);
  o[5] = __builtin_amdgcn_cvt_pk_f32_fp8(g.z, true);
  o[6] = __builtin_amdgcn_cvt_pk_f32_fp8(g.w, false);
  o[7] = __builtin_amdgcn_cvt_pk_f32_fp8(g.w, true);
#else
  unsigned int w[4] = {(unsigned)g.x, (unsigned)g.y, (unsigned)g.z, (unsigned)g.w};
#pragma unroll
  for (int d = 0; d < 4; ++d) {
    unsigned int x = w[d];
    o[d * 2 + 0] = (f32x2){fp8dec_sw((unsigned char)(x & 0xFF)),
                           fp8dec_sw((unsigned char)((x >> 8) & 0xFF))};
    o[d * 2 + 1] = (f32x2){fp8dec_sw((unsigned char)((x >> 16) & 0xFF)),
                           fp8dec_sw((unsigned char)((x >> 24) & 0xFF))};
  }
#endif
}

__device__ __forceinline__ float lrelu_clamp(float e) {
  e = (e > 0.f) ? e : 0.2f * e;
  return fminf(e, 80.f);
}

// ---------- dtype detection + degAB zeroing (merged) ----------
__global__ __launch_bounds__(256) void k_detect(const unsigned int* __restrict__ x, int* flag,
                                                int* __restrict__ degAB, int ndeg2) {
  if (blockIdx.x == 0) {
    __shared__ int cnt;
    if (threadIdx.x == 0) cnt = 0;
    __syncthreads();
    int c = 0;
    for (int i = threadIdx.x; i < 1024; i += 256) {
      unsigned int lo = x[i] & 0xFFFFu;
      int ex = (int)((lo >> 7) & 0xFF);
      if (ex >= 100 && ex <= 140) c++;
    }
    atomicAdd(&cnt, c);
    __syncthreads();
    if (threadIdx.x == 0) flag[0] = (cnt > 600) ? 1 : 0;  // 1 = bf16 inputs
    return;
  }
  for (int idx = (blockIdx.x - 1) * 256 + threadIdx.x; idx < ndeg2; idx += 8 * 256) degAB[idx] = 0;
}

// ---------- unified prep (+ canon direct + degree count + Wa fold) ----------
struct PrepDesc {
  const void* csrc[32]; float* cdst[32]; int cn[32];
  const void* x; float* xc; unsigned short* xp;
  const void* W1; const void* W2; const void* W3; const void* W4;
  unsigned short* P1; unsigned short* P2; unsigned short* P3; unsigned short* P4;
  int* degAB;
  const int* ei;
  const void* av[4];   // as1, ad1, as3, ad3 (raw inputs)
  float* wa[4];        // Was1, Wad1, Was3, Wad3 [128x32]
  int nxb, xtotal, ctotal, E, nn;
};
__global__ __launch_bounds__(256) void k_prep(PrepDesc d, const int* __restrict__ flag) {
  int isbf = *flag;
  int b = blockIdx.x;
  if (b < d.nxb) {
    int t8 = b * 256 + threadIdx.x;
    int i8 = t8 * 8;
    if (i8 < d.xtotal) {
      float v[8];
      if (isbf) {
        int4 raw = *(const int4*)((const unsigned short*)d.x + i8);
        const unsigned short* u = (const unsigned short*)&raw;
#pragma unroll
        for (int j = 0; j < 8; ++j) v[j] = bf2f(u[j]);
      } else {
        float4 f0 = *(const float4*)((const float*)d.x + i8);
        float4 f1 = *(const float4*)((const float*)d.x + i8 + 4);
        v[0] = f0.x; v[1] = f0.y; v[2] = f0.z; v[3] = f0.w;
        v[4] = f1.x; v[5] = f1.y; v[6] = f1.z; v[7] = f1.w;
      }
      *(float4*)(d.xc + i8)     = (float4){v[0], v[1], v[2], v[3]};
      *(float4*)(d.xc + i8 + 4) = (float4){v[4], v[5], v[6], v[7]};
      int row = i8 >> 7, c0 = i8 & 127;
      int tm = row >> 4, mr = row & 15;
      int s = c0 >> 5, quad = (c0 >> 3) & 3;
      unsigned short o[8];
#pragma unroll
      for (int j = 0; j < 8; ++j) o[j] = f2bf(v[j]);
      size_t idx = (((size_t)tm * 4 + s) * 64 + quad * 16 + mr) * 8;
      *(int4*)(d.xp + idx) = *(const int4*)o;
    }
    return;
  }
  b -= d.nxb;
  if (b < 288) {
    int u = b * 256 + threadIdx.x;
    const void* W; unsigned short* P; int K, N, lu;
    if (u < 32768)      { W = d.W1; P = d.P1; K = 128; N = 2048; lu = u; }
    else if (u < 36864) { W = d.W2; P = d.P2; K = 64;  N = 512;  lu = u - 32768; }
    else if (u < 69632) { W = d.W3; P = d.P3; K = 128; N = 2048; lu = u - 36864; }
    else                { W = d.W4; P = d.P4; K = 64;  N = 512;  lu = u - 69632; }
    int ksteps = K >> 5;
    int g = lu / (ksteps * 64);
    int rem = lu - g * (ksteps * 64);
    int s = rem >> 6, lane = rem & 63;
    int mr = lane & 15, quad = lane >> 4;
    int col = g * 16 + mr;
    int kbase = s * 32 + quad * 8;
#pragma unroll
    for (int j = 0; j < 8; ++j) {
      size_t src = (size_t)(kbase + j) * N + col;
      float v = isbf ? bf2f(((const unsigned short*)W)[src]) : ((const float*)W)[src];
      P[(size_t)lu * 8 + j] = f2bf(v);
    }
    return;
  }
  b -= 288;
  if (b < 32) {  // canon copy: one block per tensor, direct indexing (no search)
    int t = b;
    int nels = d.cn[t];
    const void* src = d.csrc[t];
    float* dst = d.cdst[t];
    for (int idx = threadIdx.x; idx < nels; idx += 256) {
      float v = isbf ? bf2f(((const unsigned short*)src)[idx])
                     : ((const float*)src)[idx];
      dst[idx] = v;
    }
    return;
  }
  b -= 32;
  {
    int degblks = (d.E + 255) >> 8;
    if (b < degblks) {  // degree count (degAB zeroed by k_detect)
      int e = b * 256 + threadIdx.x;
      if (e < d.E) {
        atomicAdd(&d.degAB[d.ei[d.E + e]], 1);
        atomicAdd(&d.degAB[d.nn + d.ei[e]], 1);
      }
      return;
    }
    b -= degblks;
  }
  {  // Wa fold: b in [0,64): matrix m = b>>4, k-block = b&15
    int m = b >> 4, kb = b & 15;
    const void* W = (m < 2) ? d.W1 : d.W3;
    const void* A = d.av[m];
    float* out = d.wa[m];
    int k = kb * 8 + (threadIdx.x >> 5);   // 8 k per block
    int h = threadIdx.x & 31;              // 32 heads
    size_t wbase = (size_t)k * 2048 + h * 64;
    size_t abase = (size_t)h * 64;
    float acc = 0.f;
    if (isbf) {
      const unsigned short* Wb = (const unsigned short*)W;
      const unsigned short* Ab = (const unsigned short*)A;
#pragma unroll
      for (int v8 = 0; v8 < 8; ++v8) {
        int4 wv = *(const int4*)(Wb + wbase + v8 * 8);
        int4 av = *(const int4*)(Ab + abase + v8 * 8);
        const unsigned short* wu = (const unsigned short*)&wv;
        const unsigned short* au = (const unsigned short*)&av;
#pragma unroll
        for (int j = 0; j < 8; ++j) acc += bf2f(wu[j]) * bf2f(au[j]);
      }
    } else {
      const float* Wf = (const float*)W;
      const float* Af = (const float*)A;
#pragma unroll
      for (int v4 = 0; v4 < 16; ++v4) {
        float4 wv = *(const float4*)(Wf + wbase + v4 * 4);
        float4 av = *(const float4*)(Af + abase + v4 * 4);
        acc += wv.x * av.x + wv.y * av.y + wv.z * av.z + wv.w * av.w;
      }
    }
    out[k * 32 + h] = acc;
  }
}

// ---------- CSR exclusive scan ----------
__global__ __launch_bounds__(1024) void k_exscan2(const int* __restrict__ degA, const int* __restrict__ degB,
                                                  int* __restrict__ rowA, int* __restrict__ rowB,
                                                  int* __restrict__ colA, int* __restrict__ colB,
                                                  int* __restrict__ curA, int* __restrict__ curB, int n) {
  const int* deg = (blockIdx.x == 0) ? degA : degB;
  int* row = (blockIdx.x == 0) ? rowA : rowB;
  int* colx = (blockIdx.x == 0) ? colA : colB;
  int* curx = (blockIdx.x == 0) ? curA : curB;
  __shared__ int wsum[16], wbase[16];
  __shared__ int carry;
  if (threadIdx.x == 0) carry = 0;
  __syncthreads();
  int lane = threadIdx.x & 63, w = threadIdx.x >> 6;
  int chunks = (n + 1023) >> 10;
  for (int ch = 0; ch < chunks; ++ch) {
    int i = (ch << 10) + threadIdx.x;
    int v = (i < n) ? deg[i] : 0;
    int sc = v;
#pragma unroll
    for (int o = 1; o < 64; o <<= 1) { int t = __shfl_up(sc, o); if (lane >= o) sc += t; }
    if (lane == 63) wsum[w] = sc;
    __syncthreads();
    if (threadIdx.x < 16) {
      int v2 = wsum[threadIdx.x], s2 = v2;
#pragma unroll
      for (int o = 1; o < 16; o <<= 1) { int t = __shfl_up(s2, o); if (lane >= o) s2 += t; }
      wbase[threadIdx.x] = s2 - v2;
      if (threadIdx.x == 15) wsum[15] = s2;
    }
    __syncthreads();
    if (i < n) {
      int rv = carry + wbase[w] + (sc - v) + i;
      row[i] = rv;
      colx[rv] = i;
      curx[i] = rv + 1;
    }
    __syncthreads();
    if (threadIdx.x == 0) carry += wsum[15];
    __syncthreads();
  }
  if (threadIdx.x == 0) row[n] = carry + n;
}

// ---------- 64-row x 64-col per-wave GEMM body ----------
#define TILE_DW 288
template<int CH, int KSTEPS>
__device__ __forceinline__ void mm_es64_body(int rg, int cg, int MT,
    const unsigned short* __restrict__ Ap, const unsigned short* __restrict__ Bp,
    unsigned char* __restrict__ C, const float* __restrict__ a_s, const float* __restrict__ a_d,
    float* __restrict__ es, float* __restrict__ ed, int N, unsigned int* tile) {
  const int TI = KSTEPS * 64;
  int vt = MT - rg * 4; if (vt > 4) vt = 4;
  int wid = threadIdx.x >> 6;
  int tn = cg * 4 + wid;
  int lane = threadIdx.x & 63;
  int mr = lane & 15, quad = lane >> 4;
  const int4* ap = (const int4*)(Ap + (size_t)rg * 4 * TI * 8) + lane;
  const unsigned short* bp = Bp + ((size_t)tn * 4 * KSTEPS) * 512 + lane * 8;
  unsigned int* twave = tile + wid * TILE_DW;
  f32x4 acc[4][4];
#pragma unroll
  for (int rt = 0; rt < 4; ++rt)
#pragma unroll
    for (int nt = 0; nt < 4; ++nt) acc[rt][nt] = (f32x4){0.f, 0.f, 0.f, 0.f};
#pragma unroll
  for (int s = 0; s < KSTEPS; ++s) {
    ABfrag bfr[4];
#pragma unroll
    for (int nt = 0; nt < 4; ++nt) bfr[nt].i4 = *(const int4*)(bp + (size_t)(nt * KSTEPS + s) * 512);
    ABfrag afr[4];
#pragma unroll
    for (int rt = 0; rt < 4; ++rt) {
      int rti = (rt < vt) ? rt : 0;   // clamp: keep tail-row-group reads inside xp
      afr[rt].i4 = ap[rti * TI + s * 64];
    }
#pragma unroll
    for (int nt = 0; nt < 4; ++nt)
#pragma unroll
      for (int rt = 0; rt < 4; ++rt)
        acc[rt][nt] = __builtin_amdgcn_mfma_f32_16x16x32_bf16(afr[rt].v, bfr[nt].v, acc[rt][nt], 0, 0, 0);
  }
  int r16 = lane >> 2, seg = lane & 3;
  int qr = r16 >> 2, rr = r16 & 3;
#pragma unroll
  for (int rt = 0; rt < 4; ++rt) {
    if (rt < vt) {
      int tm = rg * 4 + rt;
#pragma unroll
      for (int nt = 0; nt < 4; ++nt) {
        unsigned int dwv = pack4_fp8(acc[rt][nt][0], acc[rt][nt][1], acc[rt][nt][2], acc[rt][nt][3]);
        twave[quad * 72 + nt * 16 + mr] = dwv;   // 2-way bank (free)
      }
      unsigned int out[4];
#pragma unroll
      for (int w = 0; w < 4; ++w) {
        uint4 v = *(const uint4*)&twave[qr * 72 + seg * 16 + 4 * w];
        out[w] = bytesel4(v, rr);
      }
      *(int4*)(C + (size_t)(tm * 16 + r16) * N + tn * 64 + seg * 16) = *(const int4*)out;
    }
  }
  if (CH == 16) {
    float ws[4], wd[4];
#pragma unroll
    for (int nt = 0; nt < 4; ++nt) {
      ws[nt] = a_s[(tn * 4 + nt) * 16 + mr];
      wd[nt] = a_d[(tn * 4 + nt) * 16 + mr];
    }
#pragma unroll
    for (int rt = 0; rt < 4; ++rt) {
      if (rt < vt) {
        int tm = rg * 4 + rt;
        float pes[4][4], ped[4][4];
#pragma unroll
        for (int nt = 0; nt < 4; ++nt)
#pragma unroll
          for (int r = 0; r < 4; ++r) { pes[nt][r] = acc[rt][nt][r] * ws[nt]; ped[nt][r] = acc[rt][nt][r] * wd[nt]; }
#pragma unroll
        for (int m = 1; m < 16; m <<= 1)
#pragma unroll
          for (int nt = 0; nt < 4; ++nt)
#pragma unroll
            for (int r = 0; r < 4; ++r) {
              pes[nt][r] += __shfl_xor(pes[nt][r], m);
              ped[nt][r] += __shfl_xor(ped[nt][r], m);
            }
        if (mr == 0) {
#pragma unroll
          for (int nt = 0; nt < 4; ++nt)
#pragma unroll
            for (int r = 0; r < 4; ++r) {
              int row = tm * 16 + quad * 4 + r;
              es[row * 32 + tn * 4 + nt] = pes[nt][r];
              ed[row * 32 + tn * 4 + nt] = ped[nt][r];
            }
        }
      }
    }
  }
}

// ---------- merged: residual+GEMV -> scatter -> mm1 -> mm3 ----------
union SM13 {
  struct { float xs[16][128]; float ha[16][16]; float tt[16][16]; } res;
  unsigned int tile[4 * TILE_DW];
};
struct MM13XDesc {
  int resblks, sblks, mmblks, mt, E;
  const int* ei; int* colA; int* colB; int* curA; int* curB;
  const float* xc;
  const float* rp[20];
  const float* wa[4];
  float* es1; float* ed1; float* es3; float* ed3;
  void* outbase; size_t eoff; int n;
  const int* flag;
  const unsigned short* Ap;
  const unsigned short* B1; const unsigned short* B3;
  unsigned char* C1; unsigned char* C3;
};
__global__ __launch_bounds__(256) void k_mm13x(MM13XDesc d) {
  __shared__ SM13 sm;
  int b = blockIdx.x;
  if (b < d.resblks) {
    int nodebase = b * 16;
    for (int t = threadIdx.x; t < 16 * 128; t += 256)
      sm.res.xs[t >> 7][t & 127] = d.xc[(size_t)(nodebase + (t >> 7)) * 128 + (t & 127)];
    __syncthreads();
    int ni = threadIdx.x >> 4, c = threadIdx.x & 15;
    // ---- es/ed GEMV (plain layout [row*32+h]) ----
    {
      const float* w0 = d.wa[0]; const float* w1 = d.wa[1];
      const float* w2 = d.wa[2]; const float* w3 = d.wa[3];
      float a0 = 0.f, a1 = 0.f, a2 = 0.f, a3 = 0.f, a4 = 0.f, a5 = 0.f, a6 = 0.f, a7 = 0.f;
#pragma unroll 4
      for (int k = 0; k < 128; ++k) {
        float xv = sm.res.xs[ni][k];
        int o = k * 32 + c;
        a0 += xv * w0[o]; a1 += xv * w0[o + 16];
        a2 += xv * w1[o]; a3 += xv * w1[o + 16];
        a4 += xv * w2[o]; a5 += xv * w2[o + 16];
        a6 += xv * w3[o]; a7 += xv * w3[o + 16];
      }
      int row = nodebase + ni;
      d.es1[row * 32 + c] = a0; d.es1[row * 32 + c + 16] = a1;
      d.ed1[row * 32 + c] = a2; d.ed1[row * 32 + c + 16] = a3;
      d.es3[row * 32 + c] = a4; d.es3[row * 32 + c + 16] = a5;
      d.ed3[row * 32 + c] = a6; d.ed3[row * 32 + c + 16] = a7;
    }
    // ---- residual MLP ----
    const float* rwa = d.rp[0]; const float* rba = d.rp[1];
    const float* bn1g = d.rp[2]; const float* bn1b = d.rp[3];
    const float* bn1m = d.rp[4]; const float* bn1v = d.rp[5];
    const float* rwb = d.rp[6]; const float* rbb = d.rp[7];
    const float* bn2g = d.rp[8]; const float* bn2b = d.rp[9];
    const float* bn2m = d.rp[10]; const float* bn2v = d.rp[11];
    const float* wsc = d.rp[12]; const float* bsc = d.rp[13];
    const float* bnsg = d.rp[14]; const float* bnsb = d.rp[15];
    const float* bnsm = d.rp[16]; const float* bnsv = d.rp[17];
    const float* wfc = d.rp[18]; const float* bfc = d.rp[19];
    float ya = 0.f, ysc = 0.f;
#pragma unroll 8
    for (int k = 0; k < 128; ++k) {
      float xv = sm.res.xs[ni][k];
      ya  += xv * rwa[k * 16 + c];
      ysc += xv * wsc[k * 16 + c];
    }
    ya += rba[c]; ysc += bsc[c];
    float s1 = bn1g[c] * rsqrtf(bn1v[c] + 1e-5f);
    ya = (ya - bn1m[c]) * s1 + bn1b[c];
    ya = fmaxf(ya, 0.f);
    float ss = bnsg[c] * rsqrtf(bnsv[c] + 1e-5f);
    ysc = (ysc - bnsm[c]) * ss + bnsb[c];
    sm.res.ha[ni][c] = ya;
    __syncthreads();
    float h2 = rbb[c];
#pragma unroll
    for (int k = 0; k < 16; ++k) h2 += sm.res.ha[ni][k] * rwb[k * 16 + c];
    float s2 = bn2g[c] * rsqrtf(bn2v[c] + 1e-5f);
    h2 = (h2 - bn2m[c]) * s2 + bn2b[c];
    sm.res.tt[ni][c] = fmaxf(h2 + ysc, 0.f);
    __syncthreads();
    float o = bfc[c];
#pragma unroll
    for (int k = 0; k < 16; ++k) o += sm.res.tt[ni][k] * wfc[k * 16 + c];
    size_t oo = d.eoff + (size_t)(nodebase + ni) * 16 + c;
    if (*d.flag) ((unsigned short*)d.outbase)[oo] = f2bf(o);
    else         ((float*)d.outbase)[oo] = o;
    return;
  }
  b -= d.resblks;
  if (b < d.sblks) {  // CSR scatter
    int e = b * 256 + threadIdx.x;
    if (e < d.E) {
      int s = d.ei[e], dd = d.ei[d.E + e];
      d.colA[atomicAdd(&d.curA[dd], 1)] = s;
      d.colB[atomicAdd(&d.curB[s], 1)] = dd;
    }
    return;
  }
  b -= d.sblks;
  if (b < d.mmblks) {
    mm_es64_body<64,4>(b >> 3, b & 7, d.mt, d.Ap, d.B1, d.C1, nullptr, nullptr, nullptr, nullptr, 2048, sm.tile);
    return;
  }
  b -= d.mmblks;
  mm_es64_body<64,4>(b >> 3, b & 7, d.mt, d.Ap, d.B3, d.C3, nullptr, nullptr, nullptr, nullptr, 2048, sm.tile);
}

// ---------- merged gather64; ONE WAVE per node; 1-deep prefetch (round-8 best) ----------
__global__ __launch_bounds__(256) void k_g64(const unsigned char* __restrict__ h1,
                                             const unsigned char* __restrict__ h3,
                                             const float* __restrict__ es1, const float* __restrict__ ed1,
                                             const float* __restrict__ es3, const float* __restrict__ ed3,
                                             const int* __restrict__ rowA, const int* __restrict__ colA,
                                             const int* __restrict__ rowB, const int* __restrict__ colB,
                                             const float* __restrict__ b1, const float* __restrict__ b3,
                                             unsigned short* __restrict__ xsp, unsigned short* __restrict__ xtp,
                                             int n, int gb) {
  int b = blockIdx.x;
  const unsigned char* h; const float *es, *ed, *bias; const int *rowp, *col; unsigned short* outp;
  if (b < gb) { h = h1; es = es1; ed = ed1; rowp = rowA; col = colA; bias = b1; outp = xsp; }
  else { b -= gb; h = h3; es = es3; ed = ed3; rowp = rowB; col = colB; bias = b3; outp = xtp; }
  int wid = threadIdx.x >> 6, lane = threadIdx.x & 63;
  int i = b * 4 + wid;
  if (i >= n) return;
  int hd0 = lane >> 2, hd1 = 16 + hd0;
  float e0 = ed[i * 32 + hd0];
  float e1 = ed[i * 32 + hd1];
  int beg = rowp[i], end = rowp[i + 1];
  int deg = end - beg;                    // >= 1 (self-loop)
  int colv = (lane < deg) ? col[beg + lane] : 0;
  f32x2 acc0[8], acc1[8];
#pragma unroll
  for (int k = 0; k < 8; ++k) { acc0[k] = (f32x2){0.f, 0.f}; acc1[k] = (f32x2){0.f, 0.f}; }
  float Z0 = 0.f, Z1 = 0.f;
  // prologue: fetch edge 0
  int s0 = __shfl(colv, 0);
  const int4* hp0 = (const int4*)(h + (size_t)s0 * 2048);
  int4 ng0 = hp0[lane];
  int4 ng1 = hp0[64 + lane];
  float na = es[s0 * 32 + hd0];
  float nb = es[s0 * 32 + hd1];
  for (int j = 0; j < deg; ++j) {
    int4 g0 = ng0, g1 = ng1;
    float ea = na, eb = nb;
    int jn = j + 1;
    if (jn < deg) {                       // wave-uniform branch
      int sn = (jn < 64) ? __shfl(colv, jn) : col[beg + jn];
      const int4* hq = (const int4*)(h + (size_t)sn * 2048);
      ng0 = hq[lane];
      ng1 = hq[64 + lane];
      na = es[sn * 32 + hd0];
      nb = es[sn * 32 + hd1];
    }
    float q0 = __expf(lrelu_clamp(ea + e0));
    float q1 = __expf(lrelu_clamp(eb + e1));
    Z0 += q0; Z1 += q1;
    f32x2 d0[8], d1[8];
    dec16p(g0, d0); dec16p(g1, d1);
    f32x2 q0v = (f32x2){q0, q0}, q1v = (f32x2){q1, q1};
#pragma unroll
    for (int k = 0; k < 8; ++k) {
      acc0[k] = __builtin_elementwise_fma(q0v, d0[k], acc0[k]);
      acc1[k] = __builtin_elementwise_fma(q1v, d1[k], acc1[k]);
    }
  }
  float zi0 = 1.0f / Z0, zi1 = 1.0f / Z1;
  f32x2 zi0v = (f32x2){zi0, zi0}, zi1v = (f32x2){zi1, zi1};
  f32x2 v2[8];
#pragma unroll
  for (int k = 0; k < 8; ++k)
    v2[k] = __builtin_elementwise_fma(acc1[k], zi1v, acc0[k] * zi0v);
#pragma unroll
  for (int m = 4; m < 64; m <<= 1)
#pragma unroll
    for (int k = 0; k < 8; ++k) {
      v2[k].x += __shfl_xor(v2[k].x, m);
      v2[k].y += __shfl_xor(v2[k].y, m);
    }
  if (lane < 4) {
    float v[16];
#pragma unroll
    for (int k = 0; k < 8; ++k) { v[2 * k] = v2[k].x; v[2 * k + 1] = v2[k].y; }
    int tm = i >> 4, mr = i & 15;
    unsigned short ob[16];
#pragma unroll
    for (int k = 0; k < 16; ++k) {
      float t = v[k] * (1.f / 32.f) + bias[lane * 16 + k];
      t = (t > 0.f) ? t : (__expf(t) - 1.f);   // elu
      ob[k] = f2bf(t);
    }
    int s0w = lane >> 1;
#pragma unroll
    for (int g2 = 0; g2 < 2; ++g2) {
      size_t idx = (((size_t)tm * 2 + s0w) * 64 + ((lane & 1) * 2 + g2) * 16 + mr) * 8;
      *(int4*)(outp + idx) = *(const int4*)(ob + g2 * 8);  // packed-A bf16
    }
  }
}

// ---------- merged mm2 + mm4 (es/ed kept in-body) ----------
__global__ __launch_bounds__(256) void k_mm24(const unsigned short* __restrict__ xsp,
                                              const unsigned short* __restrict__ xtp,
                                              const unsigned short* __restrict__ W2p,
                                              const unsigned short* __restrict__ W4p,
                                              unsigned char* __restrict__ h2, unsigned char* __restrict__ h4,
                                              const float* __restrict__ as2, const float* __restrict__ ad2,
                                              const float* __restrict__ as4, const float* __restrict__ ad4,
                                              float* __restrict__ es2, float* __restrict__ ed2,
                                              float* __restrict__ es4, float* __restrict__ ed4,
                                              int mmblks, int mt) {
  __shared__ unsigned int tile[4 * TILE_DW];
  int b = blockIdx.x;
  if (b < mmblks)
    mm_es64_body<16,2>(b >> 1, b & 1, mt, xsp, W2p, h2, as2, ad2, es2, ed2, 512, tile);
  else {
    b -= mmblks;
    mm_es64_body<16,2>(b >> 1, b & 1, mt, xtp, W4p, h4, as4, ad4, es4, ed4, 512, tile);
  }
}

// ---------- merged gather16; ONE WAVE per node (round-8 form) ----------
__global__ __launch_bounds__(256) void k_g16(const unsigned char* __restrict__ h2,
                                             const unsigned char* __restrict__ h4,
                                             const float* __restrict__ es2, const float* __restrict__ ed2,
                                             const float* __restrict__ es4, const float* __restrict__ ed4,
                                             const int* __restrict__ rowA, const int* __restrict__ colA,
                                             const int* __restrict__ rowB, const int* __restrict__ colB,
                                             const float* __restrict__ b2, const float* __restrict__ b4,
                                             void* __restrict__ outbase, int n, int gb,
                                             const int* __restrict__ flag) {
  int b = blockIdx.x;
  const unsigned char* h; const float *es, *ed, *bias; const int *rowp, *col; size_t eoff;
  if (b < gb) { h = h2; es = es2; ed = ed2; rowp = rowA; col = colA; bias = b2; eoff = 0; }
  else { b -= gb; h = h4; es = es4; ed = ed4; rowp = rowB; col = colB; bias = b4; eoff = (size_t)n * 16; }
  int wid = threadIdx.x >> 6, lane = threadIdx.x & 63;
  int i = b * 4 + wid;
  if (i >= n) return;
  int hh = lane & 31, j2 = lane >> 5;
  float ev = ed[i * 32 + hh];
  int beg = rowp[i], end = rowp[i + 1];
  int deg = end - beg;
  int colv = (lane < deg) ? col[beg + lane] : 0;
  f32x2 acc[8];
#pragma unroll
  for (int k = 0; k < 8; ++k) acc[k] = (f32x2){0.f, 0.f};
  float Z = 0.f;
  int j = j2;
  int4 ng = (int4){0, 0, 0, 0};
  float ne = 0.f;
  if (j < deg) {
    int s = __shfl(colv, j);
    ng = ((const int4*)(h + (size_t)s * 512))[hh];
    ne = es[s * 32 + hh];
  }
  for (; j < deg; j += 2) {
    int4 g = ng; float ee = ne;
    int jn = j + 2;
    if (jn < deg) {
      int sn = (jn < 64) ? __shfl(colv, jn) : col[beg + jn];
      ng = ((const int4*)(h + (size_t)sn * 512))[hh];
      ne = es[sn * 32 + hh];
    }
    float q = __expf(lrelu_clamp(ee + ev));
    Z += q;
    f32x2 d[8];
    dec16p(g, d);
    f32x2 qv = (f32x2){q, q};
#pragma unroll
    for (int k = 0; k < 8; ++k) acc[k] = __builtin_elementwise_fma(qv, d[k], acc[k]);
  }
  Z += __shfl_xor(Z, 32);
  float zi = 1.0f / Z;
  f32x2 ziv = (f32x2){zi, zi};
  f32x2 v2[8];
#pragma unroll
  for (int k = 0; k < 8; ++k) v2[k] = acc[k] * ziv;
#pragma unroll
  for (int m = 1; m < 64; m <<= 1)
#pragma unroll
    for (int k = 0; k < 8; ++k) {
      v2[k].x += __shfl_xor(v2[k].x, m);
      v2[k].y += __shfl_xor(v2[k].y, m);
    }
  if (lane == 0) {
    float v[16];
#pragma unroll
    for (int k = 0; k < 8; ++k) { v[2 * k] = v2[k].x; v[2 * k + 1] = v2[k].y; }
    int isbf = *flag;
    if (isbf) {
      unsigned short ob[16];
#pragma unroll
      for (int k = 0; k < 16; ++k) {
        float t = v[k] * (1.f / 32.f) + bias[k];
        t = (t > 0.f) ? t : (__expf(t) - 1.f);
        ob[k] = f2bf(t);
      }
      unsigned short* o = (unsigned short*)outbase + eoff + (size_t)i * 16;
      *(int4*)o = *(const int4*)ob;
      *(int4*)(o + 8) = *(const int4*)(ob + 8);
    } else {
      float* o = (float*)outbase + eoff + (size_t)i * 16;
#pragma unroll
      for (int k = 0; k < 16; ++k) {
        float t = v[k] * (1.f / 32.f) + bias[k];
        t = (t > 0.f) ? t : (__expf(t) - 1.f);
        o[k] = t;
      }
    }
  }
}

extern "C" void kernel_launch(void* const* d_in, const int* in_sizes, int n_in,
                              void* d_out, int out_size, void* d_ws, size_t ws_size,
                              hipStream_t stream) {
  const int n = in_sizes[0] / 128;   // 10000
  const int E = in_sizes[1] / 2;     // 80000
  const int* ei = (const int*)d_in[1];

  char* wsp = (char*)d_ws; size_t off = 0;
  auto alloc = [&](size_t bytes) -> void* {
    void* p = wsp + off; off = (off + bytes + 255) & ~(size_t)255; return p;
  };
  int* flag = (int*)alloc(4);
  float* xc = (float*)alloc((size_t)n * 128 * 4);
  unsigned short* xp = (unsigned short*)alloc((size_t)n * 128 * 2);
  unsigned short* W1p = (unsigned short*)alloc((size_t)2048 * 128 * 2);
  unsigned short* W2p = (unsigned short*)alloc((size_t)512 * 64 * 2);
  unsigned short* W3p = (unsigned short*)alloc((size_t)2048 * 128 * 2);
  unsigned short* W4p = (unsigned short*)alloc((size_t)512 * 64 * 2);
  unsigned char* h1 = (unsigned char*)alloc((size_t)n * 2048);   // fp8
  unsigned char* h3 = (unsigned char*)alloc((size_t)n * 2048);
  unsigned char* h2 = (unsigned char*)alloc((size_t)n * 512);
  unsigned char* h4 = (unsigned char*)alloc((size_t)n * 512);
  float* es1 = (float*)alloc((size_t)n * 32 * 4);
  float* ed1 = (float*)alloc((size_t)n * 32 * 4);
  float* es3 = (float*)alloc((size_t)n * 32 * 4);
  float* ed3 = (float*)alloc((size_t)n * 32 * 4);
  float* es2 = (float*)alloc((size_t)n * 32 * 4);
  float* ed2 = (float*)alloc((size_t)n * 32 * 4);
  float* es4 = (float*)alloc((size_t)n * 32 * 4);
  float* ed4 = (float*)alloc((size_t)n * 32 * 4);
  unsigned short* xsp = (unsigned short*)alloc((size_t)n * 64 * 2);
  unsigned short* xtp = (unsigned short*)alloc((size_t)n * 64 * 2);
  int* rowA = (int*)alloc((size_t)(n + 1) * 4);
  int* rowB = (int*)alloc((size_t)(n + 1) * 4);
  int* colA = (int*)alloc((size_t)(E + n) * 4);
  int* colB = (int*)alloc((size_t)(E + n) * 4);
  int* degAB = (int*)alloc((size_t)2 * n * 4);
  int* degA = degAB, * degB = degAB + n;
  int* curA = (int*)alloc((size_t)n * 4);
  int* curB = (int*)alloc((size_t)n * 4);
  float* was1 = (float*)alloc((size_t)128 * 32 * 4);
  float* wad1 = (float*)alloc((size_t)128 * 32 * 4);
  float* was3 = (float*)alloc((size_t)128 * 32 * 4);
  float* wad3 = (float*)alloc((size_t)128 * 32 * 4);

  static const int cidx[32] = {3,4,5, 7,8,9, 11,12,13, 15,16,17,
                               18,19,20,21,22,23,24,25,26,27,28,29,
                               30,31,32,33,34,35,36,37};
  PrepDesc pd;
  float* canon[38] = {nullptr};
  pd.ctotal = 0;
  for (int t = 0; t < 32; ++t) {
    int ii = cidx[t];
    canon[ii] = (float*)alloc((size_t)in_sizes[ii] * 4);
    pd.csrc[t] = d_in[ii];
    pd.cdst[t] = canon[ii];
    pd.cn[t] = in_sizes[ii];
    pd.ctotal += in_sizes[ii];
  }
  pd.x = d_in[0]; pd.xc = xc; pd.xp = xp;
  pd.W1 = d_in[2]; pd.W2 = d_in[6]; pd.W3 = d_in[10]; pd.W4 = d_in[14];
  pd.P1 = W1p; pd.P2 = W2p; pd.P3 = W3p; pd.P4 = W4p;
  pd.degAB = degAB;
  pd.ei = ei;
  pd.av[0] = d_in[3]; pd.av[1] = d_in[4]; pd.av[2] = d_in[11]; pd.av[3] = d_in[12];
  pd.wa[0] = was1; pd.wa[1] = wad1; pd.wa[2] = was3; pd.wa[3] = wad3;
  pd.nxb = (n * 128 / 8 + 255) / 256;   // vectorized 8/thread
  pd.xtotal = n * 128;
  pd.E = E;
  pd.nn = n;
  (void)ws_size; (void)n_in; (void)out_size;

  const int degblks = (E + 255) / 256;  // 313

  // ---- detect + zero degAB ----
  k_detect<<<9, 256, 0, stream>>>((const unsigned int*)d_in[0], flag, degAB, 2 * n);
  // ---- unified prep + canon(32 direct blocks) + degree count + Wa fold ----
  k_prep<<<pd.nxb + 288 + 32 + degblks + 64, 256, 0, stream>>>(pd, flag);
  // ---- CSR scan ----
  k_exscan2<<<2, 1024, 0, stream>>>(degA, degB, rowA, rowB, colA, colB, curA, curB, n);

  const int mt = n / 16;              // 625
  const int nrg = (mt + 3) / 4;       // 157
  const int mmblks64 = nrg * 8;
  const int mmblks16 = nrg * 2;
  const int gb = (n + 3) / 4;         // 2500

  // ---- stage 1: residual+GEMV -> scatter -> mm1 -> mm3 (merged) ----
  MM13XDesc md;
  md.resblks = mt; md.sblks = degblks; md.mmblks = mmblks64; md.mt = mt; md.E = E;
  md.ei = ei; md.colA = colA; md.colB = colB; md.curA = curA; md.curB = curB;
  md.xc = xc;
  for (int t = 0; t < 20; ++t) md.rp[t] = canon[18 + t];
  md.wa[0] = was1; md.wa[1] = wad1; md.wa[2] = was3; md.wa[3] = wad3;
  md.es1 = es1; md.ed1 = ed1; md.es3 = es3; md.ed3 = ed3;
  md.outbase = d_out; md.eoff = (size_t)2 * n * 16; md.n = n; md.flag = flag;
  md.Ap = xp; md.B1 = W1p; md.B3 = W3p; md.C1 = h1; md.C3 = h3;
  k_mm13x<<<mt + degblks + 2 * mmblks64, 256, 0, stream>>>(md);

  // ---- stage 2: gather64 both flows (1 wave per node, round-8 body) ----
  k_g64<<<2 * gb, 256, 0, stream>>>(h1, h3, es1, ed1, es3, ed3,
                                    rowA, colA, rowB, colB,
                                    canon[5], canon[13], xsp, xtp, n, gb);
  // ---- stage 3: mm2 + mm4 ----
  k_mm24<<<2 * mmblks16, 256, 0, stream>>>(xsp, xtp, W2p, W4p, h2, h4,
                                           canon[7], canon[8], canon[15], canon[16],
                                           es2, ed2, es4, ed4, mmblks16, mt);
  // ---- stage 4: gather16 both flows -> outputs 0,1 ----
  k_g16<<<2 * gb, 256, 0, stream>>>(h2, h4, es2, ed2, es4, ed4,
                                    rowA, colA, rowB, colB,
                                    canon[9], canon[17], d_out, n, gb, flag);
}

// Round 12
// 302.606 us; speedup vs baseline: 1.5286x; 1.0128x over previous
//
#include <hip/hip_runtime.h>
#include <stdint.h>

// ---------- bf16 helpers ----------
__device__ __forceinline__ float bf2f(unsigned short u) {
  union { unsigned int i; float f; } v; v.i = ((unsigned int)u) << 16; return v.f;
}
__device__ __forceinline__ unsigned short f2bf(float f) {
  union { float f; unsigned int i; } v; v.f = f;
  unsigned int i = v.i;
  unsigned int r = (i + 0x7fffu + ((i >> 16) & 1u)) >> 16;  // RNE
  return (unsigned short)r;
}

typedef __bf16 bf16x8 __attribute__((ext_vector_type(8)));
typedef float f32x4 __attribute__((ext_vector_type(4)));
typedef float f32x2 __attribute__((ext_vector_type(2)));
union ABfrag { int4 i4; bf16x8 v; };

// ---------- fp8 e4m3fn (OCP): HW path on gfx950, SW fallback ----------
#if __has_builtin(__builtin_amdgcn_cvt_pk_fp8_f32) && __has_builtin(__builtin_amdgcn_cvt_pk_f32_fp8)
#define HW_FP8 1
#else
#define HW_FP8 0
#endif

__device__ __forceinline__ unsigned char f2fp8_sw(float f) {
  union { float f; unsigned int u; } v; v.f = f;
  unsigned int s = (v.u >> 24) & 0x80;
  float a = fabsf(f);
  if (a >= 448.f) return (unsigned char)(s | 0x7E);
  v.f = a;
  int ex = (int)(v.u >> 23);
  unsigned int man = v.u & 0x7FFFFFu;
  if (ex >= 121) {
    unsigned int val = ((unsigned int)(ex - 120) << 3) | (man >> 20);
    unsigned int rem = man & 0xFFFFFu;
    if (rem > 0x80000u || (rem == 0x80000u && (val & 1))) val++;
    if (val > 0x7E) val = 0x7E;
    return (unsigned char)(s | val);
  }
  int q = (int)(a * 512.f + 0.5f);
  if (q > 8) q = 8;
  return (unsigned char)(s | (unsigned int)q);
}
__device__ __forceinline__ float fp8dec_sw(unsigned char c) {
  unsigned int e = (c >> 3) & 15u, m = c & 7u;
  float v;
  if (e) { union { unsigned int u; float f; } x; x.u = ((e + 120) << 23) | (m << 20); v = x.f; }
  else v = (float)m * 0.001953125f;
  return (c & 0x80) ? -v : v;
}
// pack 4 floats -> 4 fp8 bytes in one dword (bytes 0..3 = a0..a3)
__device__ __forceinline__ unsigned int pack4_fp8(float a0, float a1, float a2, float a3) {
#if HW_FP8
  int dw = __builtin_amdgcn_cvt_pk_fp8_f32(a0, a1, 0, false);
  dw = __builtin_amdgcn_cvt_pk_fp8_f32(a2, a3, dw, true);
  return (unsigned int)dw;
#else
  return (unsigned)f2fp8_sw(a0) | ((unsigned)f2fp8_sw(a1) << 8) |
         ((unsigned)f2fp8_sw(a2) << 16) | ((unsigned)f2fp8_sw(a3) << 24);
#endif
}
// select byte rr from each of 4 dwords -> one dword
__device__ __forceinline__ unsigned int bytesel4(uint4 v, int rr) {
#if __has_builtin(__builtin_amdgcn_perm)
  unsigned s = (unsigned)rr | ((unsigned)(rr + 4) << 8);
  unsigned p01 = __builtin_amdgcn_perm(v.y, v.x, s);
  unsigned p23 = __builtin_amdgcn_perm(v.w, v.z, s);
  return __builtin_amdgcn_perm(p23, p01, 0x05040100u);
#else
  int sh = rr * 8;
  return ((v.x >> sh) & 0xFFu) | (((v.y >> sh) & 0xFFu) << 8) |
         (((v.z >> sh) & 0xFFu) << 16) | (((v.w >> sh) & 0xFFu) << 24);
#endif
}
// decode 16 fp8 -> 8 packed float2 (keeps cvt_pk's natural pair output)
__device__ __forceinline__ void dec16p(int4 g, f32x2 o[8]) {
#if HW_FP8
  o[0] = __builtin_amdgcn_cvt_pk_f32_fp8(g.x, false);
  o[1] = __builtin_amdgcn_cvt_pk_f32_fp8(g.x, true);
  o[2] = __builtin_amdgcn_cvt_pk_f32_fp8(g.y, false);
  o[3] = __builtin_amdgcn_cvt_pk_f32_fp8(g.y, true);
  o[4] = __builtin_amdgcn_cvt_pk_f32_fp8(g.z, false);
  o[5] = __builtin_amdgcn_cvt_pk_f32_fp8(g.z, true);
  o[6] = __builtin_amdgcn_cvt_pk_f32_fp8(g.w, false);
  o[7] = __builtin_amdgcn_cvt_pk_f32_fp8(g.w, true);
#else
  unsigned int w[4] = {(unsigned)g.x, (unsigned)g.y, (unsigned)g.z, (unsigned)g.w};
#pragma unroll
  for (int d = 0; d < 4; ++d) {
    unsigned int x = w[d];
    o[d * 2 + 0] = (f32x2){fp8dec_sw((unsigned char)(x & 0xFF)),
                           fp8dec_sw((unsigned char)((x >> 8) & 0xFF))};
    o[d * 2 + 1] = (f32x2){fp8dec_sw((unsigned char)((x >> 16) & 0xFF)),
                           fp8dec_sw((unsigned char)((x >> 24) & 0xFF))};
  }
#endif
}

__device__ __forceinline__ float lrelu_clamp(float e) {
  e = (e > 0.f) ? e : 0.2f * e;
  return fminf(e, 80.f);
}

// ---------- dtype detection + degAB zeroing (merged) ----------
__global__ __launch_bounds__(256) void k_detect(const unsigned int* __restrict__ x, int* flag,
                                                int* __restrict__ degAB, int ndeg2) {
  if (blockIdx.x == 0) {
    __shared__ int cnt;
    if (threadIdx.x == 0) cnt = 0;
    __syncthreads();
    int c = 0;
    for (int i = threadIdx.x; i < 1024; i += 256) {
      unsigned int lo = x[i] & 0xFFFFu;
      int ex = (int)((lo >> 7) & 0xFF);
      if (ex >= 100 && ex <= 140) c++;
    }
    atomicAdd(&cnt, c);
    __syncthreads();
    if (threadIdx.x == 0) flag[0] = (cnt > 600) ? 1 : 0;  // 1 = bf16 inputs
    return;
  }
  for (int idx = (blockIdx.x - 1) * 256 + threadIdx.x; idx < ndeg2; idx += 8 * 256) degAB[idx] = 0;
}

// ---------- unified prep (+ canon direct + degree count + Wa fold) ----------
struct PrepDesc {
  const void* csrc[32]; float* cdst[32]; int cn[32];
  const void* x; float* xc; unsigned short* xp;
  const void* W1; const void* W2; const void* W3; const void* W4;
  unsigned short* P1; unsigned short* P2; unsigned short* P3; unsigned short* P4;
  int* degAB;
  const int* ei;
  const void* av[4];   // as1, ad1, as3, ad3 (raw inputs)
  float* wa[4];        // Was1, Wad1, Was3, Wad3 [128x32]
  int nxb, xtotal, ctotal, E, nn;
};
__global__ __launch_bounds__(256) void k_prep(PrepDesc d, const int* __restrict__ flag) {
  int isbf = *flag;
  int b = blockIdx.x;
  if (b < d.nxb) {
    int t8 = b * 256 + threadIdx.x;
    int i8 = t8 * 8;
    if (i8 < d.xtotal) {
      float v[8];
      if (isbf) {
        int4 raw = *(const int4*)((const unsigned short*)d.x + i8);
        const unsigned short* u = (const unsigned short*)&raw;
#pragma unroll
        for (int j = 0; j < 8; ++j) v[j] = bf2f(u[j]);
      } else {
        float4 f0 = *(const float4*)((const float*)d.x + i8);
        float4 f1 = *(const float4*)((const float*)d.x + i8 + 4);
        v[0] = f0.x; v[1] = f0.y; v[2] = f0.z; v[3] = f0.w;
        v[4] = f1.x; v[5] = f1.y; v[6] = f1.z; v[7] = f1.w;
      }
      *(float4*)(d.xc + i8)     = (float4){v[0], v[1], v[2], v[3]};
      *(float4*)(d.xc + i8 + 4) = (float4){v[4], v[5], v[6], v[7]};
      int row = i8 >> 7, c0 = i8 & 127;
      int tm = row >> 4, mr = row & 15;
      int s = c0 >> 5, quad = (c0 >> 3) & 3;
      unsigned short o[8];
#pragma unroll
      for (int j = 0; j < 8; ++j) o[j] = f2bf(v[j]);
      size_t idx = (((size_t)tm * 4 + s) * 64 + quad * 16 + mr) * 8;
      *(int4*)(d.xp + idx) = *(const int4*)o;
    }
    return;
  }
  b -= d.nxb;
  if (b < 288) {
    int u = b * 256 + threadIdx.x;
    const void* W; unsigned short* P; int K, N, lu;
    if (u < 32768)      { W = d.W1; P = d.P1; K = 128; N = 2048; lu = u; }
    else if (u < 36864) { W = d.W2; P = d.P2; K = 64;  N = 512;  lu = u - 32768; }
    else if (u < 69632) { W = d.W3; P = d.P3; K = 128; N = 2048; lu = u - 36864; }
    else                { W = d.W4; P = d.P4; K = 64;  N = 512;  lu = u - 69632; }
    int ksteps = K >> 5;
    int g = lu / (ksteps * 64);
    int rem = lu - g * (ksteps * 64);
    int s = rem >> 6, lane = rem & 63;
    int mr = lane & 15, quad = lane >> 4;
    int col = g * 16 + mr;
    int kbase = s * 32 + quad * 8;
#pragma unroll
    for (int j = 0; j < 8; ++j) {
      size_t src = (size_t)(kbase + j) * N + col;
      float v = isbf ? bf2f(((const unsigned short*)W)[src]) : ((const float*)W)[src];
      P[(size_t)lu * 8 + j] = f2bf(v);
    }
    return;
  }
  b -= 288;
  if (b < 32) {  // canon copy: one block per tensor, direct indexing (no search)
    int t = b;
    int nels = d.cn[t];
    const void* src = d.csrc[t];
    float* dst = d.cdst[t];
    for (int idx = threadIdx.x; idx < nels; idx += 256) {
      float v = isbf ? bf2f(((const unsigned short*)src)[idx])
                     : ((const float*)src)[idx];
      dst[idx] = v;
    }
    return;
  }
  b -= 32;
  {
    int degblks = (d.E + 255) >> 8;
    if (b < degblks) {  // degree count (degAB zeroed by k_detect)
      int e = b * 256 + threadIdx.x;
      if (e < d.E) {
        atomicAdd(&d.degAB[d.ei[d.E + e]], 1);
        atomicAdd(&d.degAB[d.nn + d.ei[e]], 1);
      }
      return;
    }
    b -= degblks;
  }
  {  // Wa fold: b in [0,64): matrix m = b>>4, k-block = b&15
    int m = b >> 4, kb = b & 15;
    const void* W = (m < 2) ? d.W1 : d.W3;
    const void* A = d.av[m];
    float* out = d.wa[m];
    int k = kb * 8 + (threadIdx.x >> 5);   // 8 k per block
    int h = threadIdx.x & 31;              // 32 heads
    size_t wbase = (size_t)k * 2048 + h * 64;
    size_t abase = (size_t)h * 64;
    float acc = 0.f;
    if (isbf) {
      const unsigned short* Wb = (const unsigned short*)W;
      const unsigned short* Ab = (const unsigned short*)A;
#pragma unroll
      for (int v8 = 0; v8 < 8; ++v8) {
        int4 wv = *(const int4*)(Wb + wbase + v8 * 8);
        int4 av = *(const int4*)(Ab + abase + v8 * 8);
        const unsigned short* wu = (const unsigned short*)&wv;
        const unsigned short* au = (const unsigned short*)&av;
#pragma unroll
        for (int j = 0; j < 8; ++j) acc += bf2f(wu[j]) * bf2f(au[j]);
      }
    } else {
      const float* Wf = (const float*)W;
      const float* Af = (const float*)A;
#pragma unroll
      for (int v4 = 0; v4 < 16; ++v4) {
        float4 wv = *(const float4*)(Wf + wbase + v4 * 4);
        float4 av = *(const float4*)(Af + abase + v4 * 4);
        acc += wv.x * av.x + wv.y * av.y + wv.z * av.z + wv.w * av.w;
      }
    }
    out[k * 32 + h] = acc;
  }
}

// ---------- CSR exclusive scan ----------
__global__ __launch_bounds__(1024) void k_exscan2(const int* __restrict__ degA, const int* __restrict__ degB,
                                                  int* __restrict__ rowA, int* __restrict__ rowB,
                                                  int* __restrict__ colA, int* __restrict__ colB,
                                                  int* __restrict__ curA, int* __restrict__ curB, int n) {
  const int* deg = (blockIdx.x == 0) ? degA : degB;
  int* row = (blockIdx.x == 0) ? rowA : rowB;
  int* colx = (blockIdx.x == 0) ? colA : colB;
  int* curx = (blockIdx.x == 0) ? curA : curB;
  __shared__ int wsum[16], wbase[16];
  __shared__ int carry;
  if (threadIdx.x == 0) carry = 0;
  __syncthreads();
  int lane = threadIdx.x & 63, w = threadIdx.x >> 6;
  int chunks = (n + 1023) >> 10;
  for (int ch = 0; ch < chunks; ++ch) {
    int i = (ch << 10) + threadIdx.x;
    int v = (i < n) ? deg[i] : 0;
    int sc = v;
#pragma unroll
    for (int o = 1; o < 64; o <<= 1) { int t = __shfl_up(sc, o); if (lane >= o) sc += t; }
    if (lane == 63) wsum[w] = sc;
    __syncthreads();
    if (threadIdx.x < 16) {
      int v2 = wsum[threadIdx.x], s2 = v2;
#pragma unroll
      for (int o = 1; o < 16; o <<= 1) { int t = __shfl_up(s2, o); if (lane >= o) s2 += t; }
      wbase[threadIdx.x] = s2 - v2;
      if (threadIdx.x == 15) wsum[15] = s2;
    }
    __syncthreads();
    if (i < n) {
      int rv = carry + wbase[w] + (sc - v) + i;
      row[i] = rv;
      colx[rv] = i;
      curx[i] = rv + 1;
    }
    __syncthreads();
    if (threadIdx.x == 0) carry += wsum[15];
    __syncthreads();
  }
  if (threadIdx.x == 0) row[n] = carry + n;
}

// ---------- async global->LDS stage (width 16, linear layout) ----------
__device__ __forceinline__ void gload_lds16(const void* g, void* l) {
#if __has_builtin(__builtin_amdgcn_global_load_lds)
  __builtin_amdgcn_global_load_lds(
      (const __attribute__((address_space(1))) unsigned int*)g,
      (__attribute__((address_space(3))) unsigned int*)l, 16, 0, 0);
#else
  // fallback: per-lane copy (l must then be per-lane; handled at call site via +lane*16)
  *(int4*)((char*)l) = *(const int4*)g;
#endif
}

// ---------- 64-row x 64-col per-wave GEMM body; A staged via global_load_lds ----------
#define TILE_DW 288
template<int CH, int KSTEPS>
__device__ __forceinline__ void mm_es64_body(int rg, int cg, int MT,
    const unsigned short* __restrict__ Ap, const unsigned short* __restrict__ Bp,
    unsigned char* __restrict__ C, const float* __restrict__ a_s, const float* __restrict__ a_d,
    float* __restrict__ es, float* __restrict__ ed, int N,
    int4* smA, unsigned int* tile) {
  const int TI = KSTEPS * 64;              // int4 per 16-row A tile
  int vt = MT - rg * 4; if (vt > 4) vt = 4;
  int wid = threadIdx.x >> 6;
  int tn = cg * 4 + wid;
  int lane = threadIdx.x & 63;
  int mr = lane & 15, quad = lane >> 4;
  // ---- stage A panel (4*TI int4 = 4*KSTEPS KB, fully in-bounds: panels padded
  //      to 4-tile groups stay within xp/xsp allocations) ----
  {
    const char* gb = (const char*)(Ap + (size_t)rg * 4 * TI * 8);
    char* lb = (char*)smA;
#if __has_builtin(__builtin_amdgcn_global_load_lds)
#pragma unroll
    for (int k2 = 0; k2 < KSTEPS; ++k2) {
      int inst = wid * KSTEPS + k2;
      gload_lds16(gb + inst * 1024 + lane * 16, lb + inst * 1024);
    }
#else
#pragma unroll
    for (int k2 = 0; k2 < KSTEPS; ++k2) {
      int inst = wid * KSTEPS + k2;
      *(int4*)(lb + inst * 1024 + lane * 16) = *(const int4*)(gb + inst * 1024 + lane * 16);
    }
#endif
  }
  const unsigned short* bp = Bp + ((size_t)tn * 4 * KSTEPS) * 512 + lane * 8;
  unsigned int* twave = tile + wid * TILE_DW;
  f32x4 acc[4][4];
#pragma unroll
  for (int rt = 0; rt < 4; ++rt)
#pragma unroll
    for (int nt = 0; nt < 4; ++nt) acc[rt][nt] = (f32x4){0.f, 0.f, 0.f, 0.f};
  __syncthreads();   // A staged (compiler drains vmcnt before barrier)
#pragma unroll
  for (int s = 0; s < KSTEPS; ++s) {
    ABfrag bfr[4];
#pragma unroll
    for (int nt = 0; nt < 4; ++nt) bfr[nt].i4 = *(const int4*)(bp + (size_t)(nt * KSTEPS + s) * 512);
    ABfrag afr[4];
#pragma unroll
    for (int rt = 0; rt < 4; ++rt) afr[rt].i4 = smA[rt * TI + s * 64 + lane];
#pragma unroll
    for (int nt = 0; nt < 4; ++nt)
#pragma unroll
      for (int rt = 0; rt < 4; ++rt)
        acc[rt][nt] = __builtin_amdgcn_mfma_f32_16x16x32_bf16(afr[rt].v, bfr[nt].v, acc[rt][nt], 0, 0, 0);
  }
  int r16 = lane >> 2, seg = lane & 3;
  int qr = r16 >> 2, rr = r16 & 3;
#pragma unroll
  for (int rt = 0; rt < 4; ++rt) {
    if (rt < vt) {
      int tm = rg * 4 + rt;
#pragma unroll
      for (int nt = 0; nt < 4; ++nt) {
        unsigned int dwv = pack4_fp8(acc[rt][nt][0], acc[rt][nt][1], acc[rt][nt][2], acc[rt][nt][3]);
        twave[quad * 72 + nt * 16 + mr] = dwv;   // 2-way bank (free)
      }
      unsigned int out[4];
#pragma unroll
      for (int w = 0; w < 4; ++w) {
        uint4 v = *(const uint4*)&twave[qr * 72 + seg * 16 + 4 * w];
        out[w] = bytesel4(v, rr);
      }
      *(int4*)(C + (size_t)(tm * 16 + r16) * N + tn * 64 + seg * 16) = *(const int4*)out;
    }
  }
  if (CH == 16) {
    float ws[4], wd[4];
#pragma unroll
    for (int nt = 0; nt < 4; ++nt) {
      ws[nt] = a_s[(tn * 4 + nt) * 16 + mr];
      wd[nt] = a_d[(tn * 4 + nt) * 16 + mr];
    }
#pragma unroll
    for (int rt = 0; rt < 4; ++rt) {
      if (rt < vt) {
        int tm = rg * 4 + rt;
        float pes[4][4], ped[4][4];
#pragma unroll
        for (int nt = 0; nt < 4; ++nt)
#pragma unroll
          for (int r = 0; r < 4; ++r) { pes[nt][r] = acc[rt][nt][r] * ws[nt]; ped[nt][r] = acc[rt][nt][r] * wd[nt]; }
#pragma unroll
        for (int m = 1; m < 16; m <<= 1)
#pragma unroll
          for (int nt = 0; nt < 4; ++nt)
#pragma unroll
            for (int r = 0; r < 4; ++r) {
              pes[nt][r] += __shfl_xor(pes[nt][r], m);
              ped[nt][r] += __shfl_xor(ped[nt][r], m);
            }
        if (mr == 0) {
#pragma unroll
          for (int nt = 0; nt < 4; ++nt)
#pragma unroll
            for (int r = 0; r < 4; ++r) {
              int row = tm * 16 + quad * 4 + r;
              es[row * 32 + tn * 4 + nt] = pes[nt][r];
              ed[row * 32 + tn * 4 + nt] = ped[nt][r];
            }
        }
      }
    }
  }
}

// ---------- merged: residual+GEMV -> scatter -> mm1 -> mm3 ----------
union SM13 {
  struct { float xs[16][128]; float ha[16][16]; float tt[16][16]; } res;  // 10.25KB
  struct { int4 a[1024]; unsigned int tile[4 * TILE_DW]; } mm;            // 16KB + 4.6KB
};
struct MM13XDesc {
  int resblks, sblks, mmblks, mt, E;
  const int* ei; int* colA; int* colB; int* curA; int* curB;
  const float* xc;
  const float* rp[20];
  const float* wa[4];
  float* es1; float* ed1; float* es3; float* ed3;
  void* outbase; size_t eoff; int n;
  const int* flag;
  const unsigned short* Ap;
  const unsigned short* B1; const unsigned short* B3;
  unsigned char* C1; unsigned char* C3;
};
__global__ __launch_bounds__(256) void k_mm13x(MM13XDesc d) {
  __shared__ SM13 sm;
  int b = blockIdx.x;
  if (b < d.resblks) {
    int nodebase = b * 16;
    for (int t = threadIdx.x; t < 16 * 128; t += 256)
      sm.res.xs[t >> 7][t & 127] = d.xc[(size_t)(nodebase + (t >> 7)) * 128 + (t & 127)];
    __syncthreads();
    int ni = threadIdx.x >> 4, c = threadIdx.x & 15;
    // ---- es/ed GEMV (plain layout [row*32+h]) ----
    {
      const float* w0 = d.wa[0]; const float* w1 = d.wa[1];
      const float* w2 = d.wa[2]; const float* w3 = d.wa[3];
      float a0 = 0.f, a1 = 0.f, a2 = 0.f, a3 = 0.f, a4 = 0.f, a5 = 0.f, a6 = 0.f, a7 = 0.f;
#pragma unroll 4
      for (int k = 0; k < 128; ++k) {
        float xv = sm.res.xs[ni][k];
        int o = k * 32 + c;
        a0 += xv * w0[o]; a1 += xv * w0[o + 16];
        a2 += xv * w1[o]; a3 += xv * w1[o + 16];
        a4 += xv * w2[o]; a5 += xv * w2[o + 16];
        a6 += xv * w3[o]; a7 += xv * w3[o + 16];
      }
      int row = nodebase + ni;
      d.es1[row * 32 + c] = a0; d.es1[row * 32 + c + 16] = a1;
      d.ed1[row * 32 + c] = a2; d.ed1[row * 32 + c + 16] = a3;
      d.es3[row * 32 + c] = a4; d.es3[row * 32 + c + 16] = a5;
      d.ed3[row * 32 + c] = a6; d.ed3[row * 32 + c + 16] = a7;
    }
    // ---- residual MLP ----
    const float* rwa = d.rp[0]; const float* rba = d.rp[1];
    const float* bn1g = d.rp[2]; const float* bn1b = d.rp[3];
    const float* bn1m = d.rp[4]; const float* bn1v = d.rp[5];
    const float* rwb = d.rp[6]; const float* rbb = d.rp[7];
    const float* bn2g = d.rp[8]; const float* bn2b = d.rp[9];
    const float* bn2m = d.rp[10]; const float* bn2v = d.rp[11];
    const float* wsc = d.rp[12]; const float* bsc = d.rp[13];
    const float* bnsg = d.rp[14]; const float* bnsb = d.rp[15];
    const float* bnsm = d.rp[16]; const float* bnsv = d.rp[17];
    const float* wfc = d.rp[18]; const float* bfc = d.rp[19];
    float ya = 0.f, ysc = 0.f;
#pragma unroll 8
    for (int k = 0; k < 128; ++k) {
      float xv = sm.res.xs[ni][k];
      ya  += xv * rwa[k * 16 + c];
      ysc += xv * wsc[k * 16 + c];
    }
    ya += rba[c]; ysc += bsc[c];
    float s1 = bn1g[c] * rsqrtf(bn1v[c] + 1e-5f);
    ya = (ya - bn1m[c]) * s1 + bn1b[c];
    ya = fmaxf(ya, 0.f);
    float ss = bnsg[c] * rsqrtf(bnsv[c] + 1e-5f);
    ysc = (ysc - bnsm[c]) * ss + bnsb[c];
    sm.res.ha[ni][c] = ya;
    __syncthreads();
    float h2 = rbb[c];
#pragma unroll
    for (int k = 0; k < 16; ++k) h2 += sm.res.ha[ni][k] * rwb[k * 16 + c];
    float s2 = bn2g[c] * rsqrtf(bn2v[c] + 1e-5f);
    h2 = (h2 - bn2m[c]) * s2 + bn2b[c];
    sm.res.tt[ni][c] = fmaxf(h2 + ysc, 0.f);
    __syncthreads();
    float o = bfc[c];
#pragma unroll
    for (int k = 0; k < 16; ++k) o += sm.res.tt[ni][k] * wfc[k * 16 + c];
    size_t oo = d.eoff + (size_t)(nodebase + ni) * 16 + c;
    if (*d.flag) ((unsigned short*)d.outbase)[oo] = f2bf(o);
    else         ((float*)d.outbase)[oo] = o;
    return;
  }
  b -= d.resblks;
  if (b < d.sblks) {  // CSR scatter
    int e = b * 256 + threadIdx.x;
    if (e < d.E) {
      int s = d.ei[e], dd = d.ei[d.E + e];
      d.colA[atomicAdd(&d.curA[dd], 1)] = s;
      d.colB[atomicAdd(&d.curB[s], 1)] = dd;
    }
    return;
  }
  b -= d.sblks;
  if (b < d.mmblks) {
    mm_es64_body<64,4>(b >> 3, b & 7, d.mt, d.Ap, d.B1, d.C1, nullptr, nullptr, nullptr, nullptr, 2048, sm.mm.a, sm.mm.tile);
    return;
  }
  b -= d.mmblks;
  mm_es64_body<64,4>(b >> 3, b & 7, d.mt, d.Ap, d.B3, d.C3, nullptr, nullptr, nullptr, nullptr, 2048, sm.mm.a, sm.mm.tile);
}

// ---------- merged gather64; ONE WAVE per node; 1-deep prefetch (round-8 best) ----------
__global__ __launch_bounds__(256) void k_g64(const unsigned char* __restrict__ h1,
                                             const unsigned char* __restrict__ h3,
                                             const float* __restrict__ es1, const float* __restrict__ ed1,
                                             const float* __restrict__ es3, const float* __restrict__ ed3,
                                             const int* __restrict__ rowA, const int* __restrict__ colA,
                                             const int* __restrict__ rowB, const int* __restrict__ colB,
                                             const float* __restrict__ b1, const float* __restrict__ b3,
                                             unsigned short* __restrict__ xsp, unsigned short* __restrict__ xtp,
                                             int n, int gb) {
  int b = blockIdx.x;
  const unsigned char* h; const float *es, *ed, *bias; const int *rowp, *col; unsigned short* outp;
  if (b < gb) { h = h1; es = es1; ed = ed1; rowp = rowA; col = colA; bias = b1; outp = xsp; }
  else { b -= gb; h = h3; es = es3; ed = ed3; rowp = rowB; col = colB; bias = b3; outp = xtp; }
  int wid = threadIdx.x >> 6, lane = threadIdx.x & 63;
  int i = b * 4 + wid;
  if (i >= n) return;
  int hd0 = lane >> 2, hd1 = 16 + hd0;
  float e0 = ed[i * 32 + hd0];
  float e1 = ed[i * 32 + hd1];
  int beg = rowp[i], end = rowp[i + 1];
  int deg = end - beg;                    // >= 1 (self-loop)
  int colv = (lane < deg) ? col[beg + lane] : 0;
  f32x2 acc0[8], acc1[8];
#pragma unroll
  for (int k = 0; k < 8; ++k) { acc0[k] = (f32x2){0.f, 0.f}; acc1[k] = (f32x2){0.f, 0.f}; }
  float Z0 = 0.f, Z1 = 0.f;
  // prologue: fetch edge 0
  int s0 = __shfl(colv, 0);
  const int4* hp0 = (const int4*)(h + (size_t)s0 * 2048);
  int4 ng0 = hp0[lane];
  int4 ng1 = hp0[64 + lane];
  float na = es[s0 * 32 + hd0];
  float nb = es[s0 * 32 + hd1];
  for (int j = 0; j < deg; ++j) {
    int4 g0 = ng0, g1 = ng1;
    float ea = na, eb = nb;
    int jn = j + 1;
    if (jn < deg) {                       // wave-uniform branch
      int sn = (jn < 64) ? __shfl(colv, jn) : col[beg + jn];
      const int4* hq = (const int4*)(h + (size_t)sn * 2048);
      ng0 = hq[lane];
      ng1 = hq[64 + lane];
      na = es[sn * 32 + hd0];
      nb = es[sn * 32 + hd1];
    }
    float q0 = __expf(lrelu_clamp(ea + e0));
    float q1 = __expf(lrelu_clamp(eb + e1));
    Z0 += q0; Z1 += q1;
    f32x2 d0[8], d1[8];
    dec16p(g0, d0); dec16p(g1, d1);
    f32x2 q0v = (f32x2){q0, q0}, q1v = (f32x2){q1, q1};
#pragma unroll
    for (int k = 0; k < 8; ++k) {
      acc0[k] = __builtin_elementwise_fma(q0v, d0[k], acc0[k]);
      acc1[k] = __builtin_elementwise_fma(q1v, d1[k], acc1[k]);
    }
  }
  float zi0 = 1.0f / Z0, zi1 = 1.0f / Z1;
  f32x2 zi0v = (f32x2){zi0, zi0}, zi1v = (f32x2){zi1, zi1};
  f32x2 v2[8];
#pragma unroll
  for (int k = 0; k < 8; ++k)
    v2[k] = __builtin_elementwise_fma(acc1[k], zi1v, acc0[k] * zi0v);
#pragma unroll
  for (int m = 4; m < 64; m <<= 1)
#pragma unroll
    for (int k = 0; k < 8; ++k) {
      v2[k].x += __shfl_xor(v2[k].x, m);
      v2[k].y += __shfl_xor(v2[k].y, m);
    }
  if (lane < 4) {
    float v[16];
#pragma unroll
    for (int k = 0; k < 8; ++k) { v[2 * k] = v2[k].x; v[2 * k + 1] = v2[k].y; }
    int tm = i >> 4, mr = i & 15;
    unsigned short ob[16];
#pragma unroll
    for (int k = 0; k < 16; ++k) {
      float t = v[k] * (1.f / 32.f) + bias[lane * 16 + k];
      t = (t > 0.f) ? t : (__expf(t) - 1.f);   // elu
      ob[k] = f2bf(t);
    }
    int s0w = lane >> 1;
#pragma unroll
    for (int g2 = 0; g2 < 2; ++g2) {
      size_t idx = (((size_t)tm * 2 + s0w) * 64 + ((lane & 1) * 2 + g2) * 16 + mr) * 8;
      *(int4*)(outp + idx) = *(const int4*)(ob + g2 * 8);  // packed-A bf16
    }
  }
}

// ---------- merged mm2 + mm4 (es/ed kept in-body) ----------
__global__ __launch_bounds__(256) void k_mm24(const unsigned short* __restrict__ xsp,
                                              const unsigned short* __restrict__ xtp,
                                              const unsigned short* __restrict__ W2p,
                                              const unsigned short* __restrict__ W4p,
                                              unsigned char* __restrict__ h2, unsigned char* __restrict__ h4,
                                              const float* __restrict__ as2, const float* __restrict__ ad2,
                                              const float* __restrict__ as4, const float* __restrict__ ad4,
                                              float* __restrict__ es2, float* __restrict__ ed2,
                                              float* __restrict__ es4, float* __restrict__ ed4,
                                              int mmblks, int mt) {
  __shared__ struct { int4 a[512]; unsigned int tile[4 * TILE_DW]; } sm;  // KSTEPS=2: 8KB A
  int b = blockIdx.x;
  if (b < mmblks)
    mm_es64_body<16,2>(b >> 1, b & 1, mt, xsp, W2p, h2, as2, ad2, es2, ed2, 512, sm.a, sm.tile);
  else {
    b -= mmblks;
    mm_es64_body<16,2>(b >> 1, b & 1, mt, xtp, W4p, h4, as4, ad4, es4, ed4, 512, sm.a, sm.tile);
  }
}

// ---------- merged gather16; ONE WAVE per node (round-8 form) ----------
__global__ __launch_bounds__(256) void k_g16(const unsigned char* __restrict__ h2,
                                             const unsigned char* __restrict__ h4,
                                             const float* __restrict__ es2, const float* __restrict__ ed2,
                                             const float* __restrict__ es4, const float* __restrict__ ed4,
                                             const int* __restrict__ rowA, const int* __restrict__ colA,
                                             const int* __restrict__ rowB, const int* __restrict__ colB,
                                             const float* __restrict__ b2, const float* __restrict__ b4,
                                             void* __restrict__ outbase, int n, int gb,
                                             const int* __restrict__ flag) {
  int b = blockIdx.x;
  const unsigned char* h; const float *es, *ed, *bias; const int *rowp, *col; size_t eoff;
  if (b < gb) { h = h2; es = es2; ed = ed2; rowp = rowA; col = colA; bias = b2; eoff = 0; }
  else { b -= gb; h = h4; es = es4; ed = ed4; rowp = rowB; col = colB; bias = b4; eoff = (size_t)n * 16; }
  int wid = threadIdx.x >> 6, lane = threadIdx.x & 63;
  int i = b * 4 + wid;
  if (i >= n) return;
  int hh = lane & 31, j2 = lane >> 5;
  float ev = ed[i * 32 + hh];
  int beg = rowp[i], end = rowp[i + 1];
  int deg = end - beg;
  int colv = (lane < deg) ? col[beg + lane] : 0;
  f32x2 acc[8];
#pragma unroll
  for (int k = 0; k < 8; ++k) acc[k] = (f32x2){0.f, 0.f};
  float Z = 0.f;
  int j = j2;
  int4 ng = (int4){0, 0, 0, 0};
  float ne = 0.f;
  if (j < deg) {
    int s = __shfl(colv, j);
    ng = ((const int4*)(h + (size_t)s * 512))[hh];
    ne = es[s * 32 + hh];
  }
  for (; j < deg; j += 2) {
    int4 g = ng; float ee = ne;
    int jn = j + 2;
    if (jn < deg) {
      int sn = (jn < 64) ? __shfl(colv, jn) : col[beg + jn];
      ng = ((const int4*)(h + (size_t)sn * 512))[hh];
      ne = es[sn * 32 + hh];
    }
    float q = __expf(lrelu_clamp(ee + ev));
    Z += q;
    f32x2 d[8];
    dec16p(g, d);
    f32x2 qv = (f32x2){q, q};
#pragma unroll
    for (int k = 0; k < 8; ++k) acc[k] = __builtin_elementwise_fma(qv, d[k], acc[k]);
  }
  Z += __shfl_xor(Z, 32);
  float zi = 1.0f / Z;
  f32x2 ziv = (f32x2){zi, zi};
  f32x2 v2[8];
#pragma unroll
  for (int k = 0; k < 8; ++k) v2[k] = acc[k] * ziv;
#pragma unroll
  for (int m = 1; m < 64; m <<= 1)
#pragma unroll
    for (int k = 0; k < 8; ++k) {
      v2[k].x += __shfl_xor(v2[k].x, m);
      v2[k].y += __shfl_xor(v2[k].y, m);
    }
  if (lane == 0) {
    float v[16];
#pragma unroll
    for (int k = 0; k < 8; ++k) { v[2 * k] = v2[k].x; v[2 * k + 1] = v2[k].y; }
    int isbf = *flag;
    if (isbf) {
      unsigned short ob[16];
#pragma unroll
      for (int k = 0; k < 16; ++k) {
        float t = v[k] * (1.f / 32.f) + bias[k];
        t = (t > 0.f) ? t : (__expf(t) - 1.f);
        ob[k] = f2bf(t);
      }
      unsigned short* o = (unsigned short*)outbase + eoff + (size_t)i * 16;
      *(int4*)o = *(const int4*)ob;
      *(int4*)(o + 8) = *(const int4*)(ob + 8);
    } else {
      float* o = (float*)outbase + eoff + (size_t)i * 16;
#pragma unroll
      for (int k = 0; k < 16; ++k) {
        float t = v[k] * (1.f / 32.f) + bias[k];
        t = (t > 0.f) ? t : (__expf(t) - 1.f);
        o[k] = t;
      }
    }
  }
}

extern "C" void kernel_launch(void* const* d_in, const int* in_sizes, int n_in,
                              void* d_out, int out_size, void* d_ws, size_t ws_size,
                              hipStream_t stream) {
  const int n = in_sizes[0] / 128;   // 10000
  const int E = in_sizes[1] / 2;     // 80000
  const int* ei = (const int*)d_in[1];

  char* wsp = (char*)d_ws; size_t off = 0;
  auto alloc = [&](size_t bytes) -> void* {
    void* p = wsp + off; off = (off + bytes + 255) & ~(size_t)255; return p;
  };
  int* flag = (int*)alloc(4);
  float* xc = (float*)alloc((size_t)n * 128 * 4);
  unsigned short* xp = (unsigned short*)alloc((size_t)n * 128 * 2);
  unsigned short* W1p = (unsigned short*)alloc((size_t)2048 * 128 * 2);
  unsigned short* W2p = (unsigned short*)alloc((size_t)512 * 64 * 2);
  unsigned short* W3p = (unsigned short*)alloc((size_t)2048 * 128 * 2);
  unsigned short* W4p = (unsigned short*)alloc((size_t)512 * 64 * 2);
  unsigned char* h1 = (unsigned char*)alloc((size_t)n * 2048);   // fp8
  unsigned char* h3 = (unsigned char*)alloc((size_t)n * 2048);
  unsigned char* h2 = (unsigned char*)alloc((size_t)n * 512);
  unsigned char* h4 = (unsigned char*)alloc((size_t)n * 512);
  float* es1 = (float*)alloc((size_t)n * 32 * 4);
  float* ed1 = (float*)alloc((size_t)n * 32 * 4);
  float* es3 = (float*)alloc((size_t)n * 32 * 4);
  float* ed3 = (float*)alloc((size_t)n * 32 * 4);
  float* es2 = (float*)alloc((size_t)n * 32 * 4);
  float* ed2 = (float*)alloc((size_t)n * 32 * 4);
  float* es4 = (float*)alloc((size_t)n * 32 * 4);
  float* ed4 = (float*)alloc((size_t)n * 32 * 4);
  unsigned short* xsp = (unsigned short*)alloc((size_t)n * 64 * 2);
  unsigned short* xtp = (unsigned short*)alloc((size_t)n * 64 * 2);
  int* rowA = (int*)alloc((size_t)(n + 1) * 4);
  int* rowB = (int*)alloc((size_t)(n + 1) * 4);
  int* colA = (int*)alloc((size_t)(E + n) * 4);
  int* colB = (int*)alloc((size_t)(E + n) * 4);
  int* degAB = (int*)alloc((size_t)2 * n * 4);
  int* degA = degAB, * degB = degAB + n;
  int* curA = (int*)alloc((size_t)n * 4);
  int* curB = (int*)alloc((size_t)n * 4);
  float* was1 = (float*)alloc((size_t)128 * 32 * 4);
  float* wad1 = (float*)alloc((size_t)128 * 32 * 4);
  float* was3 = (float*)alloc((size_t)128 * 32 * 4);
  float* wad3 = (float*)alloc((size_t)128 * 32 * 4);

  static const int cidx[32] = {3,4,5, 7,8,9, 11,12,13, 15,16,17,
                               18,19,20,21,22,23,24,25,26,27,28,29,
                               30,31,32,33,34,35,36,37};
  PrepDesc pd;
  float* canon[38] = {nullptr};
  pd.ctotal = 0;
  for (int t = 0; t < 32; ++t) {
    int ii = cidx[t];
    canon[ii] = (float*)alloc((size_t)in_sizes[ii] * 4);
    pd.csrc[t] = d_in[ii];
    pd.cdst[t] = canon[ii];
    pd.cn[t] = in_sizes[ii];
    pd.ctotal += in_sizes[ii];
  }
  pd.x = d_in[0]; pd.xc = xc; pd.xp = xp;
  pd.W1 = d_in[2]; pd.W2 = d_in[6]; pd.W3 = d_in[10]; pd.W4 = d_in[14];
  pd.P1 = W1p; pd.P2 = W2p; pd.P3 = W3p; pd.P4 = W4p;
  pd.degAB = degAB;
  pd.ei = ei;
  pd.av[0] = d_in[3]; pd.av[1] = d_in[4]; pd.av[2] = d_in[11]; pd.av[3] = d_in[12];
  pd.wa[0] = was1; pd.wa[1] = wad1; pd.wa[2] = was3; pd.wa[3] = wad3;
  pd.nxb = (n * 128 / 8 + 255) / 256;   // vectorized 8/thread
  pd.xtotal = n * 128;
  pd.E = E;
  pd.nn = n;
  (void)ws_size; (void)n_in; (void)out_size;

  const int degblks = (E + 255) / 256;  // 313

  // ---- detect + zero degAB ----
  k_detect<<<9, 256, 0, stream>>>((const unsigned int*)d_in[0], flag, degAB, 2 * n);
  // ---- unified prep + canon(32 direct blocks) + degree count + Wa fold ----
  k_prep<<<pd.nxb + 288 + 32 + degblks + 64, 256, 0, stream>>>(pd, flag);
  // ---- CSR scan ----
  k_exscan2<<<2, 1024, 0, stream>>>(degA, degB, rowA, rowB, colA, colB, curA, curB, n);

  const int mt = n / 16;              // 625
  const int nrg = (mt + 3) / 4;       // 157
  const int mmblks64 = nrg * 8;
  const int mmblks16 = nrg * 2;
  const int gb = (n + 3) / 4;         // 2500

  // ---- stage 1: residual+GEMV -> scatter -> mm1 -> mm3 (merged; A via gload_lds) ----
  MM13XDesc md;
  md.resblks = mt; md.sblks = degblks; md.mmblks = mmblks64; md.mt = mt; md.E = E;
  md.ei = ei; md.colA = colA; md.colB = colB; md.curA = curA; md.curB = curB;
  md.xc = xc;
  for (int t = 0; t < 20; ++t) md.rp[t] = canon[18 + t];
  md.wa[0] = was1; md.wa[1] = wad1; md.wa[2] = was3; md.wa[3] = wad3;
  md.es1 = es1; md.ed1 = ed1; md.es3 = es3; md.ed3 = ed3;
  md.outbase = d_out; md.eoff = (size_t)2 * n * 16; md.n = n; md.flag = flag;
  md.Ap = xp; md.B1 = W1p; md.B3 = W3p; md.C1 = h1; md.C3 = h3;
  k_mm13x<<<mt + degblks + 2 * mmblks64, 256, 0, stream>>>(md);

  // ---- stage 2: gather64 both flows (1 wave per node, round-8 body) ----
  k_g64<<<2 * gb, 256, 0, stream>>>(h1, h3, es1, ed1, es3, ed3,
                                    rowA, colA, rowB, colB,
                                    canon[5], canon[13], xsp, xtp, n, gb);
  // ---- stage 3: mm2 + mm4 (A via gload_lds) ----
  k_mm24<<<2 * mmblks16, 256, 0, stream>>>(xsp, xtp, W2p, W4p, h2, h4,
                                           canon[7], canon[8], canon[15], canon[16],
                                           es2, ed2, es4, ed4, mmblks16, mt);
  // ---- stage 4: gather16 both flows -> outputs 0,1 ----
  k_g16<<<2 * gb, 256, 0, stream>>>(h2, h4, es2, ed2, es4, ed4,
                                    rowA, colA, rowB, colB,
                                    canon[9], canon[17], d_out, n, gb, flag);
}